// Round 4
// baseline (875.060 us; speedup 1.0000x reference)
//
#include <hip/hip_runtime.h>

#define BB 4
#define LL 2048
#define QQ 2048
#define HH 16
#define DD 64
#define EE 1024
#define NB 512

// ---------- dst[z] = src[2z] + src[2z+1]  (slab pair reduce; in-place safe) ----------
__global__ __launch_bounds__(256) void add_pairs(
    float* __restrict__ dst, long dstStride,
    const float* __restrict__ src, long srcPairStride, long n)
{
  float* d = dst + (long)blockIdx.z * dstStride;
  const float* s0 = src + (long)blockIdx.z * srcPairStride;
  const float* s1 = s0 + n;
  long i0 = ((long)blockIdx.x * 256 + threadIdx.x) * 4;
  long stride = (long)gridDim.x * 1024;
  for (long i = i0; i < n; i += stride) {
    float4 a = *(const float4*)&s0[i];
    float4 b = *(const float4*)&s1[i];
    a.x += b.x; a.y += b.y; a.z += b.z; a.w += b.w;
    *(float4*)&d[i] = a;
  }
}

// ================= 128x128-tile fp32 GEMMs, 256 thr, 8x8 microtile, split-K =================
// LDS [k][m] K-major, pad to 132 floats. 4 ds_read_b128 per 64 FMA per kk.

// C[z][m,n] = sum_{k in chunk ks} A[m,k]*B[n,k]; z = b*NS+ks
// pairOffA != 0: A-element = A[x] + A[pairOffA + x]  (folds slab pair-add into staging)
__global__ __launch_bounds__(256) void gemm_nt128(
    const float* __restrict__ A, const float* __restrict__ B, float* __restrict__ C,
    int N, int K, long sA, long sB, long sC, int NS, int Kc, long pairOffA)
{
  const int z = blockIdx.z;
  const int b = z / NS, ks = z - b * NS;
  A += (long)b * sA + (long)ks * Kc;
  B += (long)b * sB + (long)ks * Kc;
  C += (long)z * sC;
  __shared__ float As[32][132], Bs[32][132];
  const int t = threadIdx.x;
  const int tx = t & 15, ty = t >> 4;
  const long m0 = (long)blockIdx.y * 128, n0 = (long)blockIdx.x * 128;
  float acc[8][8] = {};
  for (int k0 = 0; k0 < Kc; k0 += 32) {
    #pragma unroll
    for (int i = 0; i < 4; i++) {
      int f = t + i * 256;               // 0..1023
      int r = f >> 3, k4 = f & 7;        // row 0..127, k-quad 0..7
      long ia = (m0 + r) * K + k0 + k4 * 4;
      float4 va = *(const float4*)&A[ia];
      if (pairOffA) {
        float4 v2 = *(const float4*)&A[pairOffA + ia];
        va.x += v2.x; va.y += v2.y; va.z += v2.z; va.w += v2.w;
      }
      As[k4*4+0][r] = va.x; As[k4*4+1][r] = va.y; As[k4*4+2][r] = va.z; As[k4*4+3][r] = va.w;
      float4 vb = *(const float4*)&B[(n0 + r) * K + k0 + k4 * 4];
      Bs[k4*4+0][r] = vb.x; Bs[k4*4+1][r] = vb.y; Bs[k4*4+2][r] = vb.z; Bs[k4*4+3][r] = vb.w;
    }
    __syncthreads();
    #pragma unroll
    for (int kk = 0; kk < 32; kk++) {
      float4 a0 = *(const float4*)&As[kk][ty*8];
      float4 a1 = *(const float4*)&As[kk][ty*8+4];
      float4 b0 = *(const float4*)&Bs[kk][tx*8];
      float4 b1 = *(const float4*)&Bs[kk][tx*8+4];
      float ar[8] = {a0.x,a0.y,a0.z,a0.w,a1.x,a1.y,a1.z,a1.w};
      float br[8] = {b0.x,b0.y,b0.z,b0.w,b1.x,b1.y,b1.z,b1.w};
      #pragma unroll
      for (int i = 0; i < 8; i++)
        #pragma unroll
        for (int j = 0; j < 8; j++)
          acc[i][j] += ar[i] * br[j];
    }
    __syncthreads();
  }
  #pragma unroll
  for (int i = 0; i < 8; i++) {
    float4 o0 = make_float4(acc[i][0], acc[i][1], acc[i][2], acc[i][3]);
    float4 o1 = make_float4(acc[i][4], acc[i][5], acc[i][6], acc[i][7]);
    *(float4*)&C[(m0 + ty*8 + i) * N + n0 + tx*8    ] = o0;
    *(float4*)&C[(m0 + ty*8 + i) * N + n0 + tx*8 + 4] = o1;
  }
}

// C[z][m,n] = sum_{k in chunk} A[k,m]*B[k,n]; A: KxM row-major, B: KxN row-major
__global__ __launch_bounds__(256) void gemm_tn128(
    const float* __restrict__ A, const float* __restrict__ B, float* __restrict__ C,
    int M, int N, long sA, long sB, long sC, int NS, int Kc)
{
  const int z = blockIdx.z;
  const int b = z / NS, ks = z - b * NS;
  A += (long)b * sA + (long)ks * Kc * M;
  B += (long)b * sB + (long)ks * Kc * N;
  C += (long)z * sC;
  __shared__ float As[32][132], Bs[32][132];
  const int t = threadIdx.x;
  const int tx = t & 15, ty = t >> 4;
  const long m0 = (long)blockIdx.y * 128, n0 = (long)blockIdx.x * 128;
  float acc[8][8] = {};
  for (int k0 = 0; k0 < Kc; k0 += 32) {
    #pragma unroll
    for (int i = 0; i < 4; i++) {
      int f = t + i * 256;               // 0..1023 = 32 k-rows x 32 f4
      int r = f >> 5, c4 = f & 31;
      *(float4*)&As[r][c4 * 4] = *(const float4*)&A[(long)(k0 + r) * M + m0 + c4 * 4];
      *(float4*)&Bs[r][c4 * 4] = *(const float4*)&B[(long)(k0 + r) * N + n0 + c4 * 4];
    }
    __syncthreads();
    #pragma unroll
    for (int kk = 0; kk < 32; kk++) {
      float4 a0 = *(const float4*)&As[kk][ty*8];
      float4 a1 = *(const float4*)&As[kk][ty*8+4];
      float4 b0 = *(const float4*)&Bs[kk][tx*8];
      float4 b1 = *(const float4*)&Bs[kk][tx*8+4];
      float ar[8] = {a0.x,a0.y,a0.z,a0.w,a1.x,a1.y,a1.z,a1.w};
      float br[8] = {b0.x,b0.y,b0.z,b0.w,b1.x,b1.y,b1.z,b1.w};
      #pragma unroll
      for (int i = 0; i < 8; i++)
        #pragma unroll
        for (int j = 0; j < 8; j++)
          acc[i][j] += ar[i] * br[j];
    }
    __syncthreads();
  }
  #pragma unroll
  for (int i = 0; i < 8; i++) {
    float4 o0 = make_float4(acc[i][0], acc[i][1], acc[i][2], acc[i][3]);
    float4 o1 = make_float4(acc[i][4], acc[i][5], acc[i][6], acc[i][7]);
    *(float4*)&C[(m0 + ty*8 + i) * N + n0 + tx*8    ] = o0;
    *(float4*)&C[(m0 + ty*8 + i) * N + n0 + tx*8 + 4] = o1;
  }
}

// 64x64/4x4 NT GEMM kept for tier-2 per-batch st7
__global__ __launch_bounds__(256) void gemm_nt64(
    const float* __restrict__ A, const float* __restrict__ B, float* __restrict__ C,
    int M, int N, int K, long sA, long sB, long sC)
{
  A += (long)blockIdx.z * sA; B += (long)blockIdx.z * sB; C += (long)blockIdx.z * sC;
  __shared__ float As[32][68], Bs[32][68];
  const int t = threadIdx.x;
  const int tx = t & 15, ty = t >> 4;
  const int m0 = blockIdx.y * 64, n0 = blockIdx.x * 64;
  float acc[4][4] = {};
  for (int k0 = 0; k0 < K; k0 += 32) {
    #pragma unroll
    for (int i = 0; i < 2; i++) {
      int f = t + i * 256;
      int r = f >> 3, k4 = f & 7;
      float4 va = *(const float4*)&A[(long)(m0 + r) * K + k0 + k4 * 4];
      As[k4*4+0][r] = va.x; As[k4*4+1][r] = va.y; As[k4*4+2][r] = va.z; As[k4*4+3][r] = va.w;
      float4 vb = *(const float4*)&B[(long)(n0 + r) * K + k0 + k4 * 4];
      Bs[k4*4+0][r] = vb.x; Bs[k4*4+1][r] = vb.y; Bs[k4*4+2][r] = vb.z; Bs[k4*4+3][r] = vb.w;
    }
    __syncthreads();
    #pragma unroll
    for (int kk = 0; kk < 32; kk++) {
      float4 a4 = *(const float4*)&As[kk][ty * 4];
      float4 b4 = *(const float4*)&Bs[kk][tx * 4];
      float ar[4] = {a4.x, a4.y, a4.z, a4.w};
      float br[4] = {b4.x, b4.y, b4.z, b4.w};
      #pragma unroll
      for (int i = 0; i < 4; i++)
        #pragma unroll
        for (int j = 0; j < 4; j++)
          acc[i][j] += ar[i] * br[j];
    }
    __syncthreads();
  }
  #pragma unroll
  for (int i = 0; i < 4; i++) {
    float4 o = make_float4(acc[i][0], acc[i][1], acc[i][2], acc[i][3]);
    *(float4*)&C[(long)(m0 + ty*4 + i) * N + n0 + tx*4] = o;
  }
}

// ================= collapsed scores path (linear in qry and keys) =================
// pairOff != 0: Bm element = Bm[x] + Bm[pairOff + x] (split-K slab pair)
__global__ __launch_bounds__(256) void nb_uvec(
    const float* __restrict__ Bm, const float* __restrict__ wmu, const float* __restrict__ wsg,
    float* __restrict__ ump, float* __restrict__ usp, long sBm, long sU, long pairOff)
{
  Bm += (long)blockIdx.z * sBm; ump += (long)blockIdx.z * sU; usp += (long)blockIdx.z * sU;
  const int e = blockIdx.x * 256 + threadIdx.x;
  const int c = blockIdx.y;
  float am = 0.f, as = 0.f;
  #pragma unroll 8
  for (int n = c * 64; n < c * 64 + 64; n++) {
    float bv = Bm[(long)n * EE + e];
    if (pairOff) bv += Bm[pairOff + (long)n * EE + e];
    am += wmu[n] * bv;
    as += wsg[n] * bv;
  }
  ump[(long)c * EE + e] = am;
  usp[(long)c * EE + e] = as;
}

__global__ __launch_bounds__(256) void nb_kw(
    const float* __restrict__ Wk, const float* __restrict__ ump, const float* __restrict__ usp,
    float* __restrict__ kwm, float* __restrict__ kws, long sU, long sK)
{
  ump += (long)blockIdx.z * sU; usp += (long)blockIdx.z * sU;
  kwm += (long)blockIdx.z * sK; kws += (long)blockIdx.z * sK;
  __shared__ float pm[256], ps[256];
  const int e = blockIdx.x, t = threadIdx.x;
  const float* row = Wk + (long)e * EE;
  float am = 0.f, as = 0.f;
  for (int i = t; i < EE; i += 256) {
    float um = 0.f, us = 0.f;
    #pragma unroll
    for (int c = 0; c < 8; c++) { um += ump[(long)c * EE + i]; us += usp[(long)c * EE + i]; }
    float w = row[i];
    am += w * um;
    as += w * us;
  }
  pm[t] = am; ps[t] = as;
  __syncthreads();
  for (int s = 128; s > 0; s >>= 1) {
    if (t < s) { pm[t] += pm[t + s]; ps[t] += ps[t + s]; }
    __syncthreads();
  }
  if (t == 0) { kwm[e] = pm[0]; kws[e] = ps[0]; }
}

__global__ __launch_bounds__(256) void nb_amas(
    const float* __restrict__ Wq, const float* __restrict__ kwm, const float* __restrict__ kws,
    float* __restrict__ AmAs, long sK, long sAm)
{
  kwm += (long)blockIdx.z * sK; kws += (long)blockIdx.z * sK;
  AmAs += (long)blockIdx.z * sAm;
  __shared__ float km[64], ks[64];
  const int t = threadIdx.x;
  const int h = blockIdx.y;
  const int e = blockIdx.x * 256 + t;
  if (t < 64) { km[t] = kwm[h * 64 + t]; ks[t] = kws[h * 64 + t]; }
  __syncthreads();
  float am = 0.f, as = 0.f;
  #pragma unroll 8
  for (int d = 0; d < 64; d++) {
    float w = Wq[(long)(h * 64 + d) * EE + e];
    am += km[d] * w;
    as += ks[d] * w;
  }
  AmAs[(long)e * 32 + h]      = am;
  AmAs[(long)e * 32 + 16 + h] = as;
}

__global__ __launch_bounds__(256) void nb_musig(
    const float* __restrict__ qb, const float* __restrict__ AmAs,
    float* __restrict__ muq, float* __restrict__ sg2, long sQ, long sAm, long sMu)
{
  qb += (long)blockIdx.z * sQ; AmAs += (long)blockIdx.z * sAm;
  muq += (long)blockIdx.z * sMu; sg2 += (long)blockIdx.z * sMu;
  __shared__ float qs[EE];
  __shared__ float part[8][32];
  const int t = threadIdx.x, qrow = blockIdx.x;
  for (int i = t; i < EE; i += 256) qs[i] = qb[(long)qrow * EE + i];
  __syncthreads();
  const int o = t & 31, ch = t >> 5;
  float acc = 0.f;
  const int e0 = ch * 128;
  #pragma unroll 8
  for (int i = 0; i < 128; i++) {
    int e = e0 + i;
    acc += qs[e] * AmAs[(long)e * 32 + o];
  }
  part[ch][o] = acc;
  __syncthreads();
  if (t < 32) {
    float s = 0.f;
    #pragma unroll
    for (int c = 0; c < 8; c++) s += part[c][o];
    s *= 0.125f;
    if (o < 16) {
      muq[(long)o * QQ + qrow] = 1.f / (1.f + expf(-s));
    } else {
      float sp = (s > 20.f) ? s : log1pf(expf(s));
      sg2[(long)(o - 16) * QQ + qrow] = fmaxf(sp, 1e-4f);
    }
  }
}

// ================= ctx: 128q x 64e tile per head, 128 thr, 8x8 micro =================
// r via native rcp/exp/rsq: ~10 VALU/element vs ~100 for libm expf + precise div/sqrt.
__global__ __launch_bounds__(128) void nb_ctx128(
    const float* __restrict__ vals, const float* __restrict__ muq, const float* __restrict__ sg2,
    const float* __restrict__ bmu,  const float* __restrict__ bsg, float* __restrict__ ctx,
    long sV, long sMu, long sC)
{
  vals += (long)blockIdx.z * sV; ctx += (long)blockIdx.z * sC;
  muq += (long)blockIdx.z * sMu; sg2 += (long)blockIdx.z * sMu;
  __shared__ float As[32][132], Bs[32][68];     // As: r^T [n][q], Bs: vals [n][e]
  __shared__ __align__(16) float mu_s[128], s2_s[128];
  const int t = threadIdx.x;
  const int tx = t & 7, ty = t >> 3;
  const long q0 = (long)blockIdx.x * 128;
  const int h = blockIdx.y;
  mu_s[t] = muq[(long)h * QQ + q0 + t];
  s2_s[t] = sg2[(long)h * QQ + q0 + t];
  __syncthreads();
  float acc[8][8] = {};
  for (int n0 = 0; n0 < NB; n0 += 32) {
    #pragma unroll
    for (int i = 0; i < 4; i++) {
      int f = t + i * 128;               // 512 f4 = 32n x 16 f4
      int r = f >> 4, c4 = f & 15;
      *(float4*)&Bs[r][c4 * 4] = *(const float4*)&vals[(long)(n0 + r) * EE + h * 64 + c4 * 4];
    }
    #pragma unroll
    for (int i = 0; i < 8; i++) {
      int idx = t + i * 128;             // 1024 groups = 32n x 32 q-quads
      int n = idx >> 5, qg = idx & 31;
      float bm = bmu[n0 + n], bs = bsg[n0 + n];
      float bs2 = bs * bs;
      float4 m4 = *(const float4*)&mu_s[qg * 4];
      float4 s4 = *(const float4*)&s2_s[qg * 4];
      float4 rr;
      {
        float v0 = s4.x + bs2, d0 = m4.x - bm;
        float v1 = s4.y + bs2, d1 = m4.y - bm;
        float v2 = s4.z + bs2, d2 = m4.z - bm;
        float v3 = s4.w + bs2, d3 = m4.w - bm;
        float r0 = __builtin_amdgcn_rcpf(v0), r1 = __builtin_amdgcn_rcpf(v1);
        float r2 = __builtin_amdgcn_rcpf(v2), r3 = __builtin_amdgcn_rcpf(v3);
        rr.x = __expf(d0 * d0 * r0 * -0.5f) * __builtin_amdgcn_rsqf(v0 * 6.2831853071795865f);
        rr.y = __expf(d1 * d1 * r1 * -0.5f) * __builtin_amdgcn_rsqf(v1 * 6.2831853071795865f);
        rr.z = __expf(d2 * d2 * r2 * -0.5f) * __builtin_amdgcn_rsqf(v2 * 6.2831853071795865f);
        rr.w = __expf(d3 * d3 * r3 * -0.5f) * __builtin_amdgcn_rsqf(v3 * 6.2831853071795865f);
      }
      *(float4*)&As[n][qg * 4] = rr;
    }
    __syncthreads();
    #pragma unroll
    for (int kk = 0; kk < 32; kk++) {
      float4 a0 = *(const float4*)&As[kk][ty*8];
      float4 a1 = *(const float4*)&As[kk][ty*8+4];
      float4 b0 = *(const float4*)&Bs[kk][tx*8];
      float4 b1 = *(const float4*)&Bs[kk][tx*8+4];
      float ar[8] = {a0.x,a0.y,a0.z,a0.w,a1.x,a1.y,a1.z,a1.w};
      float br[8] = {b0.x,b0.y,b0.z,b0.w,b1.x,b1.y,b1.z,b1.w};
      #pragma unroll
      for (int i = 0; i < 8; i++)
        #pragma unroll
        for (int j = 0; j < 8; j++)
          acc[i][j] += ar[i] * br[j];
    }
    __syncthreads();
  }
  #pragma unroll
  for (int i = 0; i < 8; i++) {
    float4 o0 = make_float4(acc[i][0], acc[i][1], acc[i][2], acc[i][3]);
    float4 o1 = make_float4(acc[i][4], acc[i][5], acc[i][6], acc[i][7]);
    *(float4*)&ctx[(q0 + ty*8 + i) * EE + h * 64 + tx*8    ] = o0;
    *(float4*)&ctx[(q0 + ty*8 + i) * EE + h * 64 + tx*8 + 4] = o1;
  }
}

extern "C" void kernel_launch(void* const* d_in, const int* in_sizes, int n_in,
                              void* d_out, int out_size, void* d_ws, size_t ws_size,
                              hipStream_t stream) {
  const float* k   = (const float*)d_in[0];
  const float* q   = (const float*)d_in[1];
  const float* Wq  = (const float*)d_in[2];
  const float* Wk  = (const float*)d_in[3];
  const float* Wv  = (const float*)d_in[4];
  const float* Wo  = (const float*)d_in[5];
  const float* wmu = (const float*)d_in[6];
  const float* wsg = (const float*)d_in[7];
  const float* Gs  = (const float*)d_in[8];
  const float* bmu = (const float*)d_in[9];
  const float* bsg = (const float*)d_in[10];
  float* out = (float*)d_out;
  char* ws = (char*)d_ws;

  const long sBm = (long)NB * EE;      // 2 MiB
  const long sU  = 8L * EE;
  const long sK  = EE;
  const long sAm = 32L * EE;
  const long sMu = (long)HH * QQ;
  const long sQ  = (long)QQ * EE;      // 8 MiB

  if (ws_size >= (50u << 20)) {
    // ---- tier 1 (42 MiB used) ----
    // BmP [0,16): 8 split-K slabs (z=b*2+ks, stride sBm) — dead after st3+uvec
    // valsP [16,32): 8 slabs — dead after add_pairs
    // ctx4 [0,32): written by nb_ctx128 (after both producers dead)
    // vals4 [32,40) | smalls [40,42)
    float* BmP   = (float*)(ws + 0);
    float* valsP = (float*)(ws + (16u << 20));
    float* ctx4  = (float*)(ws + 0);
    float* vals4 = (float*)(ws + (32u << 20));
    char*  sm    = ws + (40u << 20);
    float* ump4  = (float*)(sm);                    // 128 KiB
    float* usp4  = (float*)(sm + (128u << 10));     // 128 KiB
    float* kwm4  = (float*)(sm + (256u << 10));     // 16 KiB
    float* kws4  = (float*)(sm + (272u << 10));     // 16 KiB
    float* AmAs4 = (float*)(sm + (288u << 10));     // 512 KiB
    float* muq4  = (float*)(sm + (800u << 10));     // 512 KiB
    float* sg24  = (float*)(sm + (1312u << 10));    // 512 KiB

    // st2: Bm = Gs^T @ k, split-K=2 (256 blocks); pairs consumed directly downstream
    gemm_tn128<<<dim3(EE/128, NB/128, BB*2), 256, 0, stream>>>(
        Gs, k, BmP, NB, EE, 0L, (long)LL*EE, sBm, 2, LL/2);
    // st3: vals = (Bm0+Bm1) @ Wv^T, split-K=2 (256 blocks), pair-add folded into staging
    gemm_nt128<<<dim3(EE/128, NB/128, BB*2), 256, 0, stream>>>(
        BmP, Wv, valsP, EE, EE, 2*sBm, 0L, sBm, 2, EE/2, sBm);
    add_pairs<<<dim3(256, 1, BB), 256, 0, stream>>>(vals4, sBm, valsP, 2*sBm, sBm);
    // collapsed scores chain (uvec reads Bm pair directly)
    nb_uvec  <<<dim3(EE/256, 8, BB),  256, 0, stream>>>(BmP, wmu, wsg, ump4, usp4, 2*sBm, sU, sBm);
    nb_kw    <<<dim3(EE, 1, BB),      256, 0, stream>>>(Wk, ump4, usp4, kwm4, kws4, sU, sK);
    nb_amas  <<<dim3(EE/256, HH, BB), 256, 0, stream>>>(Wq, kwm4, kws4, AmAs4, sK, sAm);
    nb_musig <<<dim3(QQ, 1, BB),      256, 0, stream>>>(q, AmAs4, muq4, sg24, sQ, sAm, sMu);
    // ctx (1024 blocks) then st7 batched (512 blocks)
    nb_ctx128<<<dim3(QQ/128, HH, BB), 128, 0, stream>>>(
        vals4, muq4, sg24, bmu, bsg, ctx4, sBm, sMu, sQ);
    gemm_nt128<<<dim3(EE/128, QQ/128, BB), 256, 0, stream>>>(
        ctx4, Wo, out, EE, EE, sQ, 0L, sQ, 1, EE, 0L);
  } else {
    // ---- tier 2 (ws >= 26 MiB) ----
    float* BmP   = (float*)(ws + 0);
    float* ctxS  = (float*)(ws + 0);
    float* vals4 = (float*)(ws + (16u << 20));
    char*  sm    = ws + (24u << 20);
    float* ump4  = (float*)(sm);
    float* usp4  = (float*)(sm + (128u << 10));
    float* kwm4  = (float*)(sm + (256u << 10));
    float* kws4  = (float*)(sm + (272u << 10));
    float* AmAs4 = (float*)(sm + (288u << 10));
    float* muq4  = (float*)(sm + (800u << 10));
    float* sg24  = (float*)(sm + (1312u << 10));

    gemm_tn128<<<dim3(EE/128, NB/128, BB*2), 256, 0, stream>>>(
        Gs, k, BmP, NB, EE, 0L, (long)LL*EE, sBm, 2, LL/2);
    add_pairs<<<dim3(256, 1, BB), 256, 0, stream>>>(BmP, 2*sBm, BmP, 2*sBm, sBm);
    gemm_nt128<<<dim3(EE/128, NB/128, BB), 256, 0, stream>>>(
        BmP, Wv, vals4, EE, EE, 2*sBm, 0L, sBm, 1, EE, 0L);
    nb_uvec  <<<dim3(EE/256, 8, BB),  256, 0, stream>>>(BmP, wmu, wsg, ump4, usp4, 2*sBm, sU, 0L);
    nb_kw    <<<dim3(EE, 1, BB),      256, 0, stream>>>(Wk, ump4, usp4, kwm4, kws4, sU, sK);
    nb_amas  <<<dim3(EE/256, HH, BB), 256, 0, stream>>>(Wq, kwm4, kws4, AmAs4, sK, sAm);
    nb_musig <<<dim3(QQ, 1, BB),      256, 0, stream>>>(q, AmAs4, muq4, sg24, sQ, sAm, sMu);
    for (int b = 0; b < BB; b++) {
      nb_ctx128<<<dim3(QQ/128, HH, 1), 128, 0, stream>>>(
          vals4 + (long)b*sBm, muq4 + (long)b*sMu, sg24 + (long)b*sMu,
          bmu, bsg, ctxS, 0L, 0L, 0L);
      gemm_nt64<<<dim3(EE/64, QQ/64, 1), 256, 0, stream>>>(
          ctxS, Wo, out + (long)b*sQ, QQ, EE, EE, 0L, 0L, 0L);
    }
  }
  (void)in_sizes; (void)n_in; (void)out_size;
}

// Round 5
// 706.704 us; speedup vs baseline: 1.2382x; 1.2382x over previous
//
#include <hip/hip_runtime.h>

#define BB 4
#define LL 2048
#define QQ 2048
#define HH 16
#define DD 64
#define EE 1024
#define NB 512

// ---------- dst[z] = src[2z] + src[2z+1]  (slab pair reduce; in-place safe) ----------
__global__ __launch_bounds__(256) void add_pairs(
    float* __restrict__ dst, long dstStride,
    const float* __restrict__ src, long srcPairStride, long n)
{
  float* d = dst + (long)blockIdx.z * dstStride;
  const float* s0 = src + (long)blockIdx.z * srcPairStride;
  const float* s1 = s0 + n;
  long i0 = ((long)blockIdx.x * 256 + threadIdx.x) * 4;
  long stride = (long)gridDim.x * 1024;
  for (long i = i0; i < n; i += stride) {
    float4 a = *(const float4*)&s0[i];
    float4 b = *(const float4*)&s1[i];
    a.x += b.x; a.y += b.y; a.z += b.z; a.w += b.w;
    *(float4*)&d[i] = a;
  }
}

// ================= 128x128-tile fp32 GEMMs, 256 thr, 8x8 microtile, split-K =================
// LDS [k][m] K-major, pad to 132 floats. 4 ds_read_b128 per 64 FMA per kk.
// NOTE: no runtime flags in the staging loop — a uniform branch there cost 30% in round 4.

// C[z][m,n] = sum_{k in chunk ks} A[m,k]*B[n,k]; z = b*NS+ks
__global__ __launch_bounds__(256) void gemm_nt128(
    const float* __restrict__ A, const float* __restrict__ B, float* __restrict__ C,
    int N, int K, long sA, long sB, long sC, int NS, int Kc)
{
  const int z = blockIdx.z;
  const int b = z / NS, ks = z - b * NS;
  A += (long)b * sA + (long)ks * Kc;
  B += (long)b * sB + (long)ks * Kc;
  C += (long)z * sC;
  __shared__ float As[32][132], Bs[32][132];
  const int t = threadIdx.x;
  const int tx = t & 15, ty = t >> 4;
  const long m0 = (long)blockIdx.y * 128, n0 = (long)blockIdx.x * 128;
  float acc[8][8] = {};
  for (int k0 = 0; k0 < Kc; k0 += 32) {
    #pragma unroll
    for (int i = 0; i < 4; i++) {
      int f = t + i * 256;               // 0..1023
      int r = f >> 3, k4 = f & 7;        // row 0..127, k-quad 0..7
      float4 va = *(const float4*)&A[(m0 + r) * K + k0 + k4 * 4];
      As[k4*4+0][r] = va.x; As[k4*4+1][r] = va.y; As[k4*4+2][r] = va.z; As[k4*4+3][r] = va.w;
      float4 vb = *(const float4*)&B[(n0 + r) * K + k0 + k4 * 4];
      Bs[k4*4+0][r] = vb.x; Bs[k4*4+1][r] = vb.y; Bs[k4*4+2][r] = vb.z; Bs[k4*4+3][r] = vb.w;
    }
    __syncthreads();
    #pragma unroll
    for (int kk = 0; kk < 32; kk++) {
      float4 a0 = *(const float4*)&As[kk][ty*8];
      float4 a1 = *(const float4*)&As[kk][ty*8+4];
      float4 b0 = *(const float4*)&Bs[kk][tx*8];
      float4 b1 = *(const float4*)&Bs[kk][tx*8+4];
      float ar[8] = {a0.x,a0.y,a0.z,a0.w,a1.x,a1.y,a1.z,a1.w};
      float br[8] = {b0.x,b0.y,b0.z,b0.w,b1.x,b1.y,b1.z,b1.w};
      #pragma unroll
      for (int i = 0; i < 8; i++)
        #pragma unroll
        for (int j = 0; j < 8; j++)
          acc[i][j] += ar[i] * br[j];
    }
    __syncthreads();
  }
  #pragma unroll
  for (int i = 0; i < 8; i++) {
    float4 o0 = make_float4(acc[i][0], acc[i][1], acc[i][2], acc[i][3]);
    float4 o1 = make_float4(acc[i][4], acc[i][5], acc[i][6], acc[i][7]);
    *(float4*)&C[(m0 + ty*8 + i) * N + n0 + tx*8    ] = o0;
    *(float4*)&C[(m0 + ty*8 + i) * N + n0 + tx*8 + 4] = o1;
  }
}

// C[z][m,n] = sum_{k in chunk} A[k,m]*B[k,n]; A: KxM row-major, B: KxN row-major
__global__ __launch_bounds__(256) void gemm_tn128(
    const float* __restrict__ A, const float* __restrict__ B, float* __restrict__ C,
    int M, int N, long sA, long sB, long sC, int NS, int Kc)
{
  const int z = blockIdx.z;
  const int b = z / NS, ks = z - b * NS;
  A += (long)b * sA + (long)ks * Kc * M;
  B += (long)b * sB + (long)ks * Kc * N;
  C += (long)z * sC;
  __shared__ float As[32][132], Bs[32][132];
  const int t = threadIdx.x;
  const int tx = t & 15, ty = t >> 4;
  const long m0 = (long)blockIdx.y * 128, n0 = (long)blockIdx.x * 128;
  float acc[8][8] = {};
  for (int k0 = 0; k0 < Kc; k0 += 32) {
    #pragma unroll
    for (int i = 0; i < 4; i++) {
      int f = t + i * 256;               // 0..1023 = 32 k-rows x 32 f4
      int r = f >> 5, c4 = f & 31;
      *(float4*)&As[r][c4 * 4] = *(const float4*)&A[(long)(k0 + r) * M + m0 + c4 * 4];
      *(float4*)&Bs[r][c4 * 4] = *(const float4*)&B[(long)(k0 + r) * N + n0 + c4 * 4];
    }
    __syncthreads();
    #pragma unroll
    for (int kk = 0; kk < 32; kk++) {
      float4 a0 = *(const float4*)&As[kk][ty*8];
      float4 a1 = *(const float4*)&As[kk][ty*8+4];
      float4 b0 = *(const float4*)&Bs[kk][tx*8];
      float4 b1 = *(const float4*)&Bs[kk][tx*8+4];
      float ar[8] = {a0.x,a0.y,a0.z,a0.w,a1.x,a1.y,a1.z,a1.w};
      float br[8] = {b0.x,b0.y,b0.z,b0.w,b1.x,b1.y,b1.z,b1.w};
      #pragma unroll
      for (int i = 0; i < 8; i++)
        #pragma unroll
        for (int j = 0; j < 8; j++)
          acc[i][j] += ar[i] * br[j];
    }
    __syncthreads();
  }
  #pragma unroll
  for (int i = 0; i < 8; i++) {
    float4 o0 = make_float4(acc[i][0], acc[i][1], acc[i][2], acc[i][3]);
    float4 o1 = make_float4(acc[i][4], acc[i][5], acc[i][6], acc[i][7]);
    *(float4*)&C[(m0 + ty*8 + i) * N + n0 + tx*8    ] = o0;
    *(float4*)&C[(m0 + ty*8 + i) * N + n0 + tx*8 + 4] = o1;
  }
}

// 64x64/4x4 NT GEMM kept for tier-2 per-batch st7
__global__ __launch_bounds__(256) void gemm_nt64(
    const float* __restrict__ A, const float* __restrict__ B, float* __restrict__ C,
    int M, int N, int K, long sA, long sB, long sC)
{
  A += (long)blockIdx.z * sA; B += (long)blockIdx.z * sB; C += (long)blockIdx.z * sC;
  __shared__ float As[32][68], Bs[32][68];
  const int t = threadIdx.x;
  const int tx = t & 15, ty = t >> 4;
  const int m0 = blockIdx.y * 64, n0 = blockIdx.x * 64;
  float acc[4][4] = {};
  for (int k0 = 0; k0 < K; k0 += 32) {
    #pragma unroll
    for (int i = 0; i < 2; i++) {
      int f = t + i * 256;
      int r = f >> 3, k4 = f & 7;
      float4 va = *(const float4*)&A[(long)(m0 + r) * K + k0 + k4 * 4];
      As[k4*4+0][r] = va.x; As[k4*4+1][r] = va.y; As[k4*4+2][r] = va.z; As[k4*4+3][r] = va.w;
      float4 vb = *(const float4*)&B[(long)(n0 + r) * K + k0 + k4 * 4];
      Bs[k4*4+0][r] = vb.x; Bs[k4*4+1][r] = vb.y; Bs[k4*4+2][r] = vb.z; Bs[k4*4+3][r] = vb.w;
    }
    __syncthreads();
    #pragma unroll
    for (int kk = 0; kk < 32; kk++) {
      float4 a4 = *(const float4*)&As[kk][ty * 4];
      float4 b4 = *(const float4*)&Bs[kk][tx * 4];
      float ar[4] = {a4.x, a4.y, a4.z, a4.w};
      float br[4] = {b4.x, b4.y, b4.z, b4.w};
      #pragma unroll
      for (int i = 0; i < 4; i++)
        #pragma unroll
        for (int j = 0; j < 4; j++)
          acc[i][j] += ar[i] * br[j];
    }
    __syncthreads();
  }
  #pragma unroll
  for (int i = 0; i < 4; i++) {
    float4 o = make_float4(acc[i][0], acc[i][1], acc[i][2], acc[i][3]);
    *(float4*)&C[(long)(m0 + ty*4 + i) * N + n0 + tx*4] = o;
  }
}

// ================= collapsed scores path (linear in qry and keys) =================
__global__ __launch_bounds__(256) void nb_uvec(
    const float* __restrict__ Bm, const float* __restrict__ wmu, const float* __restrict__ wsg,
    float* __restrict__ ump, float* __restrict__ usp, long sBm, long sU)
{
  Bm += (long)blockIdx.z * sBm; ump += (long)blockIdx.z * sU; usp += (long)blockIdx.z * sU;
  const int e = blockIdx.x * 256 + threadIdx.x;
  const int c = blockIdx.y;
  float am = 0.f, as = 0.f;
  #pragma unroll 8
  for (int n = c * 64; n < c * 64 + 64; n++) {
    float bv = Bm[(long)n * EE + e];
    am += wmu[n] * bv;
    as += wsg[n] * bv;
  }
  ump[(long)c * EE + e] = am;
  usp[(long)c * EE + e] = as;
}

__global__ __launch_bounds__(256) void nb_kw(
    const float* __restrict__ Wk, const float* __restrict__ ump, const float* __restrict__ usp,
    float* __restrict__ kwm, float* __restrict__ kws, long sU, long sK)
{
  ump += (long)blockIdx.z * sU; usp += (long)blockIdx.z * sU;
  kwm += (long)blockIdx.z * sK; kws += (long)blockIdx.z * sK;
  __shared__ float pm[256], ps[256];
  const int e = blockIdx.x, t = threadIdx.x;
  const float* row = Wk + (long)e * EE;
  float am = 0.f, as = 0.f;
  for (int i = t; i < EE; i += 256) {
    float um = 0.f, us = 0.f;
    #pragma unroll
    for (int c = 0; c < 8; c++) { um += ump[(long)c * EE + i]; us += usp[(long)c * EE + i]; }
    float w = row[i];
    am += w * um;
    as += w * us;
  }
  pm[t] = am; ps[t] = as;
  __syncthreads();
  for (int s = 128; s > 0; s >>= 1) {
    if (t < s) { pm[t] += pm[t + s]; ps[t] += ps[t + s]; }
    __syncthreads();
  }
  if (t == 0) { kwm[e] = pm[0]; kws[e] = ps[0]; }
}

__global__ __launch_bounds__(256) void nb_amas(
    const float* __restrict__ Wq, const float* __restrict__ kwm, const float* __restrict__ kws,
    float* __restrict__ AmAs, long sK, long sAm)
{
  kwm += (long)blockIdx.z * sK; kws += (long)blockIdx.z * sK;
  AmAs += (long)blockIdx.z * sAm;
  __shared__ float km[64], ks[64];
  const int t = threadIdx.x;
  const int h = blockIdx.y;
  const int e = blockIdx.x * 256 + t;
  if (t < 64) { km[t] = kwm[h * 64 + t]; ks[t] = kws[h * 64 + t]; }
  __syncthreads();
  float am = 0.f, as = 0.f;
  #pragma unroll 8
  for (int d = 0; d < 64; d++) {
    float w = Wq[(long)(h * 64 + d) * EE + e];
    am += km[d] * w;
    as += ks[d] * w;
  }
  AmAs[(long)e * 32 + h]      = am;
  AmAs[(long)e * 32 + 16 + h] = as;
}

__global__ __launch_bounds__(256) void nb_musig(
    const float* __restrict__ qb, const float* __restrict__ AmAs,
    float* __restrict__ muq, float* __restrict__ sg2, long sQ, long sAm, long sMu)
{
  qb += (long)blockIdx.z * sQ; AmAs += (long)blockIdx.z * sAm;
  muq += (long)blockIdx.z * sMu; sg2 += (long)blockIdx.z * sMu;
  __shared__ float qs[EE];
  __shared__ float part[8][32];
  const int t = threadIdx.x, qrow = blockIdx.x;
  for (int i = t; i < EE; i += 256) qs[i] = qb[(long)qrow * EE + i];
  __syncthreads();
  const int o = t & 31, ch = t >> 5;
  float acc = 0.f;
  const int e0 = ch * 128;
  #pragma unroll 8
  for (int i = 0; i < 128; i++) {
    int e = e0 + i;
    acc += qs[e] * AmAs[(long)e * 32 + o];
  }
  part[ch][o] = acc;
  __syncthreads();
  if (t < 32) {
    float s = 0.f;
    #pragma unroll
    for (int c = 0; c < 8; c++) s += part[c][o];
    s *= 0.125f;
    if (o < 16) {
      muq[(long)o * QQ + qrow] = 1.f / (1.f + expf(-s));
    } else {
      float sp = (s > 20.f) ? s : log1pf(expf(s));
      sg2[(long)(o - 16) * QQ + qrow] = fmaxf(sp, 1e-4f);
    }
  }
}

// ================= ctx: 128q x 64e tile per head, 128 thr, 8x8 micro =================
// r via native rcp/exp/rsq: ~10 VALU/element vs ~100 for libm expf + precise div/sqrt.
// (validated round 4: absmax identical to libm version)
__global__ __launch_bounds__(128) void nb_ctx128(
    const float* __restrict__ vals, const float* __restrict__ muq, const float* __restrict__ sg2,
    const float* __restrict__ bmu,  const float* __restrict__ bsg, float* __restrict__ ctx,
    long sV, long sMu, long sC)
{
  vals += (long)blockIdx.z * sV; ctx += (long)blockIdx.z * sC;
  muq += (long)blockIdx.z * sMu; sg2 += (long)blockIdx.z * sMu;
  __shared__ float As[32][132], Bs[32][68];     // As: r^T [n][q], Bs: vals [n][e]
  __shared__ __align__(16) float mu_s[128], s2_s[128];
  const int t = threadIdx.x;
  const int tx = t & 7, ty = t >> 3;
  const long q0 = (long)blockIdx.x * 128;
  const int h = blockIdx.y;
  mu_s[t] = muq[(long)h * QQ + q0 + t];
  s2_s[t] = sg2[(long)h * QQ + q0 + t];
  __syncthreads();
  float acc[8][8] = {};
  for (int n0 = 0; n0 < NB; n0 += 32) {
    #pragma unroll
    for (int i = 0; i < 4; i++) {
      int f = t + i * 128;               // 512 f4 = 32n x 16 f4
      int r = f >> 4, c4 = f & 15;
      *(float4*)&Bs[r][c4 * 4] = *(const float4*)&vals[(long)(n0 + r) * EE + h * 64 + c4 * 4];
    }
    #pragma unroll
    for (int i = 0; i < 8; i++) {
      int idx = t + i * 128;             // 1024 groups = 32n x 32 q-quads
      int n = idx >> 5, qg = idx & 31;
      float bm = bmu[n0 + n], bs = bsg[n0 + n];
      float bs2 = bs * bs;
      float4 m4 = *(const float4*)&mu_s[qg * 4];
      float4 s4 = *(const float4*)&s2_s[qg * 4];
      float4 rr;
      {
        float v0 = s4.x + bs2, d0 = m4.x - bm;
        float v1 = s4.y + bs2, d1 = m4.y - bm;
        float v2 = s4.z + bs2, d2 = m4.z - bm;
        float v3 = s4.w + bs2, d3 = m4.w - bm;
        float r0 = __builtin_amdgcn_rcpf(v0), r1 = __builtin_amdgcn_rcpf(v1);
        float r2 = __builtin_amdgcn_rcpf(v2), r3 = __builtin_amdgcn_rcpf(v3);
        rr.x = __expf(d0 * d0 * r0 * -0.5f) * __builtin_amdgcn_rsqf(v0 * 6.2831853071795865f);
        rr.y = __expf(d1 * d1 * r1 * -0.5f) * __builtin_amdgcn_rsqf(v1 * 6.2831853071795865f);
        rr.z = __expf(d2 * d2 * r2 * -0.5f) * __builtin_amdgcn_rsqf(v2 * 6.2831853071795865f);
        rr.w = __expf(d3 * d3 * r3 * -0.5f) * __builtin_amdgcn_rsqf(v3 * 6.2831853071795865f);
      }
      *(float4*)&As[n][qg * 4] = rr;
    }
    __syncthreads();
    #pragma unroll
    for (int kk = 0; kk < 32; kk++) {
      float4 a0 = *(const float4*)&As[kk][ty*8];
      float4 a1 = *(const float4*)&As[kk][ty*8+4];
      float4 b0 = *(const float4*)&Bs[kk][tx*8];
      float4 b1 = *(const float4*)&Bs[kk][tx*8+4];
      float ar[8] = {a0.x,a0.y,a0.z,a0.w,a1.x,a1.y,a1.z,a1.w};
      float br[8] = {b0.x,b0.y,b0.z,b0.w,b1.x,b1.y,b1.z,b1.w};
      #pragma unroll
      for (int i = 0; i < 8; i++)
        #pragma unroll
        for (int j = 0; j < 8; j++)
          acc[i][j] += ar[i] * br[j];
    }
    __syncthreads();
  }
  #pragma unroll
  for (int i = 0; i < 8; i++) {
    float4 o0 = make_float4(acc[i][0], acc[i][1], acc[i][2], acc[i][3]);
    float4 o1 = make_float4(acc[i][4], acc[i][5], acc[i][6], acc[i][7]);
    *(float4*)&ctx[(q0 + ty*8 + i) * EE + h * 64 + tx*8    ] = o0;
    *(float4*)&ctx[(q0 + ty*8 + i) * EE + h * 64 + tx*8 + 4] = o1;
  }
}

extern "C" void kernel_launch(void* const* d_in, const int* in_sizes, int n_in,
                              void* d_out, int out_size, void* d_ws, size_t ws_size,
                              hipStream_t stream) {
  const float* k   = (const float*)d_in[0];
  const float* q   = (const float*)d_in[1];
  const float* Wq  = (const float*)d_in[2];
  const float* Wk  = (const float*)d_in[3];
  const float* Wv  = (const float*)d_in[4];
  const float* Wo  = (const float*)d_in[5];
  const float* wmu = (const float*)d_in[6];
  const float* wsg = (const float*)d_in[7];
  const float* Gs  = (const float*)d_in[8];
  const float* bmu = (const float*)d_in[9];
  const float* bsg = (const float*)d_in[10];
  float* out = (float*)d_out;
  char* ws = (char*)d_ws;

  const long sBm = (long)NB * EE;      // 2 MiB
  const long sU  = 8L * EE;
  const long sK  = EE;
  const long sAm = 32L * EE;
  const long sMu = (long)HH * QQ;
  const long sQ  = (long)QQ * EE;      // 8 MiB

  if (ws_size >= (50u << 20)) {
    // ---- tier 1 (round-3 proven layout) ----
    // [0,32) MiB transient: BmP(16) -> valsP(16) -> ctx4(32)
    // [32,40) Bm4 | [40,48) vals4 | [48,50) smalls
    float* BmP   = (float*)(ws + 0);
    float* valsP = (float*)(ws + 0);
    float* ctx4  = (float*)(ws + 0);
    float* Bm4   = (float*)(ws + (32u << 20));
    float* vals4 = (float*)(ws + (40u << 20));
    char*  sm    = ws + (48u << 20);
    float* ump4  = (float*)(sm);                    // 128 KiB
    float* usp4  = (float*)(sm + (128u << 10));     // 128 KiB
    float* kwm4  = (float*)(sm + (256u << 10));     // 16 KiB
    float* kws4  = (float*)(sm + (272u << 10));     // 16 KiB
    float* AmAs4 = (float*)(sm + (288u << 10));     // 512 KiB
    float* muq4  = (float*)(sm + (800u << 10));     // 512 KiB
    float* sg24  = (float*)(sm + (1312u << 10));    // 512 KiB

    // st2: Bm = Gs^T @ k, split-K=2 (256 blocks)
    gemm_tn128<<<dim3(EE/128, NB/128, BB*2), 256, 0, stream>>>(
        Gs, k, BmP, NB, EE, 0L, (long)LL*EE, sBm, 2, LL/2);
    add_pairs<<<dim3(256, 1, BB), 256, 0, stream>>>(Bm4, sBm, BmP, 2*sBm, sBm);
    // st3: vals = Bm @ Wv^T, split-K=2 (256 blocks)
    gemm_nt128<<<dim3(EE/128, NB/128, BB*2), 256, 0, stream>>>(
        Bm4, Wv, valsP, EE, EE, sBm, 0L, sBm, 2, EE/2);
    add_pairs<<<dim3(256, 1, BB), 256, 0, stream>>>(vals4, sBm, valsP, 2*sBm, sBm);
    // collapsed scores chain
    nb_uvec  <<<dim3(EE/256, 8, BB),  256, 0, stream>>>(Bm4, wmu, wsg, ump4, usp4, sBm, sU);
    nb_kw    <<<dim3(EE, 1, BB),      256, 0, stream>>>(Wk, ump4, usp4, kwm4, kws4, sU, sK);
    nb_amas  <<<dim3(EE/256, HH, BB), 256, 0, stream>>>(Wq, kwm4, kws4, AmAs4, sK, sAm);
    nb_musig <<<dim3(QQ, 1, BB),      256, 0, stream>>>(q, AmAs4, muq4, sg24, sQ, sAm, sMu);
    // ctx (1024 blocks) then st7 batched (512 blocks)
    nb_ctx128<<<dim3(QQ/128, HH, BB), 128, 0, stream>>>(
        vals4, muq4, sg24, bmu, bsg, ctx4, sBm, sMu, sQ);
    gemm_nt128<<<dim3(EE/128, QQ/128, BB), 256, 0, stream>>>(
        ctx4, Wo, out, EE, EE, sQ, 0L, sQ, 1, EE);
  } else {
    // ---- tier 2 (ws >= 26 MiB) ----
    float* BmP   = (float*)(ws + 0);
    float* ctxS  = (float*)(ws + 0);
    float* vals4 = (float*)(ws + (16u << 20));
    char*  sm    = ws + (24u << 20);
    float* ump4  = (float*)(sm);
    float* usp4  = (float*)(sm + (128u << 10));
    float* kwm4  = (float*)(sm + (256u << 10));
    float* kws4  = (float*)(sm + (272u << 10));
    float* AmAs4 = (float*)(sm + (288u << 10));
    float* muq4  = (float*)(sm + (800u << 10));
    float* sg24  = (float*)(sm + (1312u << 10));

    gemm_tn128<<<dim3(EE/128, NB/128, BB*2), 256, 0, stream>>>(
        Gs, k, BmP, NB, EE, 0L, (long)LL*EE, sBm, 2, LL/2);
    add_pairs<<<dim3(256, 1, BB), 256, 0, stream>>>(BmP, 2*sBm, BmP, 2*sBm, sBm);
    gemm_nt128<<<dim3(EE/128, NB/128, BB), 256, 0, stream>>>(
        BmP, Wv, vals4, EE, EE, 2*sBm, 0L, sBm, 1, EE);
    nb_uvec  <<<dim3(EE/256, 8, BB),  256, 0, stream>>>(BmP, wmu, wsg, ump4, usp4, 2*sBm, sU);
    nb_kw    <<<dim3(EE, 1, BB),      256, 0, stream>>>(Wk, ump4, usp4, kwm4, kws4, sU, sK);
    nb_amas  <<<dim3(EE/256, HH, BB), 256, 0, stream>>>(Wq, kwm4, kws4, AmAs4, sK, sAm);
    nb_musig <<<dim3(QQ, 1, BB),      256, 0, stream>>>(q, AmAs4, muq4, sg24, sQ, sAm, sMu);
    for (int b = 0; b < BB; b++) {
      nb_ctx128<<<dim3(QQ/128, HH, 1), 128, 0, stream>>>(
          vals4 + (long)b*sBm, muq4 + (long)b*sMu, sg24 + (long)b*sMu,
          bmu, bsg, ctxS, 0L, 0L, 0L);
      gemm_nt64<<<dim3(EE/64, QQ/64, 1), 256, 0, stream>>>(
          ctxS, Wo, out + (long)b*sQ, QQ, EE, EE, 0L, 0L, 0L);
    }
  }
  (void)in_sizes; (void)n_in; (void)out_size;
}

// Round 6
// 625.299 us; speedup vs baseline: 1.3994x; 1.1302x over previous
//
#include <hip/hip_runtime.h>

#define BB 4
#define LL 2048
#define QQ 2048
#define HH 16
#define DD 64
#define EE 1024
#define NB 512

typedef __attribute__((ext_vector_type(8))) short bf16x8;   // 8 bf16 (4 VGPRs)
typedef __attribute__((ext_vector_type(4))) float f32x4;    // MFMA acc

__device__ inline ushort bf16_rne(float f) {
  uint u = __float_as_uint(f);
  return (ushort)((u + 0x7fffu + ((u >> 16) & 1u)) >> 16);
}
__device__ inline float bf16_f(ushort h) { return __uint_as_float((uint)h << 16); }

// pack 8 floats -> hi/lo bf16 uint4s (RNE both levels)
__device__ inline void cvt8_pack(const float* a, uint4& ph, uint4& pl) {
  ushort h[8], l[8];
  #pragma unroll
  for (int j = 0; j < 8; j++) {
    ushort hb = bf16_rne(a[j]);
    float rm = a[j] - bf16_f(hb);
    h[j] = hb; l[j] = bf16_rne(rm);
  }
  ph = make_uint4((uint)h[0] | ((uint)h[1] << 16), (uint)h[2] | ((uint)h[3] << 16),
                  (uint)h[4] | ((uint)h[5] << 16), (uint)h[6] | ((uint)h[7] << 16));
  pl = make_uint4((uint)l[0] | ((uint)l[1] << 16), (uint)l[2] | ((uint)l[3] << 16),
                  (uint)l[4] | ((uint)l[5] << 16), (uint)l[6] | ((uint)l[7] << 16));
}

// ---------- x (fp32, n elems, n%2048==0) -> hi/lo bf16 planes ----------
__global__ __launch_bounds__(256) void cvt_hilo(
    const float* __restrict__ x, ushort* __restrict__ hi, ushort* __restrict__ lo, long n)
{
  long i0 = ((long)blockIdx.x * 256 + threadIdx.x) * 8;
  long stride = (long)gridDim.x * 2048;
  for (long i = i0; i < n; i += stride) {
    float a[8];
    *(float4*)&a[0] = *(const float4*)&x[i];
    *(float4*)&a[4] = *(const float4*)&x[i + 4];
    uint4 ph, pl;
    cvt8_pack(a, ph, pl);
    *(uint4*)&hi[i] = ph;
    *(uint4*)&lo[i] = pl;
  }
}

// ---------- dst[z] = src[2z] + src[2z+1]  (slab pair reduce; in-place safe) ----------
__global__ __launch_bounds__(256) void add_pairs(
    float* __restrict__ dst, long dstStride,
    const float* __restrict__ src, long srcPairStride, long n)
{
  float* d = dst + (long)blockIdx.z * dstStride;
  const float* s0 = src + (long)blockIdx.z * srcPairStride;
  const float* s1 = s0 + n;
  long i0 = ((long)blockIdx.x * 256 + threadIdx.x) * 4;
  long stride = (long)gridDim.x * 1024;
  for (long i = i0; i < n; i += stride) {
    float4 a = *(const float4*)&s0[i];
    float4 b = *(const float4*)&s1[i];
    a.x += b.x; a.y += b.y; a.z += b.z; a.w += b.w;
    *(float4*)&d[i] = a;
  }
}

// ================= 128x128-tile fp32 GEMMs (proven r3/r5 versions) =================

__global__ __launch_bounds__(256) void gemm_nt128(
    const float* __restrict__ A, const float* __restrict__ B, float* __restrict__ C,
    int N, int K, long sA, long sB, long sC, int NS, int Kc)
{
  const int z = blockIdx.z;
  const int b = z / NS, ks = z - b * NS;
  A += (long)b * sA + (long)ks * Kc;
  B += (long)b * sB + (long)ks * Kc;
  C += (long)z * sC;
  __shared__ float As[32][132], Bs[32][132];
  const int t = threadIdx.x;
  const int tx = t & 15, ty = t >> 4;
  const long m0 = (long)blockIdx.y * 128, n0 = (long)blockIdx.x * 128;
  float acc[8][8] = {};
  for (int k0 = 0; k0 < Kc; k0 += 32) {
    #pragma unroll
    for (int i = 0; i < 4; i++) {
      int f = t + i * 256;
      int r = f >> 3, k4 = f & 7;
      float4 va = *(const float4*)&A[(m0 + r) * K + k0 + k4 * 4];
      As[k4*4+0][r] = va.x; As[k4*4+1][r] = va.y; As[k4*4+2][r] = va.z; As[k4*4+3][r] = va.w;
      float4 vb = *(const float4*)&B[(n0 + r) * K + k0 + k4 * 4];
      Bs[k4*4+0][r] = vb.x; Bs[k4*4+1][r] = vb.y; Bs[k4*4+2][r] = vb.z; Bs[k4*4+3][r] = vb.w;
    }
    __syncthreads();
    #pragma unroll
    for (int kk = 0; kk < 32; kk++) {
      float4 a0 = *(const float4*)&As[kk][ty*8];
      float4 a1 = *(const float4*)&As[kk][ty*8+4];
      float4 b0 = *(const float4*)&Bs[kk][tx*8];
      float4 b1 = *(const float4*)&Bs[kk][tx*8+4];
      float ar[8] = {a0.x,a0.y,a0.z,a0.w,a1.x,a1.y,a1.z,a1.w};
      float br[8] = {b0.x,b0.y,b0.z,b0.w,b1.x,b1.y,b1.z,b1.w};
      #pragma unroll
      for (int i = 0; i < 8; i++)
        #pragma unroll
        for (int j = 0; j < 8; j++)
          acc[i][j] += ar[i] * br[j];
    }
    __syncthreads();
  }
  #pragma unroll
  for (int i = 0; i < 8; i++) {
    float4 o0 = make_float4(acc[i][0], acc[i][1], acc[i][2], acc[i][3]);
    float4 o1 = make_float4(acc[i][4], acc[i][5], acc[i][6], acc[i][7]);
    *(float4*)&C[(m0 + ty*8 + i) * N + n0 + tx*8    ] = o0;
    *(float4*)&C[(m0 + ty*8 + i) * N + n0 + tx*8 + 4] = o1;
  }
}

__global__ __launch_bounds__(256) void gemm_tn128(
    const float* __restrict__ A, const float* __restrict__ B, float* __restrict__ C,
    int M, int N, long sA, long sB, long sC, int NS, int Kc)
{
  const int z = blockIdx.z;
  const int b = z / NS, ks = z - b * NS;
  A += (long)b * sA + (long)ks * Kc * M;
  B += (long)b * sB + (long)ks * Kc * N;
  C += (long)z * sC;
  __shared__ float As[32][132], Bs[32][132];
  const int t = threadIdx.x;
  const int tx = t & 15, ty = t >> 4;
  const long m0 = (long)blockIdx.y * 128, n0 = (long)blockIdx.x * 128;
  float acc[8][8] = {};
  for (int k0 = 0; k0 < Kc; k0 += 32) {
    #pragma unroll
    for (int i = 0; i < 4; i++) {
      int f = t + i * 256;
      int r = f >> 5, c4 = f & 31;
      *(float4*)&As[r][c4 * 4] = *(const float4*)&A[(long)(k0 + r) * M + m0 + c4 * 4];
      *(float4*)&Bs[r][c4 * 4] = *(const float4*)&B[(long)(k0 + r) * N + n0 + c4 * 4];
    }
    __syncthreads();
    #pragma unroll
    for (int kk = 0; kk < 32; kk++) {
      float4 a0 = *(const float4*)&As[kk][ty*8];
      float4 a1 = *(const float4*)&As[kk][ty*8+4];
      float4 b0 = *(const float4*)&Bs[kk][tx*8];
      float4 b1 = *(const float4*)&Bs[kk][tx*8+4];
      float ar[8] = {a0.x,a0.y,a0.z,a0.w,a1.x,a1.y,a1.z,a1.w};
      float br[8] = {b0.x,b0.y,b0.z,b0.w,b1.x,b1.y,b1.z,b1.w};
      #pragma unroll
      for (int i = 0; i < 8; i++)
        #pragma unroll
        for (int j = 0; j < 8; j++)
          acc[i][j] += ar[i] * br[j];
    }
    __syncthreads();
  }
  #pragma unroll
  for (int i = 0; i < 8; i++) {
    float4 o0 = make_float4(acc[i][0], acc[i][1], acc[i][2], acc[i][3]);
    float4 o1 = make_float4(acc[i][4], acc[i][5], acc[i][6], acc[i][7]);
    *(float4*)&C[(m0 + ty*8 + i) * N + n0 + tx*8    ] = o0;
    *(float4*)&C[(m0 + ty*8 + i) * N + n0 + tx*8 + 4] = o1;
  }
}

// 64x64/4x4 NT GEMM kept for tier-2 per-batch st7
__global__ __launch_bounds__(256) void gemm_nt64(
    const float* __restrict__ A, const float* __restrict__ B, float* __restrict__ C,
    int M, int N, int K, long sA, long sB, long sC)
{
  A += (long)blockIdx.z * sA; B += (long)blockIdx.z * sB; C += (long)blockIdx.z * sC;
  __shared__ float As[32][68], Bs[32][68];
  const int t = threadIdx.x;
  const int tx = t & 15, ty = t >> 4;
  const int m0 = blockIdx.y * 64, n0 = blockIdx.x * 64;
  float acc[4][4] = {};
  for (int k0 = 0; k0 < K; k0 += 32) {
    #pragma unroll
    for (int i = 0; i < 2; i++) {
      int f = t + i * 256;
      int r = f >> 3, k4 = f & 7;
      float4 va = *(const float4*)&A[(long)(m0 + r) * K + k0 + k4 * 4];
      As[k4*4+0][r] = va.x; As[k4*4+1][r] = va.y; As[k4*4+2][r] = va.z; As[k4*4+3][r] = va.w;
      float4 vb = *(const float4*)&B[(long)(n0 + r) * K + k0 + k4 * 4];
      Bs[k4*4+0][r] = vb.x; Bs[k4*4+1][r] = vb.y; Bs[k4*4+2][r] = vb.z; Bs[k4*4+3][r] = vb.w;
    }
    __syncthreads();
    #pragma unroll
    for (int kk = 0; kk < 32; kk++) {
      float4 a4 = *(const float4*)&As[kk][ty * 4];
      float4 b4 = *(const float4*)&Bs[kk][tx * 4];
      float ar[4] = {a4.x, a4.y, a4.z, a4.w};
      float br[4] = {b4.x, b4.y, b4.z, b4.w};
      #pragma unroll
      for (int i = 0; i < 4; i++)
        #pragma unroll
        for (int j = 0; j < 4; j++)
          acc[i][j] += ar[i] * br[j];
    }
    __syncthreads();
  }
  #pragma unroll
  for (int i = 0; i < 4; i++) {
    float4 o = make_float4(acc[i][0], acc[i][1], acc[i][2], acc[i][3]);
    *(float4*)&C[(long)(m0 + ty*4 + i) * N + n0 + tx*4] = o;
  }
}

// ================= bf16x3 MFMA GEMM: out[m,n] = sum_k A[m,k]*B[n,k] =================
// A given as hi/lo bf16 planes [z][M][K]; B as hi/lo planes [N][K] (shared over z).
// LDS holds tiles in exact 16x16x32 fragment order -> all DS ops linear, conflict-free.
// Fragment layout (guide-verified, m89/m91 family): A: lane = (row&15) + 16*(k>>3),
// elem k&7; B: lane = (col&15) + 16*(k>>3); D: col = lane&15, row = (lane>>4)*4 + reg.
__global__ __launch_bounds__(256) void gemm_nt128_b3(
    const ushort* __restrict__ Ah, const ushort* __restrict__ Al,
    const ushort* __restrict__ Bh, const ushort* __restrict__ Bl,
    float* __restrict__ C, int N, int K, long sA, long sC)
{
  Ah += (long)blockIdx.z * sA; Al += (long)blockIdx.z * sA;
  C  += (long)blockIdx.z * sC;
  // 8 frags per plane, 512 shorts (1 KB) each
  __shared__ ushort AhS[4096], AlS[4096], BhS[4096], BlS[4096];   // 32 KB
  const int t = threadIdx.x;
  const int l = t & 63, w = t >> 6;           // lane, wave
  const long m0 = (long)blockIdx.y * 128, n0 = (long)blockIdx.x * 128;
  const int frA = (w & 1) * 4;                // wave's A frag base (rows)
  const int frB = (w >> 1) * 4;               // wave's B frag base (cols)
  f32x4 acc[4][4] = {};
  for (int k0 = 0; k0 < K; k0 += 32) {
    // ---- stage: 512 (row, k-quad) slots; each thread converts nothing, just moves 16B ----
    #pragma unroll
    for (int p = 0; p < 2; p++) {
      int t2 = t + p * 256;
      int row = t2 >> 2, kq = t2 & 3;
      long goff = (m0 + row) * (long)K + k0 + kq * 8;     // shorts
      long gofB = (n0 + row) * (long)K + k0 + kq * 8;
      int dst = (row >> 4) * 512 + ((row & 15) + 16 * kq) * 8;
      *(uint4*)&AhS[dst] = *(const uint4*)(Ah + goff);
      *(uint4*)&AlS[dst] = *(const uint4*)(Al + goff);
      *(uint4*)&BhS[dst] = *(const uint4*)(Bh + gofB);
      *(uint4*)&BlS[dst] = *(const uint4*)(Bl + gofB);
    }
    __syncthreads();
    // ---- compute: 16 frag pairs x 3 MFMA ----
    bf16x8 ah[4], al[4], bh[4], bl[4];
    #pragma unroll
    for (int i = 0; i < 4; i++) {
      ah[i] = *(const bf16x8*)&AhS[(frA + i) * 512 + l * 8];
      al[i] = *(const bf16x8*)&AlS[(frA + i) * 512 + l * 8];
      bh[i] = *(const bf16x8*)&BhS[(frB + i) * 512 + l * 8];
      bl[i] = *(const bf16x8*)&BlS[(frB + i) * 512 + l * 8];
    }
    #pragma unroll
    for (int i = 0; i < 4; i++)
      #pragma unroll
      for (int j = 0; j < 4; j++) {
        acc[i][j] = __builtin_amdgcn_mfma_f32_16x16x32_bf16(ah[i], bh[j], acc[i][j], 0, 0, 0);
        acc[i][j] = __builtin_amdgcn_mfma_f32_16x16x32_bf16(ah[i], bl[j], acc[i][j], 0, 0, 0);
        acc[i][j] = __builtin_amdgcn_mfma_f32_16x16x32_bf16(al[i], bh[j], acc[i][j], 0, 0, 0);
      }
    __syncthreads();
  }
  // ---- write: D[i,j] lane l reg r -> row 4*(l>>4)+r, col l&15 ----
  const long rbase = m0 + (w & 1) * 64 + (l >> 4) * 4;
  const int  cbase = (int)n0 + (w >> 1) * 64 + (l & 15);
  #pragma unroll
  for (int i = 0; i < 4; i++)
    #pragma unroll
    for (int j = 0; j < 4; j++)
      #pragma unroll
      for (int r = 0; r < 4; r++)
        C[(rbase + i * 16 + r) * N + cbase + j * 16] = acc[i][j][r];
}

// ================= collapsed scores path (unchanged) =================
__global__ __launch_bounds__(256) void nb_uvec(
    const float* __restrict__ Bm, const float* __restrict__ wmu, const float* __restrict__ wsg,
    float* __restrict__ ump, float* __restrict__ usp, long sBm, long sU)
{
  Bm += (long)blockIdx.z * sBm; ump += (long)blockIdx.z * sU; usp += (long)blockIdx.z * sU;
  const int e = blockIdx.x * 256 + threadIdx.x;
  const int c = blockIdx.y;
  float am = 0.f, as = 0.f;
  #pragma unroll 8
  for (int n = c * 64; n < c * 64 + 64; n++) {
    float bv = Bm[(long)n * EE + e];
    am += wmu[n] * bv;
    as += wsg[n] * bv;
  }
  ump[(long)c * EE + e] = am;
  usp[(long)c * EE + e] = as;
}

__global__ __launch_bounds__(256) void nb_kw(
    const float* __restrict__ Wk, const float* __restrict__ ump, const float* __restrict__ usp,
    float* __restrict__ kwm, float* __restrict__ kws, long sU, long sK)
{
  ump += (long)blockIdx.z * sU; usp += (long)blockIdx.z * sU;
  kwm += (long)blockIdx.z * sK; kws += (long)blockIdx.z * sK;
  __shared__ float pm[256], ps[256];
  const int e = blockIdx.x, t = threadIdx.x;
  const float* row = Wk + (long)e * EE;
  float am = 0.f, as = 0.f;
  for (int i = t; i < EE; i += 256) {
    float um = 0.f, us = 0.f;
    #pragma unroll
    for (int c = 0; c < 8; c++) { um += ump[(long)c * EE + i]; us += usp[(long)c * EE + i]; }
    float w = row[i];
    am += w * um;
    as += w * us;
  }
  pm[t] = am; ps[t] = as;
  __syncthreads();
  for (int s = 128; s > 0; s >>= 1) {
    if (t < s) { pm[t] += pm[t + s]; ps[t] += ps[t + s]; }
    __syncthreads();
  }
  if (t == 0) { kwm[e] = pm[0]; kws[e] = ps[0]; }
}

__global__ __launch_bounds__(256) void nb_amas(
    const float* __restrict__ Wq, const float* __restrict__ kwm, const float* __restrict__ kws,
    float* __restrict__ AmAs, long sK, long sAm)
{
  kwm += (long)blockIdx.z * sK; kws += (long)blockIdx.z * sK;
  AmAs += (long)blockIdx.z * sAm;
  __shared__ float km[64], ks[64];
  const int t = threadIdx.x;
  const int h = blockIdx.y;
  const int e = blockIdx.x * 256 + t;
  if (t < 64) { km[t] = kwm[h * 64 + t]; ks[t] = kws[h * 64 + t]; }
  __syncthreads();
  float am = 0.f, as = 0.f;
  #pragma unroll 8
  for (int d = 0; d < 64; d++) {
    float w = Wq[(long)(h * 64 + d) * EE + e];
    am += km[d] * w;
    as += ks[d] * w;
  }
  AmAs[(long)e * 32 + h]      = am;
  AmAs[(long)e * 32 + 16 + h] = as;
}

__global__ __launch_bounds__(256) void nb_musig(
    const float* __restrict__ qb, const float* __restrict__ AmAs,
    float* __restrict__ muq, float* __restrict__ sg2, long sQ, long sAm, long sMu)
{
  qb += (long)blockIdx.z * sQ; AmAs += (long)blockIdx.z * sAm;
  muq += (long)blockIdx.z * sMu; sg2 += (long)blockIdx.z * sMu;
  __shared__ float qs[EE];
  __shared__ float part[8][32];
  const int t = threadIdx.x, qrow = blockIdx.x;
  for (int i = t; i < EE; i += 256) qs[i] = qb[(long)qrow * EE + i];
  __syncthreads();
  const int o = t & 31, ch = t >> 5;
  float acc = 0.f;
  const int e0 = ch * 128;
  #pragma unroll 8
  for (int i = 0; i < 128; i++) {
    int e = e0 + i;
    acc += qs[e] * AmAs[(long)e * 32 + o];
  }
  part[ch][o] = acc;
  __syncthreads();
  if (t < 32) {
    float s = 0.f;
    #pragma unroll
    for (int c = 0; c < 8; c++) s += part[c][o];
    s *= 0.125f;
    if (o < 16) {
      muq[(long)o * QQ + qrow] = 1.f / (1.f + expf(-s));
    } else {
      float sp = (s > 20.f) ? s : log1pf(expf(s));
      sg2[(long)(o - 16) * QQ + qrow] = fmaxf(sp, 1e-4f);
    }
  }
}

// ================= ctx: fp32-out version (tier 2, unchanged) =================
__global__ __launch_bounds__(128) void nb_ctx128(
    const float* __restrict__ vals, const float* __restrict__ muq, const float* __restrict__ sg2,
    const float* __restrict__ bmu,  const float* __restrict__ bsg, float* __restrict__ ctx,
    long sV, long sMu, long sC)
{
  vals += (long)blockIdx.z * sV; ctx += (long)blockIdx.z * sC;
  muq += (long)blockIdx.z * sMu; sg2 += (long)blockIdx.z * sMu;
  __shared__ float As[32][132], Bs[32][68];
  __shared__ __align__(16) float mu_s[128], s2_s[128];
  const int t = threadIdx.x;
  const int tx = t & 7, ty = t >> 3;
  const long q0 = (long)blockIdx.x * 128;
  const int h = blockIdx.y;
  mu_s[t] = muq[(long)h * QQ + q0 + t];
  s2_s[t] = sg2[(long)h * QQ + q0 + t];
  __syncthreads();
  float acc[8][8] = {};
  for (int n0 = 0; n0 < NB; n0 += 32) {
    #pragma unroll
    for (int i = 0; i < 4; i++) {
      int f = t + i * 128;
      int r = f >> 4, c4 = f & 15;
      *(float4*)&Bs[r][c4 * 4] = *(const float4*)&vals[(long)(n0 + r) * EE + h * 64 + c4 * 4];
    }
    #pragma unroll
    for (int i = 0; i < 8; i++) {
      int idx = t + i * 128;
      int n = idx >> 5, qg = idx & 31;
      float bm = bmu[n0 + n], bs = bsg[n0 + n];
      float bs2 = bs * bs;
      float4 m4 = *(const float4*)&mu_s[qg * 4];
      float4 s4 = *(const float4*)&s2_s[qg * 4];
      float4 rr;
      {
        float v0 = s4.x + bs2, d0 = m4.x - bm;
        float v1 = s4.y + bs2, d1 = m4.y - bm;
        float v2 = s4.z + bs2, d2 = m4.z - bm;
        float v3 = s4.w + bs2, d3 = m4.w - bm;
        float r0 = __builtin_amdgcn_rcpf(v0), r1 = __builtin_amdgcn_rcpf(v1);
        float r2 = __builtin_amdgcn_rcpf(v2), r3 = __builtin_amdgcn_rcpf(v3);
        rr.x = __expf(d0 * d0 * r0 * -0.5f) * __builtin_amdgcn_rsqf(v0 * 6.2831853071795865f);
        rr.y = __expf(d1 * d1 * r1 * -0.5f) * __builtin_amdgcn_rsqf(v1 * 6.2831853071795865f);
        rr.z = __expf(d2 * d2 * r2 * -0.5f) * __builtin_amdgcn_rsqf(v2 * 6.2831853071795865f);
        rr.w = __expf(d3 * d3 * r3 * -0.5f) * __builtin_amdgcn_rsqf(v3 * 6.2831853071795865f);
      }
      *(float4*)&As[n][qg * 4] = rr;
    }
    __syncthreads();
    #pragma unroll
    for (int kk = 0; kk < 32; kk++) {
      float4 a0 = *(const float4*)&As[kk][ty*8];
      float4 a1 = *(const float4*)&As[kk][ty*8+4];
      float4 b0 = *(const float4*)&Bs[kk][tx*8];
      float4 b1 = *(const float4*)&Bs[kk][tx*8+4];
      float ar[8] = {a0.x,a0.y,a0.z,a0.w,a1.x,a1.y,a1.z,a1.w};
      float br[8] = {b0.x,b0.y,b0.z,b0.w,b1.x,b1.y,b1.z,b1.w};
      #pragma unroll
      for (int i = 0; i < 8; i++)
        #pragma unroll
        for (int j = 0; j < 8; j++)
          acc[i][j] += ar[i] * br[j];
    }
    __syncthreads();
  }
  #pragma unroll
  for (int i = 0; i < 8; i++) {
    float4 o0 = make_float4(acc[i][0], acc[i][1], acc[i][2], acc[i][3]);
    float4 o1 = make_float4(acc[i][4], acc[i][5], acc[i][6], acc[i][7]);
    *(float4*)&ctx[(q0 + ty*8 + i) * EE + h * 64 + tx*8    ] = o0;
    *(float4*)&ctx[(q0 + ty*8 + i) * EE + h * 64 + tx*8 + 4] = o1;
  }
}

// ================= ctx variant writing bf16 hi/lo planes (tier 1) =================
__global__ __launch_bounds__(128) void nb_ctx128_b3(
    const float* __restrict__ vals, const float* __restrict__ muq, const float* __restrict__ sg2,
    const float* __restrict__ bmu,  const float* __restrict__ bsg,
    ushort* __restrict__ ctxh, ushort* __restrict__ ctxl,
    long sV, long sMu, long sC)
{
  vals += (long)blockIdx.z * sV;
  ctxh += (long)blockIdx.z * sC; ctxl += (long)blockIdx.z * sC;
  muq += (long)blockIdx.z * sMu; sg2 += (long)blockIdx.z * sMu;
  __shared__ float As[32][132], Bs[32][68];
  __shared__ __align__(16) float mu_s[128], s2_s[128];
  const int t = threadIdx.x;
  const int tx = t & 7, ty = t >> 3;
  const long q0 = (long)blockIdx.x * 128;
  const int h = blockIdx.y;
  mu_s[t] = muq[(long)h * QQ + q0 + t];
  s2_s[t] = sg2[(long)h * QQ + q0 + t];
  __syncthreads();
  float acc[8][8] = {};
  for (int n0 = 0; n0 < NB; n0 += 32) {
    #pragma unroll
    for (int i = 0; i < 4; i++) {
      int f = t + i * 128;
      int r = f >> 4, c4 = f & 15;
      *(float4*)&Bs[r][c4 * 4] = *(const float4*)&vals[(long)(n0 + r) * EE + h * 64 + c4 * 4];
    }
    #pragma unroll
    for (int i = 0; i < 8; i++) {
      int idx = t + i * 128;
      int n = idx >> 5, qg = idx & 31;
      float bm = bmu[n0 + n], bs = bsg[n0 + n];
      float bs2 = bs * bs;
      float4 m4 = *(const float4*)&mu_s[qg * 4];
      float4 s4 = *(const float4*)&s2_s[qg * 4];
      float4 rr;
      {
        float v0 = s4.x + bs2, d0 = m4.x - bm;
        float v1 = s4.y + bs2, d1 = m4.y - bm;
        float v2 = s4.z + bs2, d2 = m4.z - bm;
        float v3 = s4.w + bs2, d3 = m4.w - bm;
        float r0 = __builtin_amdgcn_rcpf(v0), r1 = __builtin_amdgcn_rcpf(v1);
        float r2 = __builtin_amdgcn_rcpf(v2), r3 = __builtin_amdgcn_rcpf(v3);
        rr.x = __expf(d0 * d0 * r0 * -0.5f) * __builtin_amdgcn_rsqf(v0 * 6.2831853071795865f);
        rr.y = __expf(d1 * d1 * r1 * -0.5f) * __builtin_amdgcn_rsqf(v1 * 6.2831853071795865f);
        rr.z = __expf(d2 * d2 * r2 * -0.5f) * __builtin_amdgcn_rsqf(v2 * 6.2831853071795865f);
        rr.w = __expf(d3 * d3 * r3 * -0.5f) * __builtin_amdgcn_rsqf(v3 * 6.2831853071795865f);
      }
      *(float4*)&As[n][qg * 4] = rr;
    }
    __syncthreads();
    #pragma unroll
    for (int kk = 0; kk < 32; kk++) {
      float4 a0 = *(const float4*)&As[kk][ty*8];
      float4 a1 = *(const float4*)&As[kk][ty*8+4];
      float4 b0 = *(const float4*)&Bs[kk][tx*8];
      float4 b1 = *(const float4*)&Bs[kk][tx*8+4];
      float ar[8] = {a0.x,a0.y,a0.z,a0.w,a1.x,a1.y,a1.z,a1.w};
      float br[8] = {b0.x,b0.y,b0.z,b0.w,b1.x,b1.y,b1.z,b1.w};
      #pragma unroll
      for (int i = 0; i < 8; i++)
        #pragma unroll
        for (int j = 0; j < 8; j++)
          acc[i][j] += ar[i] * br[j];
    }
    __syncthreads();
  }
  #pragma unroll
  for (int i = 0; i < 8; i++) {
    uint4 ph, pl;
    cvt8_pack(acc[i], ph, pl);
    long off = (q0 + ty*8 + i) * EE + h * 64 + tx*8;
    *(uint4*)&ctxh[off] = ph;
    *(uint4*)&ctxl[off] = pl;
  }
}

extern "C" void kernel_launch(void* const* d_in, const int* in_sizes, int n_in,
                              void* d_out, int out_size, void* d_ws, size_t ws_size,
                              hipStream_t stream) {
  const float* k   = (const float*)d_in[0];
  const float* q   = (const float*)d_in[1];
  const float* Wq  = (const float*)d_in[2];
  const float* Wk  = (const float*)d_in[3];
  const float* Wv  = (const float*)d_in[4];
  const float* Wo  = (const float*)d_in[5];
  const float* wmu = (const float*)d_in[6];
  const float* wsg = (const float*)d_in[7];
  const float* Gs  = (const float*)d_in[8];
  const float* bmu = (const float*)d_in[9];
  const float* bsg = (const float*)d_in[10];
  float* out = (float*)d_out;
  char* ws = (char*)d_ws;

  const long sBm = (long)NB * EE;      // 2 MiB
  const long sU  = 8L * EE;
  const long sK  = EE;
  const long sAm = 32L * EE;
  const long sMu = (long)HH * QQ;
  const long sQ  = (long)QQ * EE;      // 8 MiB fp32

  if (ws_size >= (50u << 20)) {
    // ---- tier 1 ----
    // BmP [0,16) (8 split-K slabs) -> dead after add_pairs(Bm)
    // valsP [16,32) -> dead after add_pairs(vals)
    // ctxh [0,16), ctxl [16,32)  (bf16 planes, producers dead)
    // Bm4 [32,40) -> dead after uvec/st3 ; Woh [32,34) Wol [34,36) written after
    // vals4 [40,48) | smalls [48,50)
    float* BmP   = (float*)(ws + 0);
    float* valsP = (float*)(ws + (16u << 20));
    ushort* ctxh = (ushort*)(ws + 0);
    ushort* ctxl = (ushort*)(ws + (16u << 20));
    float* Bm4   = (float*)(ws + (32u << 20));
    ushort* Woh  = (ushort*)(ws + (32u << 20));
    ushort* Wol  = (ushort*)(ws + (34u << 20));
    float* vals4 = (float*)(ws + (40u << 20));
    char*  sm    = ws + (48u << 20);
    float* ump4  = (float*)(sm);
    float* usp4  = (float*)(sm + (128u << 10));
    float* kwm4  = (float*)(sm + (256u << 10));
    float* kws4  = (float*)(sm + (272u << 10));
    float* AmAs4 = (float*)(sm + (288u << 10));
    float* muq4  = (float*)(sm + (800u << 10));
    float* sg24  = (float*)(sm + (1312u << 10));

    // st2: Bm = Gs^T @ k, split-K=2
    gemm_tn128<<<dim3(EE/128, NB/128, BB*2), 256, 0, stream>>>(
        Gs, k, BmP, NB, EE, 0L, (long)LL*EE, sBm, 2, LL/2);
    add_pairs<<<dim3(256, 1, BB), 256, 0, stream>>>(Bm4, sBm, BmP, 2*sBm, sBm);
    // st3: vals = Bm @ Wv^T, split-K=2
    gemm_nt128<<<dim3(EE/128, NB/128, BB*2), 256, 0, stream>>>(
        Bm4, Wv, valsP, EE, EE, sBm, 0L, sBm, 2, EE/2);
    add_pairs<<<dim3(256, 1, BB), 256, 0, stream>>>(vals4, sBm, valsP, 2*sBm, sBm);
    // collapsed scores chain
    nb_uvec  <<<dim3(EE/256, 8, BB),  256, 0, stream>>>(Bm4, wmu, wsg, ump4, usp4, sBm, sU);
    nb_kw    <<<dim3(EE, 1, BB),      256, 0, stream>>>(Wk, ump4, usp4, kwm4, kws4, sU, sK);
    nb_amas  <<<dim3(EE/256, HH, BB), 256, 0, stream>>>(Wq, kwm4, kws4, AmAs4, sK, sAm);
    nb_musig <<<dim3(QQ, 1, BB),      256, 0, stream>>>(q, AmAs4, muq4, sg24, sQ, sAm, sMu);
    // ctx -> bf16 hi/lo planes (BmP/valsP dead)
    nb_ctx128_b3<<<dim3(QQ/128, HH, BB), 128, 0, stream>>>(
        vals4, muq4, sg24, bmu, bsg, ctxh, ctxl, sBm, sMu, sQ);
    // Wo -> hi/lo (Bm4 dead)
    cvt_hilo<<<dim3(256), 256, 0, stream>>>(Wo, Woh, Wol, (long)EE * EE);
    // st7: out = ctx @ Wo^T via bf16x3 MFMA
    gemm_nt128_b3<<<dim3(EE/128, QQ/128, BB), 256, 0, stream>>>(
        ctxh, ctxl, Woh, Wol, out, EE, EE, sQ, sQ);
  } else {
    // ---- tier 2 (ws >= 26 MiB, all-fp32 proven path) ----
    float* BmP   = (float*)(ws + 0);
    float* ctxS  = (float*)(ws + 0);
    float* vals4 = (float*)(ws + (16u << 20));
    char*  sm    = ws + (24u << 20);
    float* ump4  = (float*)(sm);
    float* usp4  = (float*)(sm + (128u << 10));
    float* kwm4  = (float*)(sm + (256u << 10));
    float* kws4  = (float*)(sm + (272u << 10));
    float* AmAs4 = (float*)(sm + (288u << 10));
    float* muq4  = (float*)(sm + (800u << 10));
    float* sg24  = (float*)(sm + (1312u << 10));

    gemm_tn128<<<dim3(EE/128, NB/128, BB*2), 256, 0, stream>>>(
        Gs, k, BmP, NB, EE, 0L, (long)LL*EE, sBm, 2, LL/2);
    add_pairs<<<dim3(256, 1, BB), 256, 0, stream>>>(BmP, 2*sBm, BmP, 2*sBm, sBm);
    gemm_nt128<<<dim3(EE/128, NB/128, BB), 256, 0, stream>>>(
        BmP, Wv, vals4, EE, EE, 2*sBm, 0L, sBm, 1, EE);
    nb_uvec  <<<dim3(EE/256, 8, BB),  256, 0, stream>>>(BmP, wmu, wsg, ump4, usp4, 2*sBm, sU);
    nb_kw    <<<dim3(EE, 1, BB),      256, 0, stream>>>(Wk, ump4, usp4, kwm4, kws4, sU, sK);
    nb_amas  <<<dim3(EE/256, HH, BB), 256, 0, stream>>>(Wq, kwm4, kws4, AmAs4, sK, sAm);
    nb_musig <<<dim3(QQ, 1, BB),      256, 0, stream>>>(q, AmAs4, muq4, sg24, sQ, sAm, sMu);
    for (int b = 0; b < BB; b++) {
      nb_ctx128<<<dim3(QQ/128, HH, 1), 128, 0, stream>>>(
          vals4 + (long)b*sBm, muq4 + (long)b*sMu, sg24 + (long)b*sMu,
          bmu, bsg, ctxS, 0L, 0L, 0L);
      gemm_nt64<<<dim3(EE/64, QQ/64, 1), 256, 0, stream>>>(
          ctxS, Wo, out + (long)b*sQ, QQ, EE, EE, 0L, 0L, 0L);
    }
  }
  (void)in_sizes; (void)n_in; (void)out_size;
}

// Round 7
// 492.789 us; speedup vs baseline: 1.7757x; 1.2689x over previous
//
#include <hip/hip_runtime.h>

#define BB 4
#define LL 2048
#define QQ 2048
#define HH 16
#define DD 64
#define EE 1024
#define NB 512

typedef __attribute__((ext_vector_type(8))) short bf16x8;   // 8 bf16 (4 VGPRs)
typedef __attribute__((ext_vector_type(4))) float f32x4;    // MFMA acc

__device__ inline ushort bf16_rne(float f) {
  uint u = __float_as_uint(f);
  return (ushort)((u + 0x7fffu + ((u >> 16) & 1u)) >> 16);
}
__device__ inline float bf16_f(ushort h) { return __uint_as_float((uint)h << 16); }
__device__ inline void hilo(float x, ushort& h, ushort& l) {
  h = bf16_rne(x);
  l = bf16_rne(x - bf16_f(h));
}

// pack 8 floats -> hi/lo bf16 uint4s
__device__ inline void cvt8_pack(const float* a, uint4& ph, uint4& pl) {
  ushort h[8], l[8];
  #pragma unroll
  for (int j = 0; j < 8; j++) hilo(a[j], h[j], l[j]);
  ph = make_uint4((uint)h[0] | ((uint)h[1] << 16), (uint)h[2] | ((uint)h[3] << 16),
                  (uint)h[4] | ((uint)h[5] << 16), (uint)h[6] | ((uint)h[7] << 16));
  pl = make_uint4((uint)l[0] | ((uint)l[1] << 16), (uint)l[2] | ((uint)l[3] << 16),
                  (uint)l[4] | ((uint)l[5] << 16), (uint)l[6] | ((uint)l[7] << 16));
}

// ---------- x (fp32, n elems, n%2048==0) -> hi/lo bf16 planes ----------
__global__ __launch_bounds__(256) void cvt_hilo(
    const float* __restrict__ x, ushort* __restrict__ hi, ushort* __restrict__ lo, long n)
{
  long i0 = ((long)blockIdx.x * 256 + threadIdx.x) * 8;
  long stride = (long)gridDim.x * 2048;
  for (long i = i0; i < n; i += stride) {
    float a[8];
    *(float4*)&a[0] = *(const float4*)&x[i];
    *(float4*)&a[4] = *(const float4*)&x[i + 4];
    uint4 ph, pl;
    cvt8_pack(a, ph, pl);
    *(uint4*)&hi[i] = ph;
    *(uint4*)&lo[i] = pl;
  }
}

// ---------- dst[z] = src[2z] + src[2z+1] ----------
__global__ __launch_bounds__(256) void add_pairs(
    float* __restrict__ dst, long dstStride,
    const float* __restrict__ src, long srcPairStride, long n)
{
  float* d = dst + (long)blockIdx.z * dstStride;
  const float* s0 = src + (long)blockIdx.z * srcPairStride;
  const float* s1 = s0 + n;
  long i0 = ((long)blockIdx.x * 256 + threadIdx.x) * 4;
  long stride = (long)gridDim.x * 1024;
  for (long i = i0; i < n; i += stride) {
    float4 a = *(const float4*)&s0[i];
    float4 b = *(const float4*)&s1[i];
    a.x += b.x; a.y += b.y; a.z += b.z; a.w += b.w;
    *(float4*)&d[i] = a;
  }
}

// ================= fp32 128x128 GEMMs (st2 + tier-2) =================

__global__ __launch_bounds__(256) void gemm_nt128(
    const float* __restrict__ A, const float* __restrict__ B, float* __restrict__ C,
    int N, int K, long sA, long sB, long sC, int NS, int Kc)
{
  const int z = blockIdx.z;
  const int b = z / NS, ks = z - b * NS;
  A += (long)b * sA + (long)ks * Kc;
  B += (long)b * sB + (long)ks * Kc;
  C += (long)z * sC;
  __shared__ float As[32][132], Bs[32][132];
  const int t = threadIdx.x;
  const int tx = t & 15, ty = t >> 4;
  const long m0 = (long)blockIdx.y * 128, n0 = (long)blockIdx.x * 128;
  float acc[8][8] = {};
  for (int k0 = 0; k0 < Kc; k0 += 32) {
    #pragma unroll
    for (int i = 0; i < 4; i++) {
      int f = t + i * 256;
      int r = f >> 3, k4 = f & 7;
      float4 va = *(const float4*)&A[(m0 + r) * K + k0 + k4 * 4];
      As[k4*4+0][r] = va.x; As[k4*4+1][r] = va.y; As[k4*4+2][r] = va.z; As[k4*4+3][r] = va.w;
      float4 vb = *(const float4*)&B[(n0 + r) * K + k0 + k4 * 4];
      Bs[k4*4+0][r] = vb.x; Bs[k4*4+1][r] = vb.y; Bs[k4*4+2][r] = vb.z; Bs[k4*4+3][r] = vb.w;
    }
    __syncthreads();
    #pragma unroll
    for (int kk = 0; kk < 32; kk++) {
      float4 a0 = *(const float4*)&As[kk][ty*8];
      float4 a1 = *(const float4*)&As[kk][ty*8+4];
      float4 b0 = *(const float4*)&Bs[kk][tx*8];
      float4 b1 = *(const float4*)&Bs[kk][tx*8+4];
      float ar[8] = {a0.x,a0.y,a0.z,a0.w,a1.x,a1.y,a1.z,a1.w};
      float br[8] = {b0.x,b0.y,b0.z,b0.w,b1.x,b1.y,b1.z,b1.w};
      #pragma unroll
      for (int i = 0; i < 8; i++)
        #pragma unroll
        for (int j = 0; j < 8; j++)
          acc[i][j] += ar[i] * br[j];
    }
    __syncthreads();
  }
  #pragma unroll
  for (int i = 0; i < 8; i++) {
    float4 o0 = make_float4(acc[i][0], acc[i][1], acc[i][2], acc[i][3]);
    float4 o1 = make_float4(acc[i][4], acc[i][5], acc[i][6], acc[i][7]);
    *(float4*)&C[(m0 + ty*8 + i) * N + n0 + tx*8    ] = o0;
    *(float4*)&C[(m0 + ty*8 + i) * N + n0 + tx*8 + 4] = o1;
  }
}

__global__ __launch_bounds__(256) void gemm_tn128(
    const float* __restrict__ A, const float* __restrict__ B, float* __restrict__ C,
    int M, int N, long sA, long sB, long sC, int NS, int Kc)
{
  const int z = blockIdx.z;
  const int b = z / NS, ks = z - b * NS;
  A += (long)b * sA + (long)ks * Kc * M;
  B += (long)b * sB + (long)ks * Kc * N;
  C += (long)z * sC;
  __shared__ float As[32][132], Bs[32][132];
  const int t = threadIdx.x;
  const int tx = t & 15, ty = t >> 4;
  const long m0 = (long)blockIdx.y * 128, n0 = (long)blockIdx.x * 128;
  float acc[8][8] = {};
  for (int k0 = 0; k0 < Kc; k0 += 32) {
    #pragma unroll
    for (int i = 0; i < 4; i++) {
      int f = t + i * 256;
      int r = f >> 5, c4 = f & 31;
      *(float4*)&As[r][c4 * 4] = *(const float4*)&A[(long)(k0 + r) * M + m0 + c4 * 4];
      *(float4*)&Bs[r][c4 * 4] = *(const float4*)&B[(long)(k0 + r) * N + n0 + c4 * 4];
    }
    __syncthreads();
    #pragma unroll
    for (int kk = 0; kk < 32; kk++) {
      float4 a0 = *(const float4*)&As[kk][ty*8];
      float4 a1 = *(const float4*)&As[kk][ty*8+4];
      float4 b0 = *(const float4*)&Bs[kk][tx*8];
      float4 b1 = *(const float4*)&Bs[kk][tx*8+4];
      float ar[8] = {a0.x,a0.y,a0.z,a0.w,a1.x,a1.y,a1.z,a1.w};
      float br[8] = {b0.x,b0.y,b0.z,b0.w,b1.x,b1.y,b1.z,b1.w};
      #pragma unroll
      for (int i = 0; i < 8; i++)
        #pragma unroll
        for (int j = 0; j < 8; j++)
          acc[i][j] += ar[i] * br[j];
    }
    __syncthreads();
  }
  #pragma unroll
  for (int i = 0; i < 8; i++) {
    float4 o0 = make_float4(acc[i][0], acc[i][1], acc[i][2], acc[i][3]);
    float4 o1 = make_float4(acc[i][4], acc[i][5], acc[i][6], acc[i][7]);
    *(float4*)&C[(m0 + ty*8 + i) * N + n0 + tx*8    ] = o0;
    *(float4*)&C[(m0 + ty*8 + i) * N + n0 + tx*8 + 4] = o1;
  }
}

// tier-2 64x64 NT
__global__ __launch_bounds__(256) void gemm_nt64(
    const float* __restrict__ A, const float* __restrict__ B, float* __restrict__ C,
    int M, int N, int K, long sA, long sB, long sC)
{
  A += (long)blockIdx.z * sA; B += (long)blockIdx.z * sB; C += (long)blockIdx.z * sC;
  __shared__ float As[32][68], Bs[32][68];
  const int t = threadIdx.x;
  const int tx = t & 15, ty = t >> 4;
  const int m0 = blockIdx.y * 64, n0 = blockIdx.x * 64;
  float acc[4][4] = {};
  for (int k0 = 0; k0 < K; k0 += 32) {
    #pragma unroll
    for (int i = 0; i < 2; i++) {
      int f = t + i * 256;
      int r = f >> 3, k4 = f & 7;
      float4 va = *(const float4*)&A[(long)(m0 + r) * K + k0 + k4 * 4];
      As[k4*4+0][r] = va.x; As[k4*4+1][r] = va.y; As[k4*4+2][r] = va.z; As[k4*4+3][r] = va.w;
      float4 vb = *(const float4*)&B[(long)(n0 + r) * K + k0 + k4 * 4];
      Bs[k4*4+0][r] = vb.x; Bs[k4*4+1][r] = vb.y; Bs[k4*4+2][r] = vb.z; Bs[k4*4+3][r] = vb.w;
    }
    __syncthreads();
    #pragma unroll
    for (int kk = 0; kk < 32; kk++) {
      float4 a4 = *(const float4*)&As[kk][ty * 4];
      float4 b4 = *(const float4*)&Bs[kk][tx * 4];
      float ar[4] = {a4.x, a4.y, a4.z, a4.w};
      float br[4] = {b4.x, b4.y, b4.z, b4.w};
      #pragma unroll
      for (int i = 0; i < 4; i++)
        #pragma unroll
        for (int j = 0; j < 4; j++)
          acc[i][j] += ar[i] * br[j];
    }
    __syncthreads();
  }
  #pragma unroll
  for (int i = 0; i < 4; i++) {
    float4 o = make_float4(acc[i][0], acc[i][1], acc[i][2], acc[i][3]);
    *(float4*)&C[(long)(m0 + ty*4 + i) * N + n0 + tx*4] = o;
  }
}

// ================= bf16x3 MFMA NT GEMM (validated r6) + split-K =================
// Fragment convention (HW-validated r6): A: lane=(row&15)+16*(k>>3), elem=k&7;
// B: lane=(col&15)+16*(k>>3); D: col=lane&15, row=(lane>>4)*4+reg.
__global__ __launch_bounds__(256) void gemm_nt128_b3(
    const ushort* __restrict__ Ah, const ushort* __restrict__ Al,
    const ushort* __restrict__ Bh, const ushort* __restrict__ Bl,
    float* __restrict__ C, int N, int K, long sA, long sC, int NS, int Kc)
{
  const int z = blockIdx.z;
  const int zb = z / NS, ks = z - zb * NS;
  Ah += (long)zb * sA + (long)ks * Kc;
  Al += (long)zb * sA + (long)ks * Kc;
  Bh += (long)ks * Kc;
  Bl += (long)ks * Kc;
  C  += (long)z * sC;
  __shared__ ushort AhS[4096], AlS[4096], BhS[4096], BlS[4096];   // 32 KB
  const int t = threadIdx.x;
  const int l = t & 63, w = t >> 6;
  const long m0 = (long)blockIdx.y * 128, n0 = (long)blockIdx.x * 128;
  const int frA = (w & 1) * 4;
  const int frB = (w >> 1) * 4;
  f32x4 acc[4][4] = {};
  for (int k0 = 0; k0 < Kc; k0 += 32) {
    #pragma unroll
    for (int p = 0; p < 2; p++) {
      int t2 = t + p * 256;
      int row = t2 >> 2, kq = t2 & 3;
      long goff = (m0 + row) * (long)K + k0 + kq * 8;
      long gofB = (n0 + row) * (long)K + k0 + kq * 8;
      int dst = (row >> 4) * 512 + ((row & 15) + 16 * kq) * 8;
      *(uint4*)&AhS[dst] = *(const uint4*)(Ah + goff);
      *(uint4*)&AlS[dst] = *(const uint4*)(Al + goff);
      *(uint4*)&BhS[dst] = *(const uint4*)(Bh + gofB);
      *(uint4*)&BlS[dst] = *(const uint4*)(Bl + gofB);
    }
    __syncthreads();
    bf16x8 ah[4], al[4], bh[4], bl[4];
    #pragma unroll
    for (int i = 0; i < 4; i++) {
      ah[i] = *(const bf16x8*)&AhS[(frA + i) * 512 + l * 8];
      al[i] = *(const bf16x8*)&AlS[(frA + i) * 512 + l * 8];
      bh[i] = *(const bf16x8*)&BhS[(frB + i) * 512 + l * 8];
      bl[i] = *(const bf16x8*)&BlS[(frB + i) * 512 + l * 8];
    }
    #pragma unroll
    for (int i = 0; i < 4; i++)
      #pragma unroll
      for (int j = 0; j < 4; j++) {
        acc[i][j] = __builtin_amdgcn_mfma_f32_16x16x32_bf16(ah[i], bh[j], acc[i][j], 0, 0, 0);
        acc[i][j] = __builtin_amdgcn_mfma_f32_16x16x32_bf16(ah[i], bl[j], acc[i][j], 0, 0, 0);
        acc[i][j] = __builtin_amdgcn_mfma_f32_16x16x32_bf16(al[i], bh[j], acc[i][j], 0, 0, 0);
      }
    __syncthreads();
  }
  const long rbase = m0 + (w & 1) * 64 + (l >> 4) * 4;
  const int  cbase = (int)n0 + (w >> 1) * 64 + (l & 15);
  #pragma unroll
  for (int i = 0; i < 4; i++)
    #pragma unroll
    for (int j = 0; j < 4; j++)
      #pragma unroll
      for (int r = 0; r < 4; r++)
        C[(rbase + i * 16 + r) * N + cbase + j * 16] = acc[i][j][r];
}

// ================= valsT: fold split-K pair + transpose + hilo, frag-ordered ========
// out layout per (b,h): [chunk c:16][frag f:4][lane l:64][elem e:8] shorts,
// value = vals[b][n= c*32 + (l>>4)*8 + e][h*64 + f*16 + (l&15)]
__global__ __launch_bounds__(256) void cvt_valsT(
    const float* __restrict__ valsP, ushort* __restrict__ vTh, ushort* __restrict__ vTl,
    long slabStride)
{
  const int c = blockIdx.x, h = blockIdx.y, b = blockIdx.z;
  const int t = threadIdx.x;
  __shared__ float tile[32][68];
  const float* s0 = valsP + (long)(2 * b) * slabStride;
  const float* s1 = s0 + slabStride;
  // stage 32n x 64d (pair-folded), coalesced
  {
    int r = t >> 3, c8 = (t & 7) * 8;
    long g = (long)(c * 32 + r) * EE + h * 64 + c8;
    float4 a0 = *(const float4*)&s0[g];     float4 b0 = *(const float4*)&s1[g];
    float4 a1 = *(const float4*)&s0[g + 4]; float4 b1 = *(const float4*)&s1[g + 4];
    a0.x += b0.x; a0.y += b0.y; a0.z += b0.z; a0.w += b0.w;
    a1.x += b1.x; a1.y += b1.y; a1.z += b1.z; a1.w += b1.w;
    *(float4*)&tile[r][c8] = a0;
    *(float4*)&tile[r][c8 + 4] = a1;
  }
  __syncthreads();
  // emit frag-ordered hilo: slot = t; f=t>>6, l=t&63
  const int f = t >> 6, l = t & 63;
  const int d = f * 16 + (l & 15), kq = l >> 4;
  float a[8];
  #pragma unroll
  for (int e = 0; e < 8; e++) a[e] = tile[kq * 8 + e][d];
  uint4 ph, pl;
  cvt8_pack(a, ph, pl);
  long obase = (((long)(b * HH + h) * 16 + c) * 2048) + (long)t * 8;
  *(uint4*)&vTh[obase] = ph;
  *(uint4*)&vTl[obase] = pl;
}

// ================= ctx via MFMA: r generated into LDS in A-frag order ================
// block: 128 q x 64 d for one (h,b). 4 waves: wm=w&1 (q-half), wn=w>>1 (d-half 32).
__global__ __launch_bounds__(256) void nb_ctx_mf(
    const ushort* __restrict__ vTh, const ushort* __restrict__ vTl,
    const float* __restrict__ muq, const float* __restrict__ sg2,
    const float* __restrict__ bmu, const float* __restrict__ bsg,
    ushort* __restrict__ ctxh, ushort* __restrict__ ctxl,
    long sMu, long sC)
{
  const int h = blockIdx.y, b = blockIdx.z;
  const long q0 = (long)blockIdx.x * 128;
  const int t = threadIdx.x;
  const int l = t & 63, w = t >> 6, wm = w & 1, wn = w >> 1;
  __shared__ ushort AhS[4096], AlS[4096];         // 8 A-frags (128q x 32n)
  __shared__ ushort BhS[2048], BlS[2048];         // 4 B-frags (64d x 32n)
  __shared__ float mu_s[128], s2_s[128], bm_s[NB], bv_s[NB];
  const float* muqb = muq + (long)b * sMu;
  const float* sg2b = sg2 + (long)b * sMu;
  if (t < 128) {
    mu_s[t] = muqb[(long)h * QQ + q0 + t];
    s2_s[t] = sg2b[(long)h * QQ + q0 + t];
  }
  for (int i = t; i < NB; i += 256) {
    bm_s[i] = bmu[i];
    float x = bsg[i];
    bv_s[i] = x * x;
  }
  __syncthreads();
  const ushort* vThb = vTh + ((long)(b * HH + h) * 16) * 2048;
  const ushort* vTlb = vTl + ((long)(b * HH + h) * 16) * 2048;
  f32x4 acc[4][2] = {};
  for (int c = 0; c < 16; c++) {
    // stage B (linear copy, 256 uint4 per plane)
    ((uint4*)BhS)[t] = ((const uint4*)(vThb + c * 2048))[t];
    ((uint4*)BlS)[t] = ((const uint4*)(vTlb + c * 2048))[t];
    // generate A: 512 slots, 2 per thread
    #pragma unroll
    for (int p = 0; p < 2; p++) {
      int s = t + p * 256;
      int lf = s & 63;
      int q = ((s >> 6) << 4) + (lf & 15);
      int nb = c * 32 + (lf >> 4) * 8;
      float m = mu_s[q], s2 = s2_s[q];
      float a[8];
      #pragma unroll
      for (int e = 0; e < 8; e++) {
        float v = s2 + bv_s[nb + e];
        float d = m - bm_s[nb + e];
        float rv = __builtin_amdgcn_rcpf(v);
        a[e] = __expf(d * d * rv * -0.5f) * __builtin_amdgcn_rsqf(v * 6.2831853071795865f);
      }
      uint4 ph, pl;
      cvt8_pack(a, ph, pl);
      *(uint4*)&AhS[s * 8] = ph;
      *(uint4*)&AlS[s * 8] = pl;
    }
    __syncthreads();
    bf16x8 bhf[2], blf[2];
    #pragma unroll
    for (int j = 0; j < 2; j++) {
      bhf[j] = *(const bf16x8*)&BhS[(wn * 2 + j) * 512 + l * 8];
      blf[j] = *(const bf16x8*)&BlS[(wn * 2 + j) * 512 + l * 8];
    }
    #pragma unroll
    for (int i = 0; i < 4; i++) {
      bf16x8 ah = *(const bf16x8*)&AhS[(wm * 4 + i) * 512 + l * 8];
      bf16x8 al = *(const bf16x8*)&AlS[(wm * 4 + i) * 512 + l * 8];
      #pragma unroll
      for (int j = 0; j < 2; j++) {
        acc[i][j] = __builtin_amdgcn_mfma_f32_16x16x32_bf16(ah, bhf[j], acc[i][j], 0, 0, 0);
        acc[i][j] = __builtin_amdgcn_mfma_f32_16x16x32_bf16(ah, blf[j], acc[i][j], 0, 0, 0);
        acc[i][j] = __builtin_amdgcn_mfma_f32_16x16x32_bf16(al, bhf[j], acc[i][j], 0, 0, 0);
      }
    }
    __syncthreads();
  }
  // epilogue: write ctx hi/lo planes row-major [q][e]
  ushort* ch = ctxh + (long)b * sC;
  ushort* cl = ctxl + (long)b * sC;
  const long rbase = q0 + wm * 64 + (l >> 4) * 4;
  const int  cbase = h * 64 + wn * 32 + (l & 15);
  #pragma unroll
  for (int i = 0; i < 4; i++)
    #pragma unroll
    for (int j = 0; j < 2; j++)
      #pragma unroll
      for (int r = 0; r < 4; r++) {
        long off = (rbase + i * 16 + r) * EE + cbase + j * 16;
        ushort hb, lb;
        hilo(acc[i][j][r], hb, lb);
        ch[off] = hb;
        cl[off] = lb;
      }
}

// ================= collapsed scores path (unchanged) =================
__global__ __launch_bounds__(256) void nb_uvec(
    const float* __restrict__ Bm, const float* __restrict__ wmu, const float* __restrict__ wsg,
    float* __restrict__ ump, float* __restrict__ usp, long sBm, long sU)
{
  Bm += (long)blockIdx.z * sBm; ump += (long)blockIdx.z * sU; usp += (long)blockIdx.z * sU;
  const int e = blockIdx.x * 256 + threadIdx.x;
  const int c = blockIdx.y;
  float am = 0.f, as = 0.f;
  #pragma unroll 8
  for (int n = c * 64; n < c * 64 + 64; n++) {
    float bv = Bm[(long)n * EE + e];
    am += wmu[n] * bv;
    as += wsg[n] * bv;
  }
  ump[(long)c * EE + e] = am;
  usp[(long)c * EE + e] = as;
}

__global__ __launch_bounds__(256) void nb_kw(
    const float* __restrict__ Wk, const float* __restrict__ ump, const float* __restrict__ usp,
    float* __restrict__ kwm, float* __restrict__ kws, long sU, long sK)
{
  ump += (long)blockIdx.z * sU; usp += (long)blockIdx.z * sU;
  kwm += (long)blockIdx.z * sK; kws += (long)blockIdx.z * sK;
  __shared__ float pm[256], ps[256];
  const int e = blockIdx.x, t = threadIdx.x;
  const float* row = Wk + (long)e * EE;
  float am = 0.f, as = 0.f;
  for (int i = t; i < EE; i += 256) {
    float um = 0.f, us = 0.f;
    #pragma unroll
    for (int c = 0; c < 8; c++) { um += ump[(long)c * EE + i]; us += usp[(long)c * EE + i]; }
    float w = row[i];
    am += w * um;
    as += w * us;
  }
  pm[t] = am; ps[t] = as;
  __syncthreads();
  for (int s = 128; s > 0; s >>= 1) {
    if (t < s) { pm[t] += pm[t + s]; ps[t] += ps[t + s]; }
    __syncthreads();
  }
  if (t == 0) { kwm[e] = pm[0]; kws[e] = ps[0]; }
}

__global__ __launch_bounds__(256) void nb_amas(
    const float* __restrict__ Wq, const float* __restrict__ kwm, const float* __restrict__ kws,
    float* __restrict__ AmAs, long sK, long sAm)
{
  kwm += (long)blockIdx.z * sK; kws += (long)blockIdx.z * sK;
  AmAs += (long)blockIdx.z * sAm;
  __shared__ float km[64], ks[64];
  const int t = threadIdx.x;
  const int h = blockIdx.y;
  const int e = blockIdx.x * 256 + t;
  if (t < 64) { km[t] = kwm[h * 64 + t]; ks[t] = kws[h * 64 + t]; }
  __syncthreads();
  float am = 0.f, as = 0.f;
  #pragma unroll 8
  for (int d = 0; d < 64; d++) {
    float w = Wq[(long)(h * 64 + d) * EE + e];
    am += km[d] * w;
    as += ks[d] * w;
  }
  AmAs[(long)e * 32 + h]      = am;
  AmAs[(long)e * 32 + 16 + h] = as;
}

__global__ __launch_bounds__(256) void nb_musig(
    const float* __restrict__ qb, const float* __restrict__ AmAs,
    float* __restrict__ muq, float* __restrict__ sg2, long sQ, long sAm, long sMu)
{
  qb += (long)blockIdx.z * sQ; AmAs += (long)blockIdx.z * sAm;
  muq += (long)blockIdx.z * sMu; sg2 += (long)blockIdx.z * sMu;
  __shared__ float qs[EE];
  __shared__ float part[8][32];
  const int t = threadIdx.x, qrow = blockIdx.x;
  for (int i = t; i < EE; i += 256) qs[i] = qb[(long)qrow * EE + i];
  __syncthreads();
  const int o = t & 31, ch = t >> 5;
  float acc = 0.f;
  const int e0 = ch * 128;
  #pragma unroll 8
  for (int i = 0; i < 128; i++) {
    int e = e0 + i;
    acc += qs[e] * AmAs[(long)e * 32 + o];
  }
  part[ch][o] = acc;
  __syncthreads();
  if (t < 32) {
    float s = 0.f;
    #pragma unroll
    for (int c = 0; c < 8; c++) s += part[c][o];
    s *= 0.125f;
    if (o < 16) {
      muq[(long)o * QQ + qrow] = 1.f / (1.f + expf(-s));
    } else {
      float sp = (s > 20.f) ? s : log1pf(expf(s));
      sg2[(long)(o - 16) * QQ + qrow] = fmaxf(sp, 1e-4f);
    }
  }
}

// ================= tier-2 ctx (fp32, proven) =================
__global__ __launch_bounds__(128) void nb_ctx128(
    const float* __restrict__ vals, const float* __restrict__ muq, const float* __restrict__ sg2,
    const float* __restrict__ bmu,  const float* __restrict__ bsg, float* __restrict__ ctx,
    long sV, long sMu, long sC)
{
  vals += (long)blockIdx.z * sV; ctx += (long)blockIdx.z * sC;
  muq += (long)blockIdx.z * sMu; sg2 += (long)blockIdx.z * sMu;
  __shared__ float As[32][132], Bs[32][68];
  __shared__ __align__(16) float mu_s[128], s2_s[128];
  const int t = threadIdx.x;
  const int tx = t & 7, ty = t >> 3;
  const long q0 = (long)blockIdx.x * 128;
  const int h = blockIdx.y;
  mu_s[t] = muq[(long)h * QQ + q0 + t];
  s2_s[t] = sg2[(long)h * QQ + q0 + t];
  __syncthreads();
  float acc[8][8] = {};
  for (int n0 = 0; n0 < NB; n0 += 32) {
    #pragma unroll
    for (int i = 0; i < 4; i++) {
      int f = t + i * 128;
      int r = f >> 4, c4 = f & 15;
      *(float4*)&Bs[r][c4 * 4] = *(const float4*)&vals[(long)(n0 + r) * EE + h * 64 + c4 * 4];
    }
    #pragma unroll
    for (int i = 0; i < 8; i++) {
      int idx = t + i * 128;
      int n = idx >> 5, qg = idx & 31;
      float bm = bmu[n0 + n], bs = bsg[n0 + n];
      float bs2 = bs * bs;
      float4 m4 = *(const float4*)&mu_s[qg * 4];
      float4 s4 = *(const float4*)&s2_s[qg * 4];
      float4 rr;
      {
        float v0 = s4.x + bs2, d0 = m4.x - bm;
        float v1 = s4.y + bs2, d1 = m4.y - bm;
        float v2 = s4.z + bs2, d2 = m4.z - bm;
        float v3 = s4.w + bs2, d3 = m4.w - bm;
        float r0 = __builtin_amdgcn_rcpf(v0), r1 = __builtin_amdgcn_rcpf(v1);
        float r2 = __builtin_amdgcn_rcpf(v2), r3 = __builtin_amdgcn_rcpf(v3);
        rr.x = __expf(d0 * d0 * r0 * -0.5f) * __builtin_amdgcn_rsqf(v0 * 6.2831853071795865f);
        rr.y = __expf(d1 * d1 * r1 * -0.5f) * __builtin_amdgcn_rsqf(v1 * 6.2831853071795865f);
        rr.z = __expf(d2 * d2 * r2 * -0.5f) * __builtin_amdgcn_rsqf(v2 * 6.2831853071795865f);
        rr.w = __expf(d3 * d3 * r3 * -0.5f) * __builtin_amdgcn_rsqf(v3 * 6.2831853071795865f);
      }
      *(float4*)&As[n][qg * 4] = rr;
    }
    __syncthreads();
    #pragma unroll
    for (int kk = 0; kk < 32; kk++) {
      float4 a0 = *(const float4*)&As[kk][ty*8];
      float4 a1 = *(const float4*)&As[kk][ty*8+4];
      float4 b0 = *(const float4*)&Bs[kk][tx*8];
      float4 b1 = *(const float4*)&Bs[kk][tx*8+4];
      float ar[8] = {a0.x,a0.y,a0.z,a0.w,a1.x,a1.y,a1.z,a1.w};
      float br[8] = {b0.x,b0.y,b0.z,b0.w,b1.x,b1.y,b1.z,b1.w};
      #pragma unroll
      for (int i = 0; i < 8; i++)
        #pragma unroll
        for (int j = 0; j < 8; j++)
          acc[i][j] += ar[i] * br[j];
    }
    __syncthreads();
  }
  #pragma unroll
  for (int i = 0; i < 8; i++) {
    float4 o0 = make_float4(acc[i][0], acc[i][1], acc[i][2], acc[i][3]);
    float4 o1 = make_float4(acc[i][4], acc[i][5], acc[i][6], acc[i][7]);
    *(float4*)&ctx[(q0 + ty*8 + i) * EE + h * 64 + tx*8    ] = o0;
    *(float4*)&ctx[(q0 + ty*8 + i) * EE + h * 64 + tx*8 + 4] = o1;
  }
}

extern "C" void kernel_launch(void* const* d_in, const int* in_sizes, int n_in,
                              void* d_out, int out_size, void* d_ws, size_t ws_size,
                              hipStream_t stream) {
  const float* k   = (const float*)d_in[0];
  const float* q   = (const float*)d_in[1];
  const float* Wq  = (const float*)d_in[2];
  const float* Wk  = (const float*)d_in[3];
  const float* Wv  = (const float*)d_in[4];
  const float* Wo  = (const float*)d_in[5];
  const float* wmu = (const float*)d_in[6];
  const float* wsg = (const float*)d_in[7];
  const float* Gs  = (const float*)d_in[8];
  const float* bmu = (const float*)d_in[9];
  const float* bsg = (const float*)d_in[10];
  float* out = (float*)d_out;
  char* ws = (char*)d_ws;

  const long sBm = (long)NB * EE;      // 512K elems
  const long sU  = 8L * EE;
  const long sK  = EE;
  const long sAm = 32L * EE;
  const long sMu = (long)HH * QQ;
  const long sQ  = (long)QQ * EE;

  if (ws_size >= (50u << 20)) {
    // ---- tier 1 (50 MiB) ----
    // [0,16)  BmP (st2 slabs)      -> dead after add_pairs -> ctxh
    // [16,32) valsP (st3 slabs)    -> dead after cvt_valsT -> ctxl
    // [32,40) Bm4                  -> dead after uvec+cvt  -> Wvh[32,34) Wvl[34,36) Woh[36,38) Wol[38,40)
    // [40,48) Bmh[40,44) Bml[44,48)-> dead after st3       -> vTh[40,44) vTl[44,48)
    // [48,50) smalls
    float* BmP   = (float*)(ws + 0);
    float* valsP = (float*)(ws + (16u << 20));
    ushort* ctxh = (ushort*)(ws + 0);
    ushort* ctxl = (ushort*)(ws + (16u << 20));
    float* Bm4   = (float*)(ws + (32u << 20));
    ushort* Wvh  = (ushort*)(ws + (32u << 20));
    ushort* Wvl  = (ushort*)(ws + (34u << 20));
    ushort* Woh  = (ushort*)(ws + (36u << 20));
    ushort* Wol  = (ushort*)(ws + (38u << 20));
    ushort* Bmh  = (ushort*)(ws + (40u << 20));
    ushort* Bml  = (ushort*)(ws + (44u << 20));
    ushort* vTh  = (ushort*)(ws + (40u << 20));
    ushort* vTl  = (ushort*)(ws + (44u << 20));
    char*  sm    = ws + (48u << 20);
    float* ump4  = (float*)(sm);
    float* usp4  = (float*)(sm + (128u << 10));
    float* kwm4  = (float*)(sm + (256u << 10));
    float* kws4  = (float*)(sm + (272u << 10));
    float* AmAs4 = (float*)(sm + (288u << 10));
    float* muq4  = (float*)(sm + (800u << 10));
    float* sg24  = (float*)(sm + (1312u << 10));

    // st2 (fp32): Bm = Gs^T @ k, split-K=2
    gemm_tn128<<<dim3(EE/128, NB/128, BB*2), 256, 0, stream>>>(
        Gs, k, BmP, NB, EE, 0L, (long)LL*EE, sBm, 2, LL/2);
    add_pairs<<<dim3(256, 1, BB), 256, 0, stream>>>(Bm4, sBm, BmP, 2*sBm, sBm);
    // scores chain (uvec is Bm4's last fp32 consumer besides cvt)
    nb_uvec  <<<dim3(EE/256, 8, BB),  256, 0, stream>>>(Bm4, wmu, wsg, ump4, usp4, sBm, sU);
    nb_kw    <<<dim3(EE, 1, BB),      256, 0, stream>>>(Wk, ump4, usp4, kwm4, kws4, sU, sK);
    nb_amas  <<<dim3(EE/256, HH, BB), 256, 0, stream>>>(Wq, kwm4, kws4, AmAs4, sK, sAm);
    nb_musig <<<dim3(QQ, 1, BB),      256, 0, stream>>>(q, AmAs4, muq4, sg24, sQ, sAm, sMu);
    // Bm -> hilo, then Wv -> hilo (overwrites Bm4 region, stream-ordered after cvt(Bm4))
    cvt_hilo<<<dim3(256), 256, 0, stream>>>(Bm4, Bmh, Bml, (long)BB * sBm);
    cvt_hilo<<<dim3(256), 256, 0, stream>>>(Wv, Wvh, Wvl, (long)EE * EE);
    // st3 (MFMA bf16x3): vals slabs = Bm @ Wv^T, split-K=2
    gemm_nt128_b3<<<dim3(EE/128, NB/128, BB*2), 256, 0, stream>>>(
        Bmh, Bml, Wvh, Wvl, valsP, EE, EE, sBm, sBm, 2, EE/2);
    // valsT frag-ordered hilo (folds slab pair; Bmh/Bml dead)
    cvt_valsT<<<dim3(16, HH, BB), 256, 0, stream>>>(valsP, vTh, vTl, sBm);
    cvt_hilo<<<dim3(256), 256, 0, stream>>>(Wo, Woh, Wol, (long)EE * EE);
    // ctx (MFMA bf16x3) -> ctx hilo planes
    nb_ctx_mf<<<dim3(QQ/128, HH, BB), 256, 0, stream>>>(
        vTh, vTl, muq4, sg24, bmu, bsg, ctxh, ctxl, sMu, sQ);
    // st7 (MFMA bf16x3): out = ctx @ Wo^T
    gemm_nt128_b3<<<dim3(EE/128, QQ/128, BB), 256, 0, stream>>>(
        ctxh, ctxl, Woh, Wol, out, EE, EE, sQ, sQ, 1, EE);
  } else {
    // ---- tier 2 (ws >= 26 MiB, all-fp32 proven path) ----
    float* BmP   = (float*)(ws + 0);
    float* ctxS  = (float*)(ws + 0);
    float* vals4 = (float*)(ws + (16u << 20));
    char*  sm    = ws + (24u << 20);
    float* ump4  = (float*)(sm);
    float* usp4  = (float*)(sm + (128u << 10));
    float* kwm4  = (float*)(sm + (256u << 10));
    float* kws4  = (float*)(sm + (272u << 10));
    float* AmAs4 = (float*)(sm + (288u << 10));
    float* muq4  = (float*)(sm + (800u << 10));
    float* sg24  = (float*)(sm + (1312u << 10));

    gemm_tn128<<<dim3(EE/128, NB/128, BB*2), 256, 0, stream>>>(
        Gs, k, BmP, NB, EE, 0L, (long)LL*EE, sBm, 2, LL/2);
    add_pairs<<<dim3(256, 1, BB), 256, 0, stream>>>(BmP, 2*sBm, BmP, 2*sBm, sBm);
    gemm_nt128<<<dim3(EE/128, NB/128, BB), 256, 0, stream>>>(
        BmP, Wv, vals4, EE, EE, 2*sBm, 0L, sBm, 1, EE);
    nb_uvec  <<<dim3(EE/256, 8, BB),  256, 0, stream>>>(BmP, wmu, wsg, ump4, usp4, 2*sBm, sU);
    nb_kw    <<<dim3(EE, 1, BB),      256, 0, stream>>>(Wk, ump4, usp4, kwm4, kws4, sU, sK);
    nb_amas  <<<dim3(EE/256, HH, BB), 256, 0, stream>>>(Wq, kwm4, kws4, AmAs4, sK, sAm);
    nb_musig <<<dim3(QQ, 1, BB),      256, 0, stream>>>(q, AmAs4, muq4, sg24, sQ, sAm, sMu);
    for (int b = 0; b < BB; b++) {
      nb_ctx128<<<dim3(QQ/128, HH, 1), 128, 0, stream>>>(
          vals4 + (long)b*sBm, muq4 + (long)b*sMu, sg24 + (long)b*sMu,
          bmu, bsg, ctxS, 0L, 0L, 0L);
      gemm_nt64<<<dim3(EE/64, QQ/64, 1), 256, 0, stream>>>(
          ctxS, Wo, out + (long)b*sQ, QQ, EE, EE, 0L, 0L, 0L);
    }
  }
  (void)in_sizes; (void)n_in; (void)out_size;
}

// Round 8
// 435.006 us; speedup vs baseline: 2.0116x; 1.1328x over previous
//
#include <hip/hip_runtime.h>

#define BB 4
#define LL 2048
#define QQ 2048
#define HH 16
#define DD 64
#define EE 1024
#define NB 512

typedef __attribute__((ext_vector_type(8))) short bf16x8;   // 8 bf16 (4 VGPRs)
typedef __attribute__((ext_vector_type(4))) float f32x4;    // MFMA acc

__device__ inline ushort bf16_rne(float f) {
  uint u = __float_as_uint(f);
  return (ushort)((u + 0x7fffu + ((u >> 16) & 1u)) >> 16);
}
__device__ inline float bf16_f(ushort h) { return __uint_as_float((uint)h << 16); }
__device__ inline void hilo(float x, ushort& h, ushort& l) {
  h = bf16_rne(x);
  l = bf16_rne(x - bf16_f(h));
}

// pack 8 floats -> hi/lo bf16 uint4s
__device__ inline void cvt8_pack(const float* a, uint4& ph, uint4& pl) {
  ushort h[8], l[8];
  #pragma unroll
  for (int j = 0; j < 8; j++) hilo(a[j], h[j], l[j]);
  ph = make_uint4((uint)h[0] | ((uint)h[1] << 16), (uint)h[2] | ((uint)h[3] << 16),
                  (uint)h[4] | ((uint)h[5] << 16), (uint)h[6] | ((uint)h[7] << 16));
  pl = make_uint4((uint)l[0] | ((uint)l[1] << 16), (uint)l[2] | ((uint)l[3] << 16),
                  (uint)l[4] | ((uint)l[5] << 16), (uint)l[6] | ((uint)l[7] << 16));
}

// ---------- x (fp32, n elems) -> hi/lo bf16 planes (same layout) ----------
__global__ __launch_bounds__(256) void cvt_hilo(
    const float* __restrict__ x, ushort* __restrict__ hi, ushort* __restrict__ lo, long n)
{
  long i0 = ((long)blockIdx.x * 256 + threadIdx.x) * 8;
  long stride = (long)gridDim.x * 2048;
  for (long i = i0; i < n; i += stride) {
    float a[8];
    *(float4*)&a[0] = *(const float4*)&x[i];
    *(float4*)&a[4] = *(const float4*)&x[i + 4];
    uint4 ph, pl;
    cvt8_pack(a, ph, pl);
    *(uint4*)&hi[i] = ph;
    *(uint4*)&lo[i] = pl;
  }
}

// ---------- transpose + hilo: x fp32 [R][C] -> hi/lo [C][R] ----------
// grid(C/32, R/32, z). 32x32 LDS tile; coalesced read & write; <=2-way LDS conflicts.
__global__ __launch_bounds__(256) void cvt_hiloT(
    const float* __restrict__ x, ushort* __restrict__ hiT, ushort* __restrict__ loT,
    int R, int C, long zIn, long zOut)
{
  x += (long)blockIdx.z * zIn; hiT += (long)blockIdx.z * zOut; loT += (long)blockIdx.z * zOut;
  __shared__ float tile[32][33];
  const int t = threadIdx.x;
  const long r0 = (long)blockIdx.y * 32, c0 = (long)blockIdx.x * 32;
  {
    int row = t >> 3, c4 = t & 7;
    float4 v = *(const float4*)&x[(r0 + row) * C + c0 + c4 * 4];
    tile[row][c4*4+0] = v.x; tile[row][c4*4+1] = v.y;
    tile[row][c4*4+2] = v.z; tile[row][c4*4+3] = v.w;
  }
  __syncthreads();
  {
    int col = t >> 3, r4 = t & 7;
    ushort h[4], l[4];
    #pragma unroll
    for (int j = 0; j < 4; j++) hilo(tile[r4 * 4 + j][col], h[j], l[j]);
    uint2 ph = make_uint2((uint)h[0] | ((uint)h[1] << 16), (uint)h[2] | ((uint)h[3] << 16));
    uint2 pl = make_uint2((uint)l[0] | ((uint)l[1] << 16), (uint)l[2] | ((uint)l[3] << 16));
    long o = (c0 + col) * (long)R + r0 + r4 * 4;
    *(uint2*)&hiT[o] = ph;
    *(uint2*)&loT[o] = pl;
  }
}

// ---------- dst[z] = src[2z] + src[2z+1] ----------
__global__ __launch_bounds__(256) void add_pairs(
    float* __restrict__ dst, long dstStride,
    const float* __restrict__ src, long srcPairStride, long n)
{
  float* d = dst + (long)blockIdx.z * dstStride;
  const float* s0 = src + (long)blockIdx.z * srcPairStride;
  const float* s1 = s0 + n;
  long i0 = ((long)blockIdx.x * 256 + threadIdx.x) * 4;
  long stride = (long)gridDim.x * 1024;
  for (long i = i0; i < n; i += stride) {
    float4 a = *(const float4*)&s0[i];
    float4 b = *(const float4*)&s1[i];
    a.x += b.x; a.y += b.y; a.z += b.z; a.w += b.w;
    *(float4*)&d[i] = a;
  }
}

// ================= fp32 GEMMs (tier-2 only) =================

__global__ __launch_bounds__(256) void gemm_nt128(
    const float* __restrict__ A, const float* __restrict__ B, float* __restrict__ C,
    int N, int K, long sA, long sB, long sC, int NS, int Kc)
{
  const int z = blockIdx.z;
  const int b = z / NS, ks = z - b * NS;
  A += (long)b * sA + (long)ks * Kc;
  B += (long)b * sB + (long)ks * Kc;
  C += (long)z * sC;
  __shared__ float As[32][132], Bs[32][132];
  const int t = threadIdx.x;
  const int tx = t & 15, ty = t >> 4;
  const long m0 = (long)blockIdx.y * 128, n0 = (long)blockIdx.x * 128;
  float acc[8][8] = {};
  for (int k0 = 0; k0 < Kc; k0 += 32) {
    #pragma unroll
    for (int i = 0; i < 4; i++) {
      int f = t + i * 256;
      int r = f >> 3, k4 = f & 7;
      float4 va = *(const float4*)&A[(m0 + r) * K + k0 + k4 * 4];
      As[k4*4+0][r] = va.x; As[k4*4+1][r] = va.y; As[k4*4+2][r] = va.z; As[k4*4+3][r] = va.w;
      float4 vb = *(const float4*)&B[(n0 + r) * K + k0 + k4 * 4];
      Bs[k4*4+0][r] = vb.x; Bs[k4*4+1][r] = vb.y; Bs[k4*4+2][r] = vb.z; Bs[k4*4+3][r] = vb.w;
    }
    __syncthreads();
    #pragma unroll
    for (int kk = 0; kk < 32; kk++) {
      float4 a0 = *(const float4*)&As[kk][ty*8];
      float4 a1 = *(const float4*)&As[kk][ty*8+4];
      float4 b0 = *(const float4*)&Bs[kk][tx*8];
      float4 b1 = *(const float4*)&Bs[kk][tx*8+4];
      float ar[8] = {a0.x,a0.y,a0.z,a0.w,a1.x,a1.y,a1.z,a1.w};
      float br[8] = {b0.x,b0.y,b0.z,b0.w,b1.x,b1.y,b1.z,b1.w};
      #pragma unroll
      for (int i = 0; i < 8; i++)
        #pragma unroll
        for (int j = 0; j < 8; j++)
          acc[i][j] += ar[i] * br[j];
    }
    __syncthreads();
  }
  #pragma unroll
  for (int i = 0; i < 8; i++) {
    float4 o0 = make_float4(acc[i][0], acc[i][1], acc[i][2], acc[i][3]);
    float4 o1 = make_float4(acc[i][4], acc[i][5], acc[i][6], acc[i][7]);
    *(float4*)&C[(m0 + ty*8 + i) * N + n0 + tx*8    ] = o0;
    *(float4*)&C[(m0 + ty*8 + i) * N + n0 + tx*8 + 4] = o1;
  }
}

__global__ __launch_bounds__(256) void gemm_tn128(
    const float* __restrict__ A, const float* __restrict__ B, float* __restrict__ C,
    int M, int N, long sA, long sB, long sC, int NS, int Kc)
{
  const int z = blockIdx.z;
  const int b = z / NS, ks = z - b * NS;
  A += (long)b * sA + (long)ks * Kc * M;
  B += (long)b * sB + (long)ks * Kc * N;
  C += (long)z * sC;
  __shared__ float As[32][132], Bs[32][132];
  const int t = threadIdx.x;
  const int tx = t & 15, ty = t >> 4;
  const long m0 = (long)blockIdx.y * 128, n0 = (long)blockIdx.x * 128;
  float acc[8][8] = {};
  for (int k0 = 0; k0 < Kc; k0 += 32) {
    #pragma unroll
    for (int i = 0; i < 4; i++) {
      int f = t + i * 256;
      int r = f >> 5, c4 = f & 31;
      *(float4*)&As[r][c4 * 4] = *(const float4*)&A[(long)(k0 + r) * M + m0 + c4 * 4];
      *(float4*)&Bs[r][c4 * 4] = *(const float4*)&B[(long)(k0 + r) * N + n0 + c4 * 4];
    }
    __syncthreads();
    #pragma unroll
    for (int kk = 0; kk < 32; kk++) {
      float4 a0 = *(const float4*)&As[kk][ty*8];
      float4 a1 = *(const float4*)&As[kk][ty*8+4];
      float4 b0 = *(const float4*)&Bs[kk][tx*8];
      float4 b1 = *(const float4*)&Bs[kk][tx*8+4];
      float ar[8] = {a0.x,a0.y,a0.z,a0.w,a1.x,a1.y,a1.z,a1.w};
      float br[8] = {b0.x,b0.y,b0.z,b0.w,b1.x,b1.y,b1.z,b1.w};
      #pragma unroll
      for (int i = 0; i < 8; i++)
        #pragma unroll
        for (int j = 0; j < 8; j++)
          acc[i][j] += ar[i] * br[j];
    }
    __syncthreads();
  }
  #pragma unroll
  for (int i = 0; i < 8; i++) {
    float4 o0 = make_float4(acc[i][0], acc[i][1], acc[i][2], acc[i][3]);
    float4 o1 = make_float4(acc[i][4], acc[i][5], acc[i][6], acc[i][7]);
    *(float4*)&C[(m0 + ty*8 + i) * N + n0 + tx*8    ] = o0;
    *(float4*)&C[(m0 + ty*8 + i) * N + n0 + tx*8 + 4] = o1;
  }
}

__global__ __launch_bounds__(256) void gemm_nt64(
    const float* __restrict__ A, const float* __restrict__ B, float* __restrict__ C,
    int M, int N, int K, long sA, long sB, long sC)
{
  A += (long)blockIdx.z * sA; B += (long)blockIdx.z * sB; C += (long)blockIdx.z * sC;
  __shared__ float As[32][68], Bs[32][68];
  const int t = threadIdx.x;
  const int tx = t & 15, ty = t >> 4;
  const int m0 = blockIdx.y * 64, n0 = blockIdx.x * 64;
  float acc[4][4] = {};
  for (int k0 = 0; k0 < K; k0 += 32) {
    #pragma unroll
    for (int i = 0; i < 2; i++) {
      int f = t + i * 256;
      int r = f >> 3, k4 = f & 7;
      float4 va = *(const float4*)&A[(long)(m0 + r) * K + k0 + k4 * 4];
      As[k4*4+0][r] = va.x; As[k4*4+1][r] = va.y; As[k4*4+2][r] = va.z; As[k4*4+3][r] = va.w;
      float4 vb = *(const float4*)&B[(long)(n0 + r) * K + k0 + k4 * 4];
      Bs[k4*4+0][r] = vb.x; Bs[k4*4+1][r] = vb.y; Bs[k4*4+2][r] = vb.z; Bs[k4*4+3][r] = vb.w;
    }
    __syncthreads();
    #pragma unroll
    for (int kk = 0; kk < 32; kk++) {
      float4 a4 = *(const float4*)&As[kk][ty * 4];
      float4 b4 = *(const float4*)&Bs[kk][tx * 4];
      float ar[4] = {a4.x, a4.y, a4.z, a4.w};
      float br[4] = {b4.x, b4.y, b4.z, b4.w};
      #pragma unroll
      for (int i = 0; i < 4; i++)
        #pragma unroll
        for (int j = 0; j < 4; j++)
          acc[i][j] += ar[i] * br[j];
    }
    __syncthreads();
  }
  #pragma unroll
  for (int i = 0; i < 4; i++) {
    float4 o = make_float4(acc[i][0], acc[i][1], acc[i][2], acc[i][3]);
    *(float4*)&C[(long)(m0 + ty*4 + i) * N + n0 + tx*4] = o;
  }
}

// ================= bf16x3 MFMA NT GEMMs =================
// Fragment convention (HW-validated r6/r7): A: lane=(row&15)+16*(k>>3), elem=k&7;
// B: lane=(col&15)+16*(k>>3); D: col=lane&15, row=(lane>>4)*4+reg.

// 128x128 tile, optional split-K (z = b*NS+ks), B shared across z
__global__ __launch_bounds__(256) void gemm_nt128_b3(
    const ushort* __restrict__ Ah, const ushort* __restrict__ Al,
    const ushort* __restrict__ Bh, const ushort* __restrict__ Bl,
    float* __restrict__ C, int N, int K, long sA, long sC, int NS, int Kc)
{
  const int z = blockIdx.z;
  const int zb = z / NS, ks = z - zb * NS;
  Ah += (long)zb * sA + (long)ks * Kc;
  Al += (long)zb * sA + (long)ks * Kc;
  Bh += (long)ks * Kc;
  Bl += (long)ks * Kc;
  C  += (long)z * sC;
  __shared__ ushort AhS[4096], AlS[4096], BhS[4096], BlS[4096];
  const int t = threadIdx.x;
  const int l = t & 63, w = t >> 6;
  const long m0 = (long)blockIdx.y * 128, n0 = (long)blockIdx.x * 128;
  const int frA = (w & 1) * 4;
  const int frB = (w >> 1) * 4;
  f32x4 acc[4][4] = {};
  for (int k0 = 0; k0 < Kc; k0 += 32) {
    #pragma unroll
    for (int p = 0; p < 2; p++) {
      int t2 = t + p * 256;
      int row = t2 >> 2, kq = t2 & 3;
      long goff = (m0 + row) * (long)K + k0 + kq * 8;
      long gofB = (n0 + row) * (long)K + k0 + kq * 8;
      int dst = (row >> 4) * 512 + ((row & 15) + 16 * kq) * 8;
      *(uint4*)&AhS[dst] = *(const uint4*)(Ah + goff);
      *(uint4*)&AlS[dst] = *(const uint4*)(Al + goff);
      *(uint4*)&BhS[dst] = *(const uint4*)(Bh + gofB);
      *(uint4*)&BlS[dst] = *(const uint4*)(Bl + gofB);
    }
    __syncthreads();
    bf16x8 ah[4], al[4], bh[4], bl[4];
    #pragma unroll
    for (int i = 0; i < 4; i++) {
      ah[i] = *(const bf16x8*)&AhS[(frA + i) * 512 + l * 8];
      al[i] = *(const bf16x8*)&AlS[(frA + i) * 512 + l * 8];
      bh[i] = *(const bf16x8*)&BhS[(frB + i) * 512 + l * 8];
      bl[i] = *(const bf16x8*)&BlS[(frB + i) * 512 + l * 8];
    }
    #pragma unroll
    for (int i = 0; i < 4; i++)
      #pragma unroll
      for (int j = 0; j < 4; j++) {
        acc[i][j] = __builtin_amdgcn_mfma_f32_16x16x32_bf16(ah[i], bh[j], acc[i][j], 0, 0, 0);
        acc[i][j] = __builtin_amdgcn_mfma_f32_16x16x32_bf16(ah[i], bl[j], acc[i][j], 0, 0, 0);
        acc[i][j] = __builtin_amdgcn_mfma_f32_16x16x32_bf16(al[i], bh[j], acc[i][j], 0, 0, 0);
      }
    __syncthreads();
  }
  const long rbase = m0 + (w & 1) * 64 + (l >> 4) * 4;
  const int  cbase = (int)n0 + (w >> 1) * 64 + (l & 15);
  #pragma unroll
  for (int i = 0; i < 4; i++)
    #pragma unroll
    for (int j = 0; j < 4; j++)
      #pragma unroll
      for (int r = 0; r < 4; r++)
        C[(rbase + i * 16 + r) * N + cbase + j * 16] = acc[i][j][r];
}

// 64x128 tile, no split-K: A shared across z (sA implicit 0), B per-z. Used for st2.
__global__ __launch_bounds__(256) void gemm_nt64x128_b3(
    const ushort* __restrict__ Ah, const ushort* __restrict__ Al,
    const ushort* __restrict__ Bh, const ushort* __restrict__ Bl,
    float* __restrict__ C, int N, int K, long sB, long sC)
{
  const int z = blockIdx.z;
  Bh += (long)z * sB; Bl += (long)z * sB; C += (long)z * sC;
  __shared__ ushort AhS[2048], AlS[2048], BhS[4096], BlS[4096];   // 24 KB
  const int t = threadIdx.x;
  const int l = t & 63, w = t >> 6;
  const long m0 = (long)blockIdx.y * 64, n0 = (long)blockIdx.x * 128;
  const int wm = w & 1, wn = w >> 1;
  f32x4 acc[2][4] = {};
  for (int k0 = 0; k0 < K; k0 += 32) {
    // A: 256 slots = 64 rows x 4 kq
    {
      int row = t >> 2, kq = t & 3;
      long goff = (m0 + row) * (long)K + k0 + kq * 8;
      int dst = (row >> 4) * 512 + ((row & 15) + 16 * kq) * 8;
      *(uint4*)&AhS[dst] = *(const uint4*)(Ah + goff);
      *(uint4*)&AlS[dst] = *(const uint4*)(Al + goff);
    }
    // B: 512 slots = 128 rows x 4 kq
    #pragma unroll
    for (int p = 0; p < 2; p++) {
      int t2 = t + p * 256;
      int row = t2 >> 2, kq = t2 & 3;
      long gofB = (n0 + row) * (long)K + k0 + kq * 8;
      int dst = (row >> 4) * 512 + ((row & 15) + 16 * kq) * 8;
      *(uint4*)&BhS[dst] = *(const uint4*)(Bh + gofB);
      *(uint4*)&BlS[dst] = *(const uint4*)(Bl + gofB);
    }
    __syncthreads();
    bf16x8 ah[2], al[2], bh[4], bl[4];
    #pragma unroll
    for (int i = 0; i < 2; i++) {
      ah[i] = *(const bf16x8*)&AhS[(wm * 2 + i) * 512 + l * 8];
      al[i] = *(const bf16x8*)&AlS[(wm * 2 + i) * 512 + l * 8];
    }
    #pragma unroll
    for (int j = 0; j < 4; j++) {
      bh[j] = *(const bf16x8*)&BhS[(wn * 4 + j) * 512 + l * 8];
      bl[j] = *(const bf16x8*)&BlS[(wn * 4 + j) * 512 + l * 8];
    }
    #pragma unroll
    for (int i = 0; i < 2; i++)
      #pragma unroll
      for (int j = 0; j < 4; j++) {
        acc[i][j] = __builtin_amdgcn_mfma_f32_16x16x32_bf16(ah[i], bh[j], acc[i][j], 0, 0, 0);
        acc[i][j] = __builtin_amdgcn_mfma_f32_16x16x32_bf16(ah[i], bl[j], acc[i][j], 0, 0, 0);
        acc[i][j] = __builtin_amdgcn_mfma_f32_16x16x32_bf16(al[i], bh[j], acc[i][j], 0, 0, 0);
      }
    __syncthreads();
  }
  const long rbase = m0 + wm * 32 + (l >> 4) * 4;
  const int  cbase = (int)n0 + wn * 64 + (l & 15);
  #pragma unroll
  for (int i = 0; i < 2; i++)
    #pragma unroll
    for (int j = 0; j < 4; j++)
      #pragma unroll
      for (int r = 0; r < 4; r++)
        C[(rbase + i * 16 + r) * N + cbase + j * 16] = acc[i][j][r];
}

// ================= valsT: fold split-K pair + transpose + hilo, frag-ordered ========
__global__ __launch_bounds__(256) void cvt_valsT(
    const float* __restrict__ valsP, ushort* __restrict__ vTh, ushort* __restrict__ vTl,
    long slabStride)
{
  const int c = blockIdx.x, h = blockIdx.y, b = blockIdx.z;
  const int t = threadIdx.x;
  __shared__ float tile[32][68];
  const float* s0 = valsP + (long)(2 * b) * slabStride;
  const float* s1 = s0 + slabStride;
  {
    int r = t >> 3, c8 = (t & 7) * 8;
    long g = (long)(c * 32 + r) * EE + h * 64 + c8;
    float4 a0 = *(const float4*)&s0[g];     float4 b0 = *(const float4*)&s1[g];
    float4 a1 = *(const float4*)&s0[g + 4]; float4 b1 = *(const float4*)&s1[g + 4];
    a0.x += b0.x; a0.y += b0.y; a0.z += b0.z; a0.w += b0.w;
    a1.x += b1.x; a1.y += b1.y; a1.z += b1.z; a1.w += b1.w;
    *(float4*)&tile[r][c8] = a0;
    *(float4*)&tile[r][c8 + 4] = a1;
  }
  __syncthreads();
  const int f = t >> 6, l = t & 63;
  const int d = f * 16 + (l & 15), kq = l >> 4;
  float a[8];
  #pragma unroll
  for (int e = 0; e < 8; e++) a[e] = tile[kq * 8 + e][d];
  uint4 ph, pl;
  cvt8_pack(a, ph, pl);
  long obase = (((long)(b * HH + h) * 16 + c) * 2048) + (long)t * 8;
  *(uint4*)&vTh[obase] = ph;
  *(uint4*)&vTl[obase] = pl;
}

// ================= ctx via MFMA: r generated into LDS in A-frag order ================
__global__ __launch_bounds__(256) void nb_ctx_mf(
    const ushort* __restrict__ vTh, const ushort* __restrict__ vTl,
    const float* __restrict__ muq, const float* __restrict__ sg2,
    const float* __restrict__ bmu, const float* __restrict__ bsg,
    ushort* __restrict__ ctxh, ushort* __restrict__ ctxl,
    long sMu, long sC)
{
  const int h = blockIdx.y, b = blockIdx.z;
  const long q0 = (long)blockIdx.x * 128;
  const int t = threadIdx.x;
  const int l = t & 63, w = t >> 6, wm = w & 1, wn = w >> 1;
  __shared__ ushort AhS[4096], AlS[4096];
  __shared__ ushort BhS[2048], BlS[2048];
  __shared__ float mu_s[128], s2_s[128], bm_s[NB], bv_s[NB];
  const float* muqb = muq + (long)b * sMu;
  const float* sg2b = sg2 + (long)b * sMu;
  if (t < 128) {
    mu_s[t] = muqb[(long)h * QQ + q0 + t];
    s2_s[t] = sg2b[(long)h * QQ + q0 + t];
  }
  for (int i = t; i < NB; i += 256) {
    bm_s[i] = bmu[i];
    float x = bsg[i];
    bv_s[i] = x * x;
  }
  __syncthreads();
  const ushort* vThb = vTh + ((long)(b * HH + h) * 16) * 2048;
  const ushort* vTlb = vTl + ((long)(b * HH + h) * 16) * 2048;
  f32x4 acc[4][2] = {};
  for (int c = 0; c < 16; c++) {
    ((uint4*)BhS)[t] = ((const uint4*)(vThb + c * 2048))[t];
    ((uint4*)BlS)[t] = ((const uint4*)(vTlb + c * 2048))[t];
    #pragma unroll
    for (int p = 0; p < 2; p++) {
      int s = t + p * 256;
      int lf = s & 63;
      int q = ((s >> 6) << 4) + (lf & 15);
      int nb = c * 32 + (lf >> 4) * 8;
      float m = mu_s[q], s2 = s2_s[q];
      float a[8];
      #pragma unroll
      for (int e = 0; e < 8; e++) {
        float v = s2 + bv_s[nb + e];
        float d = m - bm_s[nb + e];
        float rv = __builtin_amdgcn_rcpf(v);
        a[e] = __expf(d * d * rv * -0.5f) * __builtin_amdgcn_rsqf(v * 6.2831853071795865f);
      }
      uint4 ph, pl;
      cvt8_pack(a, ph, pl);
      *(uint4*)&AhS[s * 8] = ph;
      *(uint4*)&AlS[s * 8] = pl;
    }
    __syncthreads();
    bf16x8 bhf[2], blf[2];
    #pragma unroll
    for (int j = 0; j < 2; j++) {
      bhf[j] = *(const bf16x8*)&BhS[(wn * 2 + j) * 512 + l * 8];
      blf[j] = *(const bf16x8*)&BlS[(wn * 2 + j) * 512 + l * 8];
    }
    #pragma unroll
    for (int i = 0; i < 4; i++) {
      bf16x8 ah = *(const bf16x8*)&AhS[(wm * 4 + i) * 512 + l * 8];
      bf16x8 al = *(const bf16x8*)&AlS[(wm * 4 + i) * 512 + l * 8];
      #pragma unroll
      for (int j = 0; j < 2; j++) {
        acc[i][j] = __builtin_amdgcn_mfma_f32_16x16x32_bf16(ah, bhf[j], acc[i][j], 0, 0, 0);
        acc[i][j] = __builtin_amdgcn_mfma_f32_16x16x32_bf16(ah, blf[j], acc[i][j], 0, 0, 0);
        acc[i][j] = __builtin_amdgcn_mfma_f32_16x16x32_bf16(al, bhf[j], acc[i][j], 0, 0, 0);
      }
    }
    __syncthreads();
  }
  ushort* ch = ctxh + (long)b * sC;
  ushort* cl = ctxl + (long)b * sC;
  const long rbase = q0 + wm * 64 + (l >> 4) * 4;
  const int  cbase = h * 64 + wn * 32 + (l & 15);
  #pragma unroll
  for (int i = 0; i < 4; i++)
    #pragma unroll
    for (int j = 0; j < 2; j++)
      #pragma unroll
      for (int r = 0; r < 4; r++) {
        long off = (rbase + i * 16 + r) * EE + cbase + j * 16;
        ushort hb, lb;
        hilo(acc[i][j][r], hb, lb);
        ch[off] = hb;
        cl[off] = lb;
      }
}

// ================= collapsed scores path (unchanged) =================
__global__ __launch_bounds__(256) void nb_uvec(
    const float* __restrict__ Bm, const float* __restrict__ wmu, const float* __restrict__ wsg,
    float* __restrict__ ump, float* __restrict__ usp, long sBm, long sU)
{
  Bm += (long)blockIdx.z * sBm; ump += (long)blockIdx.z * sU; usp += (long)blockIdx.z * sU;
  const int e = blockIdx.x * 256 + threadIdx.x;
  const int c = blockIdx.y;
  float am = 0.f, as = 0.f;
  #pragma unroll 8
  for (int n = c * 64; n < c * 64 + 64; n++) {
    float bv = Bm[(long)n * EE + e];
    am += wmu[n] * bv;
    as += wsg[n] * bv;
  }
  ump[(long)c * EE + e] = am;
  usp[(long)c * EE + e] = as;
}

__global__ __launch_bounds__(256) void nb_kw(
    const float* __restrict__ Wk, const float* __restrict__ ump, const float* __restrict__ usp,
    float* __restrict__ kwm, float* __restrict__ kws, long sU, long sK)
{
  ump += (long)blockIdx.z * sU; usp += (long)blockIdx.z * sU;
  kwm += (long)blockIdx.z * sK; kws += (long)blockIdx.z * sK;
  __shared__ float pm[256], ps[256];
  const int e = blockIdx.x, t = threadIdx.x;
  const float* row = Wk + (long)e * EE;
  float am = 0.f, as = 0.f;
  for (int i = t; i < EE; i += 256) {
    float um = 0.f, us = 0.f;
    #pragma unroll
    for (int c = 0; c < 8; c++) { um += ump[(long)c * EE + i]; us += usp[(long)c * EE + i]; }
    float w = row[i];
    am += w * um;
    as += w * us;
  }
  pm[t] = am; ps[t] = as;
  __syncthreads();
  for (int s = 128; s > 0; s >>= 1) {
    if (t < s) { pm[t] += pm[t + s]; ps[t] += ps[t + s]; }
    __syncthreads();
  }
  if (t == 0) { kwm[e] = pm[0]; kws[e] = ps[0]; }
}

__global__ __launch_bounds__(256) void nb_amas(
    const float* __restrict__ Wq, const float* __restrict__ kwm, const float* __restrict__ kws,
    float* __restrict__ AmAs, long sK, long sAm)
{
  kwm += (long)blockIdx.z * sK; kws += (long)blockIdx.z * sK;
  AmAs += (long)blockIdx.z * sAm;
  __shared__ float km[64], ks[64];
  const int t = threadIdx.x;
  const int h = blockIdx.y;
  const int e = blockIdx.x * 256 + t;
  if (t < 64) { km[t] = kwm[h * 64 + t]; ks[t] = kws[h * 64 + t]; }
  __syncthreads();
  float am = 0.f, as = 0.f;
  #pragma unroll 8
  for (int d = 0; d < 64; d++) {
    float w = Wq[(long)(h * 64 + d) * EE + e];
    am += km[d] * w;
    as += ks[d] * w;
  }
  AmAs[(long)e * 32 + h]      = am;
  AmAs[(long)e * 32 + 16 + h] = as;
}

__global__ __launch_bounds__(256) void nb_musig(
    const float* __restrict__ qb, const float* __restrict__ AmAs,
    float* __restrict__ muq, float* __restrict__ sg2, long sQ, long sAm, long sMu)
{
  qb += (long)blockIdx.z * sQ; AmAs += (long)blockIdx.z * sAm;
  muq += (long)blockIdx.z * sMu; sg2 += (long)blockIdx.z * sMu;
  __shared__ float qs[EE];
  __shared__ float part[8][32];
  const int t = threadIdx.x, qrow = blockIdx.x;
  for (int i = t; i < EE; i += 256) qs[i] = qb[(long)qrow * EE + i];
  __syncthreads();
  const int o = t & 31, ch = t >> 5;
  float acc = 0.f;
  const int e0 = ch * 128;
  #pragma unroll 8
  for (int i = 0; i < 128; i++) {
    int e = e0 + i;
    acc += qs[e] * AmAs[(long)e * 32 + o];
  }
  part[ch][o] = acc;
  __syncthreads();
  if (t < 32) {
    float s = 0.f;
    #pragma unroll
    for (int c = 0; c < 8; c++) s += part[c][o];
    s *= 0.125f;
    if (o < 16) {
      muq[(long)o * QQ + qrow] = 1.f / (1.f + expf(-s));
    } else {
      float sp = (s > 20.f) ? s : log1pf(expf(s));
      sg2[(long)(o - 16) * QQ + qrow] = fmaxf(sp, 1e-4f);
    }
  }
}

// ================= tier-2 ctx (fp32, proven) =================
__global__ __launch_bounds__(128) void nb_ctx128(
    const float* __restrict__ vals, const float* __restrict__ muq, const float* __restrict__ sg2,
    const float* __restrict__ bmu,  const float* __restrict__ bsg, float* __restrict__ ctx,
    long sV, long sMu, long sC)
{
  vals += (long)blockIdx.z * sV; ctx += (long)blockIdx.z * sC;
  muq += (long)blockIdx.z * sMu; sg2 += (long)blockIdx.z * sMu;
  __shared__ float As[32][132], Bs[32][68];
  __shared__ __align__(16) float mu_s[128], s2_s[128];
  const int t = threadIdx.x;
  const int tx = t & 7, ty = t >> 3;
  const long q0 = (long)blockIdx.x * 128;
  const int h = blockIdx.y;
  mu_s[t] = muq[(long)h * QQ + q0 + t];
  s2_s[t] = sg2[(long)h * QQ + q0 + t];
  __syncthreads();
  float acc[8][8] = {};
  for (int n0 = 0; n0 < NB; n0 += 32) {
    #pragma unroll
    for (int i = 0; i < 4; i++) {
      int f = t + i * 128;
      int r = f >> 4, c4 = f & 15;
      *(float4*)&Bs[r][c4 * 4] = *(const float4*)&vals[(long)(n0 + r) * EE + h * 64 + c4 * 4];
    }
    #pragma unroll
    for (int i = 0; i < 8; i++) {
      int idx = t + i * 128;
      int n = idx >> 5, qg = idx & 31;
      float bm = bmu[n0 + n], bs = bsg[n0 + n];
      float bs2 = bs * bs;
      float4 m4 = *(const float4*)&mu_s[qg * 4];
      float4 s4 = *(const float4*)&s2_s[qg * 4];
      float4 rr;
      {
        float v0 = s4.x + bs2, d0 = m4.x - bm;
        float v1 = s4.y + bs2, d1 = m4.y - bm;
        float v2 = s4.z + bs2, d2 = m4.z - bm;
        float v3 = s4.w + bs2, d3 = m4.w - bm;
        float r0 = __builtin_amdgcn_rcpf(v0), r1 = __builtin_amdgcn_rcpf(v1);
        float r2 = __builtin_amdgcn_rcpf(v2), r3 = __builtin_amdgcn_rcpf(v3);
        rr.x = __expf(d0 * d0 * r0 * -0.5f) * __builtin_amdgcn_rsqf(v0 * 6.2831853071795865f);
        rr.y = __expf(d1 * d1 * r1 * -0.5f) * __builtin_amdgcn_rsqf(v1 * 6.2831853071795865f);
        rr.z = __expf(d2 * d2 * r2 * -0.5f) * __builtin_amdgcn_rsqf(v2 * 6.2831853071795865f);
        rr.w = __expf(d3 * d3 * r3 * -0.5f) * __builtin_amdgcn_rsqf(v3 * 6.2831853071795865f);
      }
      *(float4*)&As[n][qg * 4] = rr;
    }
    __syncthreads();
    #pragma unroll
    for (int kk = 0; kk < 32; kk++) {
      float4 a0 = *(const float4*)&As[kk][ty*8];
      float4 a1 = *(const float4*)&As[kk][ty*8+4];
      float4 b0 = *(const float4*)&Bs[kk][tx*8];
      float4 b1 = *(const float4*)&Bs[kk][tx*8+4];
      float ar[8] = {a0.x,a0.y,a0.z,a0.w,a1.x,a1.y,a1.z,a1.w};
      float br[8] = {b0.x,b0.y,b0.z,b0.w,b1.x,b1.y,b1.z,b1.w};
      #pragma unroll
      for (int i = 0; i < 8; i++)
        #pragma unroll
        for (int j = 0; j < 8; j++)
          acc[i][j] += ar[i] * br[j];
    }
    __syncthreads();
  }
  #pragma unroll
  for (int i = 0; i < 8; i++) {
    float4 o0 = make_float4(acc[i][0], acc[i][1], acc[i][2], acc[i][3]);
    float4 o1 = make_float4(acc[i][4], acc[i][5], acc[i][6], acc[i][7]);
    *(float4*)&ctx[(q0 + ty*8 + i) * EE + h * 64 + tx*8    ] = o0;
    *(float4*)&ctx[(q0 + ty*8 + i) * EE + h * 64 + tx*8 + 4] = o1;
  }
}

extern "C" void kernel_launch(void* const* d_in, const int* in_sizes, int n_in,
                              void* d_out, int out_size, void* d_ws, size_t ws_size,
                              hipStream_t stream) {
  const float* k   = (const float*)d_in[0];
  const float* q   = (const float*)d_in[1];
  const float* Wq  = (const float*)d_in[2];
  const float* Wk  = (const float*)d_in[3];
  const float* Wv  = (const float*)d_in[4];
  const float* Wo  = (const float*)d_in[5];
  const float* wmu = (const float*)d_in[6];
  const float* wsg = (const float*)d_in[7];
  const float* Gs  = (const float*)d_in[8];
  const float* bmu = (const float*)d_in[9];
  const float* bsg = (const float*)d_in[10];
  float* out = (float*)d_out;
  char* ws = (char*)d_ws;

  const long sBm = (long)NB * EE;
  const long sU  = 8L * EE;
  const long sK  = EE;
  const long sAm = 32L * EE;
  const long sMu = (long)HH * QQ;
  const long sQ  = (long)QQ * EE;

  if (ws_size >= (50u << 20)) {
    // ---- tier 1 (50 MiB), lifetimes verified disjoint ----
    // [0,16)  kTh {S1..st2} -> Bmh[0,4) Bml[4,8) Wvh[8,10) Wvl[10,12) {..st3} -> ctxh {ctx..st7}
    // [16,32) kTl {S1..st2} -> valsP {st3..cvt_valsT} -> ctxl {ctx..st7}
    // [32,36) GsTh/GsTl {S1..st2} -> vTh [32,36) {cvt_valsT..ctx}
    // [36,40) (free)            -> vTl [36,40)
    // [40,48) Bm4 {st2..cvt(Bm4)} -> Woh[40,42) Wol[42,44) {..st7}
    // [48,50) smalls
    ushort* kTh  = (ushort*)(ws + 0);
    ushort* kTl  = (ushort*)(ws + (16u << 20));
    ushort* GsTh = (ushort*)(ws + (32u << 20));
    ushort* GsTl = (ushort*)(ws + (34u << 20));
    float*  Bm4  = (float*)(ws + (40u << 20));
    ushort* Bmh  = (ushort*)(ws + 0);
    ushort* Bml  = (ushort*)(ws + (4u << 20));
    ushort* Wvh  = (ushort*)(ws + (8u << 20));
    ushort* Wvl  = (ushort*)(ws + (10u << 20));
    float*  valsP= (float*)(ws + (16u << 20));
    ushort* vTh  = (ushort*)(ws + (32u << 20));
    ushort* vTl  = (ushort*)(ws + (36u << 20));
    ushort* Woh  = (ushort*)(ws + (40u << 20));
    ushort* Wol  = (ushort*)(ws + (42u << 20));
    ushort* ctxh = (ushort*)(ws + 0);
    ushort* ctxl = (ushort*)(ws + (16u << 20));
    char*  sm    = ws + (48u << 20);
    float* ump4  = (float*)(sm);
    float* usp4  = (float*)(sm + (128u << 10));
    float* kwm4  = (float*)(sm + (256u << 10));
    float* kws4  = (float*)(sm + (272u << 10));
    float* AmAs4 = (float*)(sm + (288u << 10));
    float* muq4  = (float*)(sm + (800u << 10));
    float* sg24  = (float*)(sm + (1312u << 10));

    // S1: transposed hilo operands for st2
    cvt_hiloT<<<dim3(NB/32, LL/32, 1),  256, 0, stream>>>(Gs, GsTh, GsTl, LL, NB, 0L, 0L);
    cvt_hiloT<<<dim3(EE/32, LL/32, BB), 256, 0, stream>>>(k, kTh, kTl, LL, EE,
                                                          (long)LL*EE, (long)LL*EE);
    // st2 (MFMA bf16x3): Bm4[nb][e] = sum_l GsT[nb][l]*kT[e][l]   (256 blocks)
    gemm_nt64x128_b3<<<dim3(EE/128, NB/64, BB), 256, 0, stream>>>(
        GsTh, GsTl, kTh, kTl, Bm4, EE, LL, (long)LL*EE, sBm);
    // scores chain
    nb_uvec  <<<dim3(EE/256, 8, BB),  256, 0, stream>>>(Bm4, wmu, wsg, ump4, usp4, sBm, sU);
    nb_kw    <<<dim3(EE, 1, BB),      256, 0, stream>>>(Wk, ump4, usp4, kwm4, kws4, sU, sK);
    nb_amas  <<<dim3(EE/256, HH, BB), 256, 0, stream>>>(Wq, kwm4, kws4, AmAs4, sK, sAm);
    nb_musig <<<dim3(QQ, 1, BB),      256, 0, stream>>>(q, AmAs4, muq4, sg24, sQ, sAm, sMu);
    // Bm/Wv -> hilo (kT dead)
    cvt_hilo<<<dim3(256), 256, 0, stream>>>(Bm4, Bmh, Bml, (long)BB * sBm);
    cvt_hilo<<<dim3(256), 256, 0, stream>>>(Wv, Wvh, Wvl, (long)EE * EE);
    // st3 (MFMA bf16x3): vals slabs = Bm @ Wv^T, split-K=2
    gemm_nt128_b3<<<dim3(EE/128, NB/128, BB*2), 256, 0, stream>>>(
        Bmh, Bml, Wvh, Wvl, valsP, EE, EE, sBm, sBm, 2, EE/2);
    // valsT frag-ordered hilo (GsT dead)
    cvt_valsT<<<dim3(16, HH, BB), 256, 0, stream>>>(valsP, vTh, vTl, sBm);
    // Wo -> hilo (Bm4 dead after cvt above)
    cvt_hilo<<<dim3(256), 256, 0, stream>>>(Wo, Woh, Wol, (long)EE * EE);
    // ctx (MFMA bf16x3) -> ctx hilo planes (Bmh/Wv/valsP dead)
    nb_ctx_mf<<<dim3(QQ/128, HH, BB), 256, 0, stream>>>(
        vTh, vTl, muq4, sg24, bmu, bsg, ctxh, ctxl, sMu, sQ);
    // st7 (MFMA bf16x3): out = ctx @ Wo^T
    gemm_nt128_b3<<<dim3(EE/128, QQ/128, BB), 256, 0, stream>>>(
        ctxh, ctxl, Woh, Wol, out, EE, EE, sQ, sQ, 1, EE);
  } else {
    // ---- tier 2 (ws >= 26 MiB, all-fp32 proven path) ----
    float* BmP   = (float*)(ws + 0);
    float* ctxS  = (float*)(ws + 0);
    float* vals4 = (float*)(ws + (16u << 20));
    char*  sm    = ws + (24u << 20);
    float* ump4  = (float*)(sm);
    float* usp4  = (float*)(sm + (128u << 10));
    float* kwm4  = (float*)(sm + (256u << 10));
    float* kws4  = (float*)(sm + (272u << 10));
    float* AmAs4 = (float*)(sm + (288u << 10));
    float* muq4  = (float*)(sm + (800u << 10));
    float* sg24  = (float*)(sm + (1312u << 10));

    gemm_tn128<<<dim3(EE/128, NB/128, BB*2), 256, 0, stream>>>(
        Gs, k, BmP, NB, EE, 0L, (long)LL*EE, sBm, 2, LL/2);
    add_pairs<<<dim3(256, 1, BB), 256, 0, stream>>>(BmP, 2*sBm, BmP, 2*sBm, sBm);
    gemm_nt128<<<dim3(EE/128, NB/128, BB), 256, 0, stream>>>(
        BmP, Wv, vals4, EE, EE, 2*sBm, 0L, sBm, 1, EE);
    nb_uvec  <<<dim3(EE/256, 8, BB),  256, 0, stream>>>(BmP, wmu, wsg, ump4, usp4, 2*sBm, sU);
    nb_kw    <<<dim3(EE, 1, BB),      256, 0, stream>>>(Wk, ump4, usp4, kwm4, kws4, sU, sK);
    nb_amas  <<<dim3(EE/256, HH, BB), 256, 0, stream>>>(Wq, kwm4, kws4, AmAs4, sK, sAm);
    nb_musig <<<dim3(QQ, 1, BB),      256, 0, stream>>>(q, AmAs4, muq4, sg24, sQ, sAm, sMu);
    for (int b = 0; b < BB; b++) {
      nb_ctx128<<<dim3(QQ/128, HH, 1), 128, 0, stream>>>(
          vals4 + (long)b*sBm, muq4 + (long)b*sMu, sg24 + (long)b*sMu,
          bmu, bsg, ctxS, 0L, 0L, 0L);
      gemm_nt64<<<dim3(EE/64, QQ/64, 1), 256, 0, stream>>>(
          ctxS, Wo, out + (long)b*sQ, QQ, EE, EE, 0L, 0L, 0L);
    }
  }
  (void)in_sizes; (void)n_in; (void)out_size;
}

// Round 9
// 422.327 us; speedup vs baseline: 2.0720x; 1.0300x over previous
//
#include <hip/hip_runtime.h>

#define BB 4
#define LL 2048
#define QQ 2048
#define HH 16
#define DD 64
#define EE 1024
#define NB 512

typedef __attribute__((ext_vector_type(8))) short bf16x8;   // 8 bf16 (4 VGPRs)
typedef __attribute__((ext_vector_type(4))) float f32x4;    // MFMA acc

__device__ inline ushort bf16_rne(float f) {
  uint u = __float_as_uint(f);
  return (ushort)((u + 0x7fffu + ((u >> 16) & 1u)) >> 16);
}
__device__ inline float bf16_f(ushort h) { return __uint_as_float((uint)h << 16); }
__device__ inline void hilo(float x, ushort& h, ushort& l) {
  h = bf16_rne(x);
  l = bf16_rne(x - bf16_f(h));
}

// pack 8 floats -> hi/lo bf16 uint4s
__device__ inline void cvt8_pack(const float* a, uint4& ph, uint4& pl) {
  ushort h[8], l[8];
  #pragma unroll
  for (int j = 0; j < 8; j++) hilo(a[j], h[j], l[j]);
  ph = make_uint4((uint)h[0] | ((uint)h[1] << 16), (uint)h[2] | ((uint)h[3] << 16),
                  (uint)h[4] | ((uint)h[5] << 16), (uint)h[6] | ((uint)h[7] << 16));
  pl = make_uint4((uint)l[0] | ((uint)l[1] << 16), (uint)l[2] | ((uint)l[3] << 16),
                  (uint)l[4] | ((uint)l[5] << 16), (uint)l[6] | ((uint)l[7] << 16));
}

// ---------- x (fp32, n elems) -> hi/lo bf16 planes (same layout) ----------
__global__ __launch_bounds__(256) void cvt_hilo(
    const float* __restrict__ x, ushort* __restrict__ hi, ushort* __restrict__ lo, long n)
{
  long i0 = ((long)blockIdx.x * 256 + threadIdx.x) * 8;
  long stride = (long)gridDim.x * 2048;
  for (long i = i0; i < n; i += stride) {
    float a[8];
    *(float4*)&a[0] = *(const float4*)&x[i];
    *(float4*)&a[4] = *(const float4*)&x[i + 4];
    uint4 ph, pl;
    cvt8_pack(a, ph, pl);
    *(uint4*)&hi[i] = ph;
    *(uint4*)&lo[i] = pl;
  }
}

// ---------- fused double cvt: blockIdx.y selects (x0) or (x1); entry-uniform ----------
__global__ __launch_bounds__(256) void cvt_hilo2(
    const float* __restrict__ x0, ushort* __restrict__ h0, ushort* __restrict__ l0,
    const float* __restrict__ x1, ushort* __restrict__ h1, ushort* __restrict__ l1, long n)
{
  const float* x = blockIdx.y ? x1 : x0;
  ushort* hi = blockIdx.y ? h1 : h0;
  ushort* lo = blockIdx.y ? l1 : l0;
  long i0 = ((long)blockIdx.x * 256 + threadIdx.x) * 8;
  long stride = (long)gridDim.x * 2048;
  for (long i = i0; i < n; i += stride) {
    float a[8];
    *(float4*)&a[0] = *(const float4*)&x[i];
    *(float4*)&a[4] = *(const float4*)&x[i + 4];
    uint4 ph, pl;
    cvt8_pack(a, ph, pl);
    *(uint4*)&hi[i] = ph;
    *(uint4*)&lo[i] = pl;
  }
}

// ---------- transpose + hilo: x fp32 [R][C] -> hi/lo [C][R] ----------
__global__ __launch_bounds__(256) void cvt_hiloT(
    const float* __restrict__ x, ushort* __restrict__ hiT, ushort* __restrict__ loT,
    int R, int C, long zIn, long zOut)
{
  x += (long)blockIdx.z * zIn; hiT += (long)blockIdx.z * zOut; loT += (long)blockIdx.z * zOut;
  __shared__ float tile[32][33];
  const int t = threadIdx.x;
  const long r0 = (long)blockIdx.y * 32, c0 = (long)blockIdx.x * 32;
  {
    int row = t >> 3, c4 = t & 7;
    float4 v = *(const float4*)&x[(r0 + row) * C + c0 + c4 * 4];
    tile[row][c4*4+0] = v.x; tile[row][c4*4+1] = v.y;
    tile[row][c4*4+2] = v.z; tile[row][c4*4+3] = v.w;
  }
  __syncthreads();
  {
    int col = t >> 3, r4 = t & 7;
    ushort h[4], l[4];
    #pragma unroll
    for (int j = 0; j < 4; j++) hilo(tile[r4 * 4 + j][col], h[j], l[j]);
    uint2 ph = make_uint2((uint)h[0] | ((uint)h[1] << 16), (uint)h[2] | ((uint)h[3] << 16));
    uint2 pl = make_uint2((uint)l[0] | ((uint)l[1] << 16), (uint)l[2] | ((uint)l[3] << 16));
    long o = (c0 + col) * (long)R + r0 + r4 * 4;
    *(uint2*)&hiT[o] = ph;
    *(uint2*)&loT[o] = pl;
  }
}

// ---------- dst[z] = src[2z] + src[2z+1] ----------
__global__ __launch_bounds__(256) void add_pairs(
    float* __restrict__ dst, long dstStride,
    const float* __restrict__ src, long srcPairStride, long n)
{
  float* d = dst + (long)blockIdx.z * dstStride;
  const float* s0 = src + (long)blockIdx.z * srcPairStride;
  const float* s1 = s0 + n;
  long i0 = ((long)blockIdx.x * 256 + threadIdx.x) * 4;
  long stride = (long)gridDim.x * 1024;
  for (long i = i0; i < n; i += stride) {
    float4 a = *(const float4*)&s0[i];
    float4 b = *(const float4*)&s1[i];
    a.x += b.x; a.y += b.y; a.z += b.z; a.w += b.w;
    *(float4*)&d[i] = a;
  }
}

// ================= fp32 GEMMs (tier-2 only) =================

__global__ __launch_bounds__(256) void gemm_nt128(
    const float* __restrict__ A, const float* __restrict__ B, float* __restrict__ C,
    int N, int K, long sA, long sB, long sC, int NS, int Kc)
{
  const int z = blockIdx.z;
  const int b = z / NS, ks = z - b * NS;
  A += (long)b * sA + (long)ks * Kc;
  B += (long)b * sB + (long)ks * Kc;
  C += (long)z * sC;
  __shared__ float As[32][132], Bs[32][132];
  const int t = threadIdx.x;
  const int tx = t & 15, ty = t >> 4;
  const long m0 = (long)blockIdx.y * 128, n0 = (long)blockIdx.x * 128;
  float acc[8][8] = {};
  for (int k0 = 0; k0 < Kc; k0 += 32) {
    #pragma unroll
    for (int i = 0; i < 4; i++) {
      int f = t + i * 256;
      int r = f >> 3, k4 = f & 7;
      float4 va = *(const float4*)&A[(m0 + r) * K + k0 + k4 * 4];
      As[k4*4+0][r] = va.x; As[k4*4+1][r] = va.y; As[k4*4+2][r] = va.z; As[k4*4+3][r] = va.w;
      float4 vb = *(const float4*)&B[(n0 + r) * K + k0 + k4 * 4];
      Bs[k4*4+0][r] = vb.x; Bs[k4*4+1][r] = vb.y; Bs[k4*4+2][r] = vb.z; Bs[k4*4+3][r] = vb.w;
    }
    __syncthreads();
    #pragma unroll
    for (int kk = 0; kk < 32; kk++) {
      float4 a0 = *(const float4*)&As[kk][ty*8];
      float4 a1 = *(const float4*)&As[kk][ty*8+4];
      float4 b0 = *(const float4*)&Bs[kk][tx*8];
      float4 b1 = *(const float4*)&Bs[kk][tx*8+4];
      float ar[8] = {a0.x,a0.y,a0.z,a0.w,a1.x,a1.y,a1.z,a1.w};
      float br[8] = {b0.x,b0.y,b0.z,b0.w,b1.x,b1.y,b1.z,b1.w};
      #pragma unroll
      for (int i = 0; i < 8; i++)
        #pragma unroll
        for (int j = 0; j < 8; j++)
          acc[i][j] += ar[i] * br[j];
    }
    __syncthreads();
  }
  #pragma unroll
  for (int i = 0; i < 8; i++) {
    float4 o0 = make_float4(acc[i][0], acc[i][1], acc[i][2], acc[i][3]);
    float4 o1 = make_float4(acc[i][4], acc[i][5], acc[i][6], acc[i][7]);
    *(float4*)&C[(m0 + ty*8 + i) * N + n0 + tx*8    ] = o0;
    *(float4*)&C[(m0 + ty*8 + i) * N + n0 + tx*8 + 4] = o1;
  }
}

__global__ __launch_bounds__(256) void gemm_tn128(
    const float* __restrict__ A, const float* __restrict__ B, float* __restrict__ C,
    int M, int N, long sA, long sB, long sC, int NS, int Kc)
{
  const int z = blockIdx.z;
  const int b = z / NS, ks = z - b * NS;
  A += (long)b * sA + (long)ks * Kc * M;
  B += (long)b * sB + (long)ks * Kc * N;
  C += (long)z * sC;
  __shared__ float As[32][132], Bs[32][132];
  const int t = threadIdx.x;
  const int tx = t & 15, ty = t >> 4;
  const long m0 = (long)blockIdx.y * 128, n0 = (long)blockIdx.x * 128;
  float acc[8][8] = {};
  for (int k0 = 0; k0 < Kc; k0 += 32) {
    #pragma unroll
    for (int i = 0; i < 4; i++) {
      int f = t + i * 256;
      int r = f >> 5, c4 = f & 31;
      *(float4*)&As[r][c4 * 4] = *(const float4*)&A[(long)(k0 + r) * M + m0 + c4 * 4];
      *(float4*)&Bs[r][c4 * 4] = *(const float4*)&B[(long)(k0 + r) * N + n0 + c4 * 4];
    }
    __syncthreads();
    #pragma unroll
    for (int kk = 0; kk < 32; kk++) {
      float4 a0 = *(const float4*)&As[kk][ty*8];
      float4 a1 = *(const float4*)&As[kk][ty*8+4];
      float4 b0 = *(const float4*)&Bs[kk][tx*8];
      float4 b1 = *(const float4*)&Bs[kk][tx*8+4];
      float ar[8] = {a0.x,a0.y,a0.z,a0.w,a1.x,a1.y,a1.z,a1.w};
      float br[8] = {b0.x,b0.y,b0.z,b0.w,b1.x,b1.y,b1.z,b1.w};
      #pragma unroll
      for (int i = 0; i < 8; i++)
        #pragma unroll
        for (int j = 0; j < 8; j++)
          acc[i][j] += ar[i] * br[j];
    }
    __syncthreads();
  }
  #pragma unroll
  for (int i = 0; i < 8; i++) {
    float4 o0 = make_float4(acc[i][0], acc[i][1], acc[i][2], acc[i][3]);
    float4 o1 = make_float4(acc[i][4], acc[i][5], acc[i][6], acc[i][7]);
    *(float4*)&C[(m0 + ty*8 + i) * N + n0 + tx*8    ] = o0;
    *(float4*)&C[(m0 + ty*8 + i) * N + n0 + tx*8 + 4] = o1;
  }
}

__global__ __launch_bounds__(256) void gemm_nt64(
    const float* __restrict__ A, const float* __restrict__ B, float* __restrict__ C,
    int M, int N, int K, long sA, long sB, long sC)
{
  A += (long)blockIdx.z * sA; B += (long)blockIdx.z * sB; C += (long)blockIdx.z * sC;
  __shared__ float As[32][68], Bs[32][68];
  const int t = threadIdx.x;
  const int tx = t & 15, ty = t >> 4;
  const int m0 = blockIdx.y * 64, n0 = blockIdx.x * 64;
  float acc[4][4] = {};
  for (int k0 = 0; k0 < K; k0 += 32) {
    #pragma unroll
    for (int i = 0; i < 2; i++) {
      int f = t + i * 256;
      int r = f >> 3, k4 = f & 7;
      float4 va = *(const float4*)&A[(long)(m0 + r) * K + k0 + k4 * 4];
      As[k4*4+0][r] = va.x; As[k4*4+1][r] = va.y; As[k4*4+2][r] = va.z; As[k4*4+3][r] = va.w;
      float4 vb = *(const float4*)&B[(long)(n0 + r) * K + k0 + k4 * 4];
      Bs[k4*4+0][r] = vb.x; Bs[k4*4+1][r] = vb.y; Bs[k4*4+2][r] = vb.z; Bs[k4*4+3][r] = vb.w;
    }
    __syncthreads();
    #pragma unroll
    for (int kk = 0; kk < 32; kk++) {
      float4 a4 = *(const float4*)&As[kk][ty * 4];
      float4 b4 = *(const float4*)&Bs[kk][tx * 4];
      float ar[4] = {a4.x, a4.y, a4.z, a4.w};
      float br[4] = {b4.x, b4.y, b4.z, b4.w};
      #pragma unroll
      for (int i = 0; i < 4; i++)
        #pragma unroll
        for (int j = 0; j < 4; j++)
          acc[i][j] += ar[i] * br[j];
    }
    __syncthreads();
  }
  #pragma unroll
  for (int i = 0; i < 4; i++) {
    float4 o = make_float4(acc[i][0], acc[i][1], acc[i][2], acc[i][3]);
    *(float4*)&C[(long)(m0 + ty*4 + i) * N + n0 + tx*4] = o;
  }
}

// ================= bf16x3 MFMA NT GEMMs =================
// Fragment convention (HW-validated r6/r7/r8): A: lane=(row&15)+16*(k>>3), elem=k&7;
// B: lane=(col&15)+16*(k>>3); D: col=lane&15, row=(lane>>4)*4+reg.
// LDS slot swizzle g(idx)=((r15)^(kq<<2))+16*kq (bijective per 64-slot frag) applied
// to BOTH ds_write (staging) and ds_read (fragment fetch): breaks the 4-way
// bank-group conflict of the naive idx=(r15)+16*kq write pattern.

// 128x128 tile, optional split-K (z = b*NS+ks), B shared across z
__global__ __launch_bounds__(256) void gemm_nt128_b3(
    const ushort* __restrict__ Ah, const ushort* __restrict__ Al,
    const ushort* __restrict__ Bh, const ushort* __restrict__ Bl,
    float* __restrict__ C, int N, int K, long sA, long sC, int NS, int Kc)
{
  const int z = blockIdx.z;
  const int zb = z / NS, ks = z - zb * NS;
  Ah += (long)zb * sA + (long)ks * Kc;
  Al += (long)zb * sA + (long)ks * Kc;
  Bh += (long)ks * Kc;
  Bl += (long)ks * Kc;
  C  += (long)z * sC;
  __shared__ ushort AhS[4096], AlS[4096], BhS[4096], BlS[4096];
  const int t = threadIdx.x;
  const int l = t & 63, w = t >> 6;
  const long m0 = (long)blockIdx.y * 128, n0 = (long)blockIdx.x * 128;
  const int frA = (w & 1) * 4;
  const int frB = (w >> 1) * 4;
  const int rs = ((((l & 15) ^ ((l >> 4) << 2)) + 16 * (l >> 4))) * 8;  // swizzled read slot
  f32x4 acc[4][4] = {};
  for (int k0 = 0; k0 < Kc; k0 += 32) {
    #pragma unroll
    for (int p = 0; p < 2; p++) {
      int t2 = t + p * 256;
      int row = t2 >> 2, kq = t2 & 3;
      long goff = (m0 + row) * (long)K + k0 + kq * 8;
      long gofB = (n0 + row) * (long)K + k0 + kq * 8;
      int dst = (row >> 4) * 512 + ((((row & 15) ^ (kq << 2)) + 16 * kq)) * 8;
      *(uint4*)&AhS[dst] = *(const uint4*)(Ah + goff);
      *(uint4*)&AlS[dst] = *(const uint4*)(Al + goff);
      *(uint4*)&BhS[dst] = *(const uint4*)(Bh + gofB);
      *(uint4*)&BlS[dst] = *(const uint4*)(Bl + gofB);
    }
    __syncthreads();
    bf16x8 ah[4], al[4], bh[4], bl[4];
    #pragma unroll
    for (int i = 0; i < 4; i++) {
      ah[i] = *(const bf16x8*)&AhS[(frA + i) * 512 + rs];
      al[i] = *(const bf16x8*)&AlS[(frA + i) * 512 + rs];
      bh[i] = *(const bf16x8*)&BhS[(frB + i) * 512 + rs];
      bl[i] = *(const bf16x8*)&BlS[(frB + i) * 512 + rs];
    }
    #pragma unroll
    for (int i = 0; i < 4; i++)
      #pragma unroll
      for (int j = 0; j < 4; j++) {
        acc[i][j] = __builtin_amdgcn_mfma_f32_16x16x32_bf16(ah[i], bh[j], acc[i][j], 0, 0, 0);
        acc[i][j] = __builtin_amdgcn_mfma_f32_16x16x32_bf16(ah[i], bl[j], acc[i][j], 0, 0, 0);
        acc[i][j] = __builtin_amdgcn_mfma_f32_16x16x32_bf16(al[i], bh[j], acc[i][j], 0, 0, 0);
      }
    __syncthreads();
  }
  const long rbase = m0 + (w & 1) * 64 + (l >> 4) * 4;
  const int  cbase = (int)n0 + (w >> 1) * 64 + (l & 15);
  #pragma unroll
  for (int i = 0; i < 4; i++)
    #pragma unroll
    for (int j = 0; j < 4; j++)
      #pragma unroll
      for (int r = 0; r < 4; r++)
        C[(rbase + i * 16 + r) * N + cbase + j * 16] = acc[i][j][r];
}

// 64x128 tile, no split-K: A shared across z, B per-z. Used for st2.
__global__ __launch_bounds__(256) void gemm_nt64x128_b3(
    const ushort* __restrict__ Ah, const ushort* __restrict__ Al,
    const ushort* __restrict__ Bh, const ushort* __restrict__ Bl,
    float* __restrict__ C, int N, int K, long sB, long sC)
{
  const int z = blockIdx.z;
  Bh += (long)z * sB; Bl += (long)z * sB; C += (long)z * sC;
  __shared__ ushort AhS[2048], AlS[2048], BhS[4096], BlS[4096];   // 24 KB
  const int t = threadIdx.x;
  const int l = t & 63, w = t >> 6;
  const long m0 = (long)blockIdx.y * 64, n0 = (long)blockIdx.x * 128;
  const int wm = w & 1, wn = w >> 1;
  const int rs = ((((l & 15) ^ ((l >> 4) << 2)) + 16 * (l >> 4))) * 8;
  f32x4 acc[2][4] = {};
  for (int k0 = 0; k0 < K; k0 += 32) {
    {
      int row = t >> 2, kq = t & 3;
      long goff = (m0 + row) * (long)K + k0 + kq * 8;
      int dst = (row >> 4) * 512 + ((((row & 15) ^ (kq << 2)) + 16 * kq)) * 8;
      *(uint4*)&AhS[dst] = *(const uint4*)(Ah + goff);
      *(uint4*)&AlS[dst] = *(const uint4*)(Al + goff);
    }
    #pragma unroll
    for (int p = 0; p < 2; p++) {
      int t2 = t + p * 256;
      int row = t2 >> 2, kq = t2 & 3;
      long gofB = (n0 + row) * (long)K + k0 + kq * 8;
      int dst = (row >> 4) * 512 + ((((row & 15) ^ (kq << 2)) + 16 * kq)) * 8;
      *(uint4*)&BhS[dst] = *(const uint4*)(Bh + gofB);
      *(uint4*)&BlS[dst] = *(const uint4*)(Bl + gofB);
    }
    __syncthreads();
    bf16x8 ah[2], al[2], bh[4], bl[4];
    #pragma unroll
    for (int i = 0; i < 2; i++) {
      ah[i] = *(const bf16x8*)&AhS[(wm * 2 + i) * 512 + rs];
      al[i] = *(const bf16x8*)&AlS[(wm * 2 + i) * 512 + rs];
    }
    #pragma unroll
    for (int j = 0; j < 4; j++) {
      bh[j] = *(const bf16x8*)&BhS[(wn * 4 + j) * 512 + rs];
      bl[j] = *(const bf16x8*)&BlS[(wn * 4 + j) * 512 + rs];
    }
    #pragma unroll
    for (int i = 0; i < 2; i++)
      #pragma unroll
      for (int j = 0; j < 4; j++) {
        acc[i][j] = __builtin_amdgcn_mfma_f32_16x16x32_bf16(ah[i], bh[j], acc[i][j], 0, 0, 0);
        acc[i][j] = __builtin_amdgcn_mfma_f32_16x16x32_bf16(ah[i], bl[j], acc[i][j], 0, 0, 0);
        acc[i][j] = __builtin_amdgcn_mfma_f32_16x16x32_bf16(al[i], bh[j], acc[i][j], 0, 0, 0);
      }
    __syncthreads();
  }
  const long rbase = m0 + wm * 32 + (l >> 4) * 4;
  const int  cbase = (int)n0 + wn * 64 + (l & 15);
  #pragma unroll
  for (int i = 0; i < 2; i++)
    #pragma unroll
    for (int j = 0; j < 4; j++)
      #pragma unroll
      for (int r = 0; r < 4; r++)
        C[(rbase + i * 16 + r) * N + cbase + j * 16] = acc[i][j][r];
}

// ================= valsT: fold split-K pair + transpose + hilo, frag-ordered ========
__global__ __launch_bounds__(256) void cvt_valsT(
    const float* __restrict__ valsP, ushort* __restrict__ vTh, ushort* __restrict__ vTl,
    long slabStride)
{
  const int c = blockIdx.x, h = blockIdx.y, b = blockIdx.z;
  const int t = threadIdx.x;
  __shared__ float tile[32][68];
  const float* s0 = valsP + (long)(2 * b) * slabStride;
  const float* s1 = s0 + slabStride;
  {
    int r = t >> 3, c8 = (t & 7) * 8;
    long g = (long)(c * 32 + r) * EE + h * 64 + c8;
    float4 a0 = *(const float4*)&s0[g];     float4 b0 = *(const float4*)&s1[g];
    float4 a1 = *(const float4*)&s0[g + 4]; float4 b1 = *(const float4*)&s1[g + 4];
    a0.x += b0.x; a0.y += b0.y; a0.z += b0.z; a0.w += b0.w;
    a1.x += b1.x; a1.y += b1.y; a1.z += b1.z; a1.w += b1.w;
    *(float4*)&tile[r][c8] = a0;
    *(float4*)&tile[r][c8 + 4] = a1;
  }
  __syncthreads();
  const int f = t >> 6, l = t & 63;
  const int d = f * 16 + (l & 15), kq = l >> 4;
  float a[8];
  #pragma unroll
  for (int e = 0; e < 8; e++) a[e] = tile[kq * 8 + e][d];
  uint4 ph, pl;
  cvt8_pack(a, ph, pl);
  long obase = (((long)(b * HH + h) * 16 + c) * 2048) + (long)t * 8;
  *(uint4*)&vTh[obase] = ph;
  *(uint4*)&vTl[obase] = pl;
}

// ================= ctx via MFMA: r generated into LDS in A-frag order ================
__global__ __launch_bounds__(256) void nb_ctx_mf(
    const ushort* __restrict__ vTh, const ushort* __restrict__ vTl,
    const float* __restrict__ muq, const float* __restrict__ sg2,
    const float* __restrict__ bmu, const float* __restrict__ bsg,
    ushort* __restrict__ ctxh, ushort* __restrict__ ctxl,
    long sMu, long sC)
{
  const int h = blockIdx.y, b = blockIdx.z;
  const long q0 = (long)blockIdx.x * 128;
  const int t = threadIdx.x;
  const int l = t & 63, w = t >> 6, wm = w & 1, wn = w >> 1;
  __shared__ ushort AhS[4096], AlS[4096];
  __shared__ ushort BhS[2048], BlS[2048];
  __shared__ float mu_s[128], s2_s[128], bm_s[NB], bv_s[NB];
  const float* muqb = muq + (long)b * sMu;
  const float* sg2b = sg2 + (long)b * sMu;
  if (t < 128) {
    mu_s[t] = muqb[(long)h * QQ + q0 + t];
    s2_s[t] = sg2b[(long)h * QQ + q0 + t];
  }
  for (int i = t; i < NB; i += 256) {
    bm_s[i] = bmu[i];
    float x = bsg[i];
    bv_s[i] = x * x;
  }
  __syncthreads();
  const ushort* vThb = vTh + ((long)(b * HH + h) * 16) * 2048;
  const ushort* vTlb = vTl + ((long)(b * HH + h) * 16) * 2048;
  f32x4 acc[4][2] = {};
  for (int c = 0; c < 16; c++) {
    ((uint4*)BhS)[t] = ((const uint4*)(vThb + c * 2048))[t];
    ((uint4*)BlS)[t] = ((const uint4*)(vTlb + c * 2048))[t];
    #pragma unroll
    for (int p = 0; p < 2; p++) {
      int s = t + p * 256;
      int lf = s & 63;
      int q = ((s >> 6) << 4) + (lf & 15);
      int nb = c * 32 + (lf >> 4) * 8;
      float m = mu_s[q], s2 = s2_s[q];
      float a[8];
      #pragma unroll
      for (int e = 0; e < 8; e++) {
        float v = s2 + bv_s[nb + e];
        float d = m - bm_s[nb + e];
        float rv = __builtin_amdgcn_rcpf(v);
        a[e] = __expf(d * d * rv * -0.5f) * __builtin_amdgcn_rsqf(v * 6.2831853071795865f);
      }
      uint4 ph, pl;
      cvt8_pack(a, ph, pl);
      *(uint4*)&AhS[s * 8] = ph;
      *(uint4*)&AlS[s * 8] = pl;
    }
    __syncthreads();
    bf16x8 bhf[2], blf[2];
    #pragma unroll
    for (int j = 0; j < 2; j++) {
      bhf[j] = *(const bf16x8*)&BhS[(wn * 2 + j) * 512 + l * 8];
      blf[j] = *(const bf16x8*)&BlS[(wn * 2 + j) * 512 + l * 8];
    }
    #pragma unroll
    for (int i = 0; i < 4; i++) {
      bf16x8 ah = *(const bf16x8*)&AhS[(wm * 4 + i) * 512 + l * 8];
      bf16x8 al = *(const bf16x8*)&AlS[(wm * 4 + i) * 512 + l * 8];
      #pragma unroll
      for (int j = 0; j < 2; j++) {
        acc[i][j] = __builtin_amdgcn_mfma_f32_16x16x32_bf16(ah, bhf[j], acc[i][j], 0, 0, 0);
        acc[i][j] = __builtin_amdgcn_mfma_f32_16x16x32_bf16(ah, blf[j], acc[i][j], 0, 0, 0);
        acc[i][j] = __builtin_amdgcn_mfma_f32_16x16x32_bf16(al, bhf[j], acc[i][j], 0, 0, 0);
      }
    }
    __syncthreads();
  }
  ushort* ch = ctxh + (long)b * sC;
  ushort* cl = ctxl + (long)b * sC;
  const long rbase = q0 + wm * 64 + (l >> 4) * 4;
  const int  cbase = h * 64 + wn * 32 + (l & 15);
  #pragma unroll
  for (int i = 0; i < 4; i++)
    #pragma unroll
    for (int j = 0; j < 2; j++)
      #pragma unroll
      for (int r = 0; r < 4; r++) {
        long off = (rbase + i * 16 + r) * EE + cbase + j * 16;
        ushort hb, lb;
        hilo(acc[i][j][r], hb, lb);
        ch[off] = hb;
        cl[off] = lb;
      }
}

// ================= collapsed scores path =================
__global__ __launch_bounds__(256) void nb_uvec(
    const float* __restrict__ Bm, const float* __restrict__ wmu, const float* __restrict__ wsg,
    float* __restrict__ ump, float* __restrict__ usp, long sBm, long sU)
{
  Bm += (long)blockIdx.z * sBm; ump += (long)blockIdx.z * sU; usp += (long)blockIdx.z * sU;
  const int e = blockIdx.x * 256 + threadIdx.x;
  const int c = blockIdx.y;
  float am = 0.f, as = 0.f;
  #pragma unroll 8
  for (int n = c * 64; n < c * 64 + 64; n++) {
    float bv = Bm[(long)n * EE + e];
    am += wmu[n] * bv;
    as += wsg[n] * bv;
  }
  ump[(long)c * EE + e] = am;
  usp[(long)c * EE + e] = as;
}

__global__ __launch_bounds__(256) void nb_kw(
    const float* __restrict__ Wk, const float* __restrict__ ump, const float* __restrict__ usp,
    float* __restrict__ kwm, float* __restrict__ kws, long sU, long sK)
{
  ump += (long)blockIdx.z * sU; usp += (long)blockIdx.z * sU;
  kwm += (long)blockIdx.z * sK; kws += (long)blockIdx.z * sK;
  __shared__ float pm[256], ps[256];
  const int e = blockIdx.x, t = threadIdx.x;
  const float* row = Wk + (long)e * EE;
  float am = 0.f, as = 0.f;
  for (int i = t; i < EE; i += 256) {
    float um = 0.f, us = 0.f;
    #pragma unroll
    for (int c = 0; c < 8; c++) { um += ump[(long)c * EE + i]; us += usp[(long)c * EE + i]; }
    float w = row[i];
    am += w * um;
    as += w * us;
  }
  pm[t] = am; ps[t] = as;
  __syncthreads();
  for (int s = 128; s > 0; s >>= 1) {
    if (t < s) { pm[t] += pm[t + s]; ps[t] += ps[t + s]; }
    __syncthreads();
  }
  if (t == 0) { kwm[e] = pm[0]; kws[e] = ps[0]; }
}

__global__ __launch_bounds__(256) void nb_amas(
    const float* __restrict__ Wq, const float* __restrict__ kwm, const float* __restrict__ kws,
    float* __restrict__ AmAs, long sK, long sAm)
{
  kwm += (long)blockIdx.z * sK; kws += (long)blockIdx.z * sK;
  AmAs += (long)blockIdx.z * sAm;
  __shared__ float km[64], ks[64];
  const int t = threadIdx.x;
  const int h = blockIdx.y;
  const int e = blockIdx.x * 256 + t;
  if (t < 64) { km[t] = kwm[h * 64 + t]; ks[t] = kws[h * 64 + t]; }
  __syncthreads();
  float am = 0.f, as = 0.f;
  #pragma unroll 8
  for (int d = 0; d < 64; d++) {
    float w = Wq[(long)(h * 64 + d) * EE + e];
    am += km[d] * w;
    as += ks[d] * w;
  }
  AmAs[(long)e * 32 + h]      = am;
  AmAs[(long)e * 32 + 16 + h] = as;
}

// 8 q-rows per block: AmAs L2 traffic /8 vs the per-row version.
__global__ __launch_bounds__(256) void nb_musig8(
    const float* __restrict__ qb, const float* __restrict__ AmAs,
    float* __restrict__ muq, float* __restrict__ sg2, long sQ, long sAm, long sMu)
{
  qb += (long)blockIdx.z * sQ; AmAs += (long)blockIdx.z * sAm;
  muq += (long)blockIdx.z * sMu; sg2 += (long)blockIdx.z * sMu;
  __shared__ float qs[8 * EE];       // 32 KB
  const int t = threadIdx.x;
  const long q0 = (long)blockIdx.x * 8;
  for (int i = t * 4; i < 8 * EE; i += 1024)
    *(float4*)&qs[i] = *(const float4*)&qb[q0 * EE + i];
  __syncthreads();
  const int o = t & 31, row = t >> 5;
  const float* qr = qs + row * EE;
  float acc = 0.f;
  #pragma unroll 8
  for (int e = 0; e < EE; e++)
    acc += qr[e] * AmAs[(long)e * 32 + o];
  float s = acc * 0.125f;
  if (o < 16) {
    muq[(long)o * QQ + q0 + row] = 1.f / (1.f + expf(-s));
  } else {
    float sp = (s > 20.f) ? s : log1pf(expf(s));
    sg2[(long)(o - 16) * QQ + q0 + row] = fmaxf(sp, 1e-4f);
  }
}

// tier-2 per-row musig (proven)
__global__ __launch_bounds__(256) void nb_musig(
    const float* __restrict__ qb, const float* __restrict__ AmAs,
    float* __restrict__ muq, float* __restrict__ sg2, long sQ, long sAm, long sMu)
{
  qb += (long)blockIdx.z * sQ; AmAs += (long)blockIdx.z * sAm;
  muq += (long)blockIdx.z * sMu; sg2 += (long)blockIdx.z * sMu;
  __shared__ float qs[EE];
  __shared__ float part[8][32];
  const int t = threadIdx.x, qrow = blockIdx.x;
  for (int i = t; i < EE; i += 256) qs[i] = qb[(long)qrow * EE + i];
  __syncthreads();
  const int o = t & 31, ch = t >> 5;
  float acc = 0.f;
  const int e0 = ch * 128;
  #pragma unroll 8
  for (int i = 0; i < 128; i++) {
    int e = e0 + i;
    acc += qs[e] * AmAs[(long)e * 32 + o];
  }
  part[ch][o] = acc;
  __syncthreads();
  if (t < 32) {
    float s = 0.f;
    #pragma unroll
    for (int c = 0; c < 8; c++) s += part[c][o];
    s *= 0.125f;
    if (o < 16) {
      muq[(long)o * QQ + qrow] = 1.f / (1.f + expf(-s));
    } else {
      float sp = (s > 20.f) ? s : log1pf(expf(s));
      sg2[(long)(o - 16) * QQ + qrow] = fmaxf(sp, 1e-4f);
    }
  }
}

// ================= tier-2 ctx (fp32, proven) =================
__global__ __launch_bounds__(128) void nb_ctx128(
    const float* __restrict__ vals, const float* __restrict__ muq, const float* __restrict__ sg2,
    const float* __restrict__ bmu,  const float* __restrict__ bsg, float* __restrict__ ctx,
    long sV, long sMu, long sC)
{
  vals += (long)blockIdx.z * sV; ctx += (long)blockIdx.z * sC;
  muq += (long)blockIdx.z * sMu; sg2 += (long)blockIdx.z * sMu;
  __shared__ float As[32][132], Bs[32][68];
  __shared__ __align__(16) float mu_s[128], s2_s[128];
  const int t = threadIdx.x;
  const int tx = t & 7, ty = t >> 3;
  const long q0 = (long)blockIdx.x * 128;
  const int h = blockIdx.y;
  mu_s[t] = muq[(long)h * QQ + q0 + t];
  s2_s[t] = sg2[(long)h * QQ + q0 + t];
  __syncthreads();
  float acc[8][8] = {};
  for (int n0 = 0; n0 < NB; n0 += 32) {
    #pragma unroll
    for (int i = 0; i < 4; i++) {
      int f = t + i * 128;
      int r = f >> 4, c4 = f & 15;
      *(float4*)&Bs[r][c4 * 4] = *(const float4*)&vals[(long)(n0 + r) * EE + h * 64 + c4 * 4];
    }
    #pragma unroll
    for (int i = 0; i < 8; i++) {
      int idx = t + i * 128;
      int n = idx >> 5, qg = idx & 31;
      float bm = bmu[n0 + n], bs = bsg[n0 + n];
      float bs2 = bs * bs;
      float4 m4 = *(const float4*)&mu_s[qg * 4];
      float4 s4 = *(const float4*)&s2_s[qg * 4];
      float4 rr;
      {
        float v0 = s4.x + bs2, d0 = m4.x - bm;
        float v1 = s4.y + bs2, d1 = m4.y - bm;
        float v2 = s4.z + bs2, d2 = m4.z - bm;
        float v3 = s4.w + bs2, d3 = m4.w - bm;
        float r0 = __builtin_amdgcn_rcpf(v0), r1 = __builtin_amdgcn_rcpf(v1);
        float r2 = __builtin_amdgcn_rcpf(v2), r3 = __builtin_amdgcn_rcpf(v3);
        rr.x = __expf(d0 * d0 * r0 * -0.5f) * __builtin_amdgcn_rsqf(v0 * 6.2831853071795865f);
        rr.y = __expf(d1 * d1 * r1 * -0.5f) * __builtin_amdgcn_rsqf(v1 * 6.2831853071795865f);
        rr.z = __expf(d2 * d2 * r2 * -0.5f) * __builtin_amdgcn_rsqf(v2 * 6.2831853071795865f);
        rr.w = __expf(d3 * d3 * r3 * -0.5f) * __builtin_amdgcn_rsqf(v3 * 6.2831853071795865f);
      }
      *(float4*)&As[n][qg * 4] = rr;
    }
    __syncthreads();
    #pragma unroll
    for (int kk = 0; kk < 32; kk++) {
      float4 a0 = *(const float4*)&As[kk][ty*8];
      float4 a1 = *(const float4*)&As[kk][ty*8+4];
      float4 b0 = *(const float4*)&Bs[kk][tx*8];
      float4 b1 = *(const float4*)&Bs[kk][tx*8+4];
      float ar[8] = {a0.x,a0.y,a0.z,a0.w,a1.x,a1.y,a1.z,a1.w};
      float br[8] = {b0.x,b0.y,b0.z,b0.w,b1.x,b1.y,b1.z,b1.w};
      #pragma unroll
      for (int i = 0; i < 8; i++)
        #pragma unroll
        for (int j = 0; j < 8; j++)
          acc[i][j] += ar[i] * br[j];
    }
    __syncthreads();
  }
  #pragma unroll
  for (int i = 0; i < 8; i++) {
    float4 o0 = make_float4(acc[i][0], acc[i][1], acc[i][2], acc[i][3]);
    float4 o1 = make_float4(acc[i][4], acc[i][5], acc[i][6], acc[i][7]);
    *(float4*)&ctx[(q0 + ty*8 + i) * EE + h * 64 + tx*8    ] = o0;
    *(float4*)&ctx[(q0 + ty*8 + i) * EE + h * 64 + tx*8 + 4] = o1;
  }
}

extern "C" void kernel_launch(void* const* d_in, const int* in_sizes, int n_in,
                              void* d_out, int out_size, void* d_ws, size_t ws_size,
                              hipStream_t stream) {
  const float* k   = (const float*)d_in[0];
  const float* q   = (const float*)d_in[1];
  const float* Wq  = (const float*)d_in[2];
  const float* Wk  = (const float*)d_in[3];
  const float* Wv  = (const float*)d_in[4];
  const float* Wo  = (const float*)d_in[5];
  const float* wmu = (const float*)d_in[6];
  const float* wsg = (const float*)d_in[7];
  const float* Gs  = (const float*)d_in[8];
  const float* bmu = (const float*)d_in[9];
  const float* bsg = (const float*)d_in[10];
  float* out = (float*)d_out;
  char* ws = (char*)d_ws;

  const long sBm = (long)NB * EE;
  const long sU  = 8L * EE;
  const long sK  = EE;
  const long sAm = 32L * EE;
  const long sMu = (long)HH * QQ;
  const long sQ  = (long)QQ * EE;

  if (ws_size >= (50u << 20)) {
    // ---- tier 1 (50 MiB), lifetimes verified disjoint (same as r8) ----
    ushort* kTh  = (ushort*)(ws + 0);
    ushort* kTl  = (ushort*)(ws + (16u << 20));
    ushort* GsTh = (ushort*)(ws + (32u << 20));
    ushort* GsTl = (ushort*)(ws + (34u << 20));
    float*  Bm4  = (float*)(ws + (40u << 20));
    ushort* Bmh  = (ushort*)(ws + 0);
    ushort* Bml  = (ushort*)(ws + (4u << 20));
    ushort* Wvh  = (ushort*)(ws + (8u << 20));
    ushort* Wvl  = (ushort*)(ws + (10u << 20));
    float*  valsP= (float*)(ws + (16u << 20));
    ushort* vTh  = (ushort*)(ws + (32u << 20));
    ushort* vTl  = (ushort*)(ws + (36u << 20));
    ushort* Woh  = (ushort*)(ws + (40u << 20));
    ushort* Wol  = (ushort*)(ws + (42u << 20));
    ushort* ctxh = (ushort*)(ws + 0);
    ushort* ctxl = (ushort*)(ws + (16u << 20));
    char*  sm    = ws + (48u << 20);
    float* ump4  = (float*)(sm);
    float* usp4  = (float*)(sm + (128u << 10));
    float* kwm4  = (float*)(sm + (256u << 10));
    float* kws4  = (float*)(sm + (272u << 10));
    float* AmAs4 = (float*)(sm + (288u << 10));
    float* muq4  = (float*)(sm + (800u << 10));
    float* sg24  = (float*)(sm + (1312u << 10));

    // S1: transposed hilo operands for st2
    cvt_hiloT<<<dim3(NB/32, LL/32, 1),  256, 0, stream>>>(Gs, GsTh, GsTl, LL, NB, 0L, 0L);
    cvt_hiloT<<<dim3(EE/32, LL/32, BB), 256, 0, stream>>>(k, kTh, kTl, LL, EE,
                                                          (long)LL*EE, (long)LL*EE);
    // st2 (MFMA bf16x3, swizzled staging): Bm4[nb][e] = sum_l GsT[nb][l]*kT[e][l]
    gemm_nt64x128_b3<<<dim3(EE/128, NB/64, BB), 256, 0, stream>>>(
        GsTh, GsTl, kTh, kTl, Bm4, EE, LL, (long)LL*EE, sBm);
    // scores chain
    nb_uvec  <<<dim3(EE/256, 8, BB),  256, 0, stream>>>(Bm4, wmu, wsg, ump4, usp4, sBm, sU);
    nb_kw    <<<dim3(EE, 1, BB),      256, 0, stream>>>(Wk, ump4, usp4, kwm4, kws4, sU, sK);
    nb_amas  <<<dim3(EE/256, HH, BB), 256, 0, stream>>>(Wq, kwm4, kws4, AmAs4, sK, sAm);
    nb_musig8<<<dim3(QQ/8, 1, BB),    256, 0, stream>>>(q, AmAs4, muq4, sg24, sQ, sAm, sMu);
    // Bm -> hilo (kT dead), then Wv+Wo -> hilo fused (Bm4 region for Wo, after Bm cvt)
    cvt_hilo<<<dim3(256), 256, 0, stream>>>(Bm4, Bmh, Bml, (long)BB * sBm);
    cvt_hilo2<<<dim3(128, 2), 256, 0, stream>>>(Wv, Wvh, Wvl, Wo, Woh, Wol, (long)EE * EE);
    // st3 (MFMA bf16x3, swizzled): vals slabs = Bm @ Wv^T, split-K=2
    gemm_nt128_b3<<<dim3(EE/128, NB/128, BB*2), 256, 0, stream>>>(
        Bmh, Bml, Wvh, Wvl, valsP, EE, EE, sBm, sBm, 2, EE/2);
    // valsT frag-ordered hilo (GsT dead)
    cvt_valsT<<<dim3(16, HH, BB), 256, 0, stream>>>(valsP, vTh, vTl, sBm);
    // ctx (MFMA bf16x3) -> ctx hilo planes
    nb_ctx_mf<<<dim3(QQ/128, HH, BB), 256, 0, stream>>>(
        vTh, vTl, muq4, sg24, bmu, bsg, ctxh, ctxl, sMu, sQ);
    // st7 (MFMA bf16x3, swizzled): out = ctx @ Wo^T
    gemm_nt128_b3<<<dim3(EE/128, QQ/128, BB), 256, 0, stream>>>(
        ctxh, ctxl, Woh, Wol, out, EE, EE, sQ, sQ, 1, EE);
  } else {
    // ---- tier 2 (ws >= 26 MiB, all-fp32 proven path) ----
    float* BmP   = (float*)(ws + 0);
    float* ctxS  = (float*)(ws + 0);
    float* vals4 = (float*)(ws + (16u << 20));
    char*  sm    = ws + (24u << 20);
    float* ump4  = (float*)(sm);
    float* usp4  = (float*)(sm + (128u << 10));
    float* kwm4  = (float*)(sm + (256u << 10));
    float* kws4  = (float*)(sm + (272u << 10));
    float* AmAs4 = (float*)(sm + (288u << 10));
    float* muq4  = (float*)(sm + (800u << 10));
    float* sg24  = (float*)(sm + (1312u << 10));

    gemm_tn128<<<dim3(EE/128, NB/128, BB*2), 256, 0, stream>>>(
        Gs, k, BmP, NB, EE, 0L, (long)LL*EE, sBm, 2, LL/2);
    add_pairs<<<dim3(256, 1, BB), 256, 0, stream>>>(BmP, 2*sBm, BmP, 2*sBm, sBm);
    gemm_nt128<<<dim3(EE/128, NB/128, BB), 256, 0, stream>>>(
        BmP, Wv, vals4, EE, EE, 2*sBm, 0L, sBm, 1, EE);
    nb_uvec  <<<dim3(EE/256, 8, BB),  256, 0, stream>>>(BmP, wmu, wsg, ump4, usp4, 2*sBm, sU);
    nb_kw    <<<dim3(EE, 1, BB),      256, 0, stream>>>(Wk, ump4, usp4, kwm4, kws4, sU, sK);
    nb_amas  <<<dim3(EE/256, HH, BB), 256, 0, stream>>>(Wq, kwm4, kws4, AmAs4, sK, sAm);
    nb_musig <<<dim3(QQ, 1, BB),      256, 0, stream>>>(q, AmAs4, muq4, sg24, sQ, sAm, sMu);
    for (int b = 0; b < BB; b++) {
      nb_ctx128<<<dim3(QQ/128, HH, 1), 128, 0, stream>>>(
          vals4 + (long)b*sBm, muq4 + (long)b*sMu, sg24 + (long)b*sMu,
          bmu, bsg, ctxS, 0L, 0L, 0L);
      gemm_nt64<<<dim3(EE/64, QQ/64, 1), 256, 0, stream>>>(
          ctxS, Wo, out + (long)b*sQ, QQ, EE, EE, 0L, 0L, 0L);
    }
  }
  (void)in_sizes; (void)n_in; (void)out_size;
}

// Round 10
// 405.822 us; speedup vs baseline: 2.1563x; 1.0407x over previous
//
#include <hip/hip_runtime.h>

#define BB 4
#define LL 2048
#define QQ 2048
#define HH 16
#define DD 64
#define EE 1024
#define NB 512

typedef __attribute__((ext_vector_type(8))) short bf16x8;   // 8 bf16 (4 VGPRs)
typedef __attribute__((ext_vector_type(4))) float f32x4;    // MFMA acc

__device__ inline ushort bf16_rne(float f) {
  uint u = __float_as_uint(f);
  return (ushort)((u + 0x7fffu + ((u >> 16) & 1u)) >> 16);
}
__device__ inline float bf16_f(ushort h) { return __uint_as_float((uint)h << 16); }
__device__ inline void hilo(float x, ushort& h, ushort& l) {
  h = bf16_rne(x);
  l = bf16_rne(x - bf16_f(h));
}

// pack 8 floats -> hi/lo bf16 uint4s
__device__ inline void cvt8_pack(const float* a, uint4& ph, uint4& pl) {
  ushort h[8], l[8];
  #pragma unroll
  for (int j = 0; j < 8; j++) hilo(a[j], h[j], l[j]);
  ph = make_uint4((uint)h[0] | ((uint)h[1] << 16), (uint)h[2] | ((uint)h[3] << 16),
                  (uint)h[4] | ((uint)h[5] << 16), (uint)h[6] | ((uint)h[7] << 16));
  pl = make_uint4((uint)l[0] | ((uint)l[1] << 16), (uint)l[2] | ((uint)l[3] << 16),
                  (uint)l[4] | ((uint)l[5] << 16), (uint)l[6] | ((uint)l[7] << 16));
}

// XCD-chunked bijective block remap (requires nwg % 8 == 0 — true for all call sites).
// Physical blocks round-robin across 8 XCDs; this relabels work so each XCD gets a
// contiguous logical chunk -> operand-panel reuse becomes L2-local (T1).
__device__ inline void xcd_remap(int& bx, int& by, int& bz) {
  int gx = gridDim.x, gy = gridDim.y;
  int nwg = gx * gy * (int)gridDim.z;
  int lin = blockIdx.x + gx * (blockIdx.y + gy * blockIdx.z);
  int swz = (lin & 7) * (nwg >> 3) + (lin >> 3);
  bx = swz % gx; int tmp = swz / gx; by = tmp % gy; bz = tmp / gy;
}

// ---------- x (fp32, n elems) -> hi/lo bf16 planes (same layout) ----------
__global__ __launch_bounds__(256) void cvt_hilo(
    const float* __restrict__ x, ushort* __restrict__ hi, ushort* __restrict__ lo, long n)
{
  long i0 = ((long)blockIdx.x * 256 + threadIdx.x) * 8;
  long stride = (long)gridDim.x * 2048;
  for (long i = i0; i < n; i += stride) {
    float a[8];
    *(float4*)&a[0] = *(const float4*)&x[i];
    *(float4*)&a[4] = *(const float4*)&x[i + 4];
    uint4 ph, pl;
    cvt8_pack(a, ph, pl);
    *(uint4*)&hi[i] = ph;
    *(uint4*)&lo[i] = pl;
  }
}

// ---------- fused double cvt: blockIdx.y selects (x0) or (x1); entry-uniform ----------
__global__ __launch_bounds__(256) void cvt_hilo2(
    const float* __restrict__ x0, ushort* __restrict__ h0, ushort* __restrict__ l0,
    const float* __restrict__ x1, ushort* __restrict__ h1, ushort* __restrict__ l1, long n)
{
  const float* x = blockIdx.y ? x1 : x0;
  ushort* hi = blockIdx.y ? h1 : h0;
  ushort* lo = blockIdx.y ? l1 : l0;
  long i0 = ((long)blockIdx.x * 256 + threadIdx.x) * 8;
  long stride = (long)gridDim.x * 2048;
  for (long i = i0; i < n; i += stride) {
    float a[8];
    *(float4*)&a[0] = *(const float4*)&x[i];
    *(float4*)&a[4] = *(const float4*)&x[i + 4];
    uint4 ph, pl;
    cvt8_pack(a, ph, pl);
    *(uint4*)&hi[i] = ph;
    *(uint4*)&lo[i] = pl;
  }
}

// ---------- transpose + hilo: x fp32 [R][C] -> hi/lo [C][R] ----------
__global__ __launch_bounds__(256) void cvt_hiloT(
    const float* __restrict__ x, ushort* __restrict__ hiT, ushort* __restrict__ loT,
    int R, int C, long zIn, long zOut)
{
  x += (long)blockIdx.z * zIn; hiT += (long)blockIdx.z * zOut; loT += (long)blockIdx.z * zOut;
  __shared__ float tile[32][33];
  const int t = threadIdx.x;
  const long r0 = (long)blockIdx.y * 32, c0 = (long)blockIdx.x * 32;
  {
    int row = t >> 3, c4 = t & 7;
    float4 v = *(const float4*)&x[(r0 + row) * C + c0 + c4 * 4];
    tile[row][c4*4+0] = v.x; tile[row][c4*4+1] = v.y;
    tile[row][c4*4+2] = v.z; tile[row][c4*4+3] = v.w;
  }
  __syncthreads();
  {
    int col = t >> 3, r4 = t & 7;
    ushort h[4], l[4];
    #pragma unroll
    for (int j = 0; j < 4; j++) hilo(tile[r4 * 4 + j][col], h[j], l[j]);
    uint2 ph = make_uint2((uint)h[0] | ((uint)h[1] << 16), (uint)h[2] | ((uint)h[3] << 16));
    uint2 pl = make_uint2((uint)l[0] | ((uint)l[1] << 16), (uint)l[2] | ((uint)l[3] << 16));
    long o = (c0 + col) * (long)R + r0 + r4 * 4;
    *(uint2*)&hiT[o] = ph;
    *(uint2*)&loT[o] = pl;
  }
}

// ---------- dst[z] = src[2z] + src[2z+1] ----------
__global__ __launch_bounds__(256) void add_pairs(
    float* __restrict__ dst, long dstStride,
    const float* __restrict__ src, long srcPairStride, long n)
{
  float* d = dst + (long)blockIdx.z * dstStride;
  const float* s0 = src + (long)blockIdx.z * srcPairStride;
  const float* s1 = s0 + n;
  long i0 = ((long)blockIdx.x * 256 + threadIdx.x) * 4;
  long stride = (long)gridDim.x * 1024;
  for (long i = i0; i < n; i += stride) {
    float4 a = *(const float4*)&s0[i];
    float4 b = *(const float4*)&s1[i];
    a.x += b.x; a.y += b.y; a.z += b.z; a.w += b.w;
    *(float4*)&d[i] = a;
  }
}

// ================= fp32 GEMMs (tier-2 only) =================

__global__ __launch_bounds__(256) void gemm_nt128(
    const float* __restrict__ A, const float* __restrict__ B, float* __restrict__ C,
    int N, int K, long sA, long sB, long sC, int NS, int Kc)
{
  const int z = blockIdx.z;
  const int b = z / NS, ks = z - b * NS;
  A += (long)b * sA + (long)ks * Kc;
  B += (long)b * sB + (long)ks * Kc;
  C += (long)z * sC;
  __shared__ float As[32][132], Bs[32][132];
  const int t = threadIdx.x;
  const int tx = t & 15, ty = t >> 4;
  const long m0 = (long)blockIdx.y * 128, n0 = (long)blockIdx.x * 128;
  float acc[8][8] = {};
  for (int k0 = 0; k0 < Kc; k0 += 32) {
    #pragma unroll
    for (int i = 0; i < 4; i++) {
      int f = t + i * 256;
      int r = f >> 3, k4 = f & 7;
      float4 va = *(const float4*)&A[(m0 + r) * K + k0 + k4 * 4];
      As[k4*4+0][r] = va.x; As[k4*4+1][r] = va.y; As[k4*4+2][r] = va.z; As[k4*4+3][r] = va.w;
      float4 vb = *(const float4*)&B[(n0 + r) * K + k0 + k4 * 4];
      Bs[k4*4+0][r] = vb.x; Bs[k4*4+1][r] = vb.y; Bs[k4*4+2][r] = vb.z; Bs[k4*4+3][r] = vb.w;
    }
    __syncthreads();
    #pragma unroll
    for (int kk = 0; kk < 32; kk++) {
      float4 a0 = *(const float4*)&As[kk][ty*8];
      float4 a1 = *(const float4*)&As[kk][ty*8+4];
      float4 b0 = *(const float4*)&Bs[kk][tx*8];
      float4 b1 = *(const float4*)&Bs[kk][tx*8+4];
      float ar[8] = {a0.x,a0.y,a0.z,a0.w,a1.x,a1.y,a1.z,a1.w};
      float br[8] = {b0.x,b0.y,b0.z,b0.w,b1.x,b1.y,b1.z,b1.w};
      #pragma unroll
      for (int i = 0; i < 8; i++)
        #pragma unroll
        for (int j = 0; j < 8; j++)
          acc[i][j] += ar[i] * br[j];
    }
    __syncthreads();
  }
  #pragma unroll
  for (int i = 0; i < 8; i++) {
    float4 o0 = make_float4(acc[i][0], acc[i][1], acc[i][2], acc[i][3]);
    float4 o1 = make_float4(acc[i][4], acc[i][5], acc[i][6], acc[i][7]);
    *(float4*)&C[(m0 + ty*8 + i) * N + n0 + tx*8    ] = o0;
    *(float4*)&C[(m0 + ty*8 + i) * N + n0 + tx*8 + 4] = o1;
  }
}

__global__ __launch_bounds__(256) void gemm_tn128(
    const float* __restrict__ A, const float* __restrict__ B, float* __restrict__ C,
    int M, int N, long sA, long sB, long sC, int NS, int Kc)
{
  const int z = blockIdx.z;
  const int b = z / NS, ks = z - b * NS;
  A += (long)b * sA + (long)ks * Kc * M;
  B += (long)b * sB + (long)ks * Kc * N;
  C += (long)z * sC;
  __shared__ float As[32][132], Bs[32][132];
  const int t = threadIdx.x;
  const int tx = t & 15, ty = t >> 4;
  const long m0 = (long)blockIdx.y * 128, n0 = (long)blockIdx.x * 128;
  float acc[8][8] = {};
  for (int k0 = 0; k0 < Kc; k0 += 32) {
    #pragma unroll
    for (int i = 0; i < 4; i++) {
      int f = t + i * 256;
      int r = f >> 5, c4 = f & 31;
      *(float4*)&As[r][c4 * 4] = *(const float4*)&A[(long)(k0 + r) * M + m0 + c4 * 4];
      *(float4*)&Bs[r][c4 * 4] = *(const float4*)&B[(long)(k0 + r) * N + n0 + c4 * 4];
    }
    __syncthreads();
    #pragma unroll
    for (int kk = 0; kk < 32; kk++) {
      float4 a0 = *(const float4*)&As[kk][ty*8];
      float4 a1 = *(const float4*)&As[kk][ty*8+4];
      float4 b0 = *(const float4*)&Bs[kk][tx*8];
      float4 b1 = *(const float4*)&Bs[kk][tx*8+4];
      float ar[8] = {a0.x,a0.y,a0.z,a0.w,a1.x,a1.y,a1.z,a1.w};
      float br[8] = {b0.x,b0.y,b0.z,b0.w,b1.x,b1.y,b1.z,b1.w};
      #pragma unroll
      for (int i = 0; i < 8; i++)
        #pragma unroll
        for (int j = 0; j < 8; j++)
          acc[i][j] += ar[i] * br[j];
    }
    __syncthreads();
  }
  #pragma unroll
  for (int i = 0; i < 8; i++) {
    float4 o0 = make_float4(acc[i][0], acc[i][1], acc[i][2], acc[i][3]);
    float4 o1 = make_float4(acc[i][4], acc[i][5], acc[i][6], acc[i][7]);
    *(float4*)&C[(m0 + ty*8 + i) * N + n0 + tx*8    ] = o0;
    *(float4*)&C[(m0 + ty*8 + i) * N + n0 + tx*8 + 4] = o1;
  }
}

__global__ __launch_bounds__(256) void gemm_nt64(
    const float* __restrict__ A, const float* __restrict__ B, float* __restrict__ C,
    int M, int N, int K, long sA, long sB, long sC)
{
  A += (long)blockIdx.z * sA; B += (long)blockIdx.z * sB; C += (long)blockIdx.z * sC;
  __shared__ float As[32][68], Bs[32][68];
  const int t = threadIdx.x;
  const int tx = t & 15, ty = t >> 4;
  const int m0 = blockIdx.y * 64, n0 = blockIdx.x * 64;
  float acc[4][4] = {};
  for (int k0 = 0; k0 < K; k0 += 32) {
    #pragma unroll
    for (int i = 0; i < 2; i++) {
      int f = t + i * 256;
      int r = f >> 3, k4 = f & 7;
      float4 va = *(const float4*)&A[(long)(m0 + r) * K + k0 + k4 * 4];
      As[k4*4+0][r] = va.x; As[k4*4+1][r] = va.y; As[k4*4+2][r] = va.z; As[k4*4+3][r] = va.w;
      float4 vb = *(const float4*)&B[(long)(n0 + r) * K + k0 + k4 * 4];
      Bs[k4*4+0][r] = vb.x; Bs[k4*4+1][r] = vb.y; Bs[k4*4+2][r] = vb.z; Bs[k4*4+3][r] = vb.w;
    }
    __syncthreads();
    #pragma unroll
    for (int kk = 0; kk < 32; kk++) {
      float4 a4 = *(const float4*)&As[kk][ty * 4];
      float4 b4 = *(const float4*)&Bs[kk][tx * 4];
      float ar[4] = {a4.x, a4.y, a4.z, a4.w};
      float br[4] = {b4.x, b4.y, b4.z, b4.w};
      #pragma unroll
      for (int i = 0; i < 4; i++)
        #pragma unroll
        for (int j = 0; j < 4; j++)
          acc[i][j] += ar[i] * br[j];
    }
    __syncthreads();
  }
  #pragma unroll
  for (int i = 0; i < 4; i++) {
    float4 o = make_float4(acc[i][0], acc[i][1], acc[i][2], acc[i][3]);
    *(float4*)&C[(long)(m0 + ty*4 + i) * N + n0 + tx*4] = o;
  }
}

// ================= bf16x3 MFMA NT GEMMs =================
// Fragment convention (HW-validated r6-r9): A: lane=(row&15)+16*(k>>3), elem=k&7;
// B: lane=(col&15)+16*(k>>3); D: col=lane&15, row=(lane>>4)*4+reg.
// LDS slot swizzle g = ((r15 ^ (kq<<1)) + 16*kq): within an 8-lane write phase
// (rows {r,r+1} x kq 0..3) bank-group = (row%8)^(2kq) -> all 8 distinct ->
// conflict-free ds_write_b128 (shift-2 left a 2-way alias: 4kq mod 8 degenerate).

// 128x128 tile, optional split-K (z = b*NS+ks), B shared across z. XCD-chunked remap.
__global__ __launch_bounds__(256) void gemm_nt128_b3(
    const ushort* __restrict__ Ah, const ushort* __restrict__ Al,
    const ushort* __restrict__ Bh, const ushort* __restrict__ Bl,
    float* __restrict__ C, int N, int K, long sA, long sC, int NS, int Kc)
{
  int bx, by, bz;
  xcd_remap(bx, by, bz);
  const int zb = bz / NS, ks = bz - zb * NS;
  Ah += (long)zb * sA + (long)ks * Kc;
  Al += (long)zb * sA + (long)ks * Kc;
  Bh += (long)ks * Kc;
  Bl += (long)ks * Kc;
  C  += (long)bz * sC;
  __shared__ ushort AhS[4096], AlS[4096], BhS[4096], BlS[4096];
  const int t = threadIdx.x;
  const int l = t & 63, w = t >> 6;
  const long m0 = (long)by * 128, n0 = (long)bx * 128;
  const int frA = (w & 1) * 4;
  const int frB = (w >> 1) * 4;
  const int rs = ((((l & 15) ^ ((l >> 4) << 1)) + 16 * (l >> 4))) * 8;  // swizzled read slot
  f32x4 acc[4][4] = {};
  for (int k0 = 0; k0 < Kc; k0 += 32) {
    #pragma unroll
    for (int p = 0; p < 2; p++) {
      int t2 = t + p * 256;
      int row = t2 >> 2, kq = t2 & 3;
      long goff = (m0 + row) * (long)K + k0 + kq * 8;
      long gofB = (n0 + row) * (long)K + k0 + kq * 8;
      int dst = (row >> 4) * 512 + ((((row & 15) ^ (kq << 1)) + 16 * kq)) * 8;
      *(uint4*)&AhS[dst] = *(const uint4*)(Ah + goff);
      *(uint4*)&AlS[dst] = *(const uint4*)(Al + goff);
      *(uint4*)&BhS[dst] = *(const uint4*)(Bh + gofB);
      *(uint4*)&BlS[dst] = *(const uint4*)(Bl + gofB);
    }
    __syncthreads();
    bf16x8 ah[4], al[4], bh[4], bl[4];
    #pragma unroll
    for (int i = 0; i < 4; i++) {
      ah[i] = *(const bf16x8*)&AhS[(frA + i) * 512 + rs];
      al[i] = *(const bf16x8*)&AlS[(frA + i) * 512 + rs];
      bh[i] = *(const bf16x8*)&BhS[(frB + i) * 512 + rs];
      bl[i] = *(const bf16x8*)&BlS[(frB + i) * 512 + rs];
    }
    #pragma unroll
    for (int i = 0; i < 4; i++)
      #pragma unroll
      for (int j = 0; j < 4; j++) {
        acc[i][j] = __builtin_amdgcn_mfma_f32_16x16x32_bf16(ah[i], bh[j], acc[i][j], 0, 0, 0);
        acc[i][j] = __builtin_amdgcn_mfma_f32_16x16x32_bf16(ah[i], bl[j], acc[i][j], 0, 0, 0);
        acc[i][j] = __builtin_amdgcn_mfma_f32_16x16x32_bf16(al[i], bh[j], acc[i][j], 0, 0, 0);
      }
    __syncthreads();
  }
  const long rbase = m0 + (w & 1) * 64 + (l >> 4) * 4;
  const int  cbase = (int)n0 + (w >> 1) * 64 + (l & 15);
  #pragma unroll
  for (int i = 0; i < 4; i++)
    #pragma unroll
    for (int j = 0; j < 4; j++)
      #pragma unroll
      for (int r = 0; r < 4; r++)
        C[(rbase + i * 16 + r) * N + cbase + j * 16] = acc[i][j][r];
}

// 64x128 tile, no split-K: A shared across z, B per-z. Used for st2. XCD remap.
__global__ __launch_bounds__(256) void gemm_nt64x128_b3(
    const ushort* __restrict__ Ah, const ushort* __restrict__ Al,
    const ushort* __restrict__ Bh, const ushort* __restrict__ Bl,
    float* __restrict__ C, int N, int K, long sB, long sC)
{
  int bx, by, bz;
  xcd_remap(bx, by, bz);
  Bh += (long)bz * sB; Bl += (long)bz * sB; C += (long)bz * sC;
  __shared__ ushort AhS[2048], AlS[2048], BhS[4096], BlS[4096];   // 24 KB
  const int t = threadIdx.x;
  const int l = t & 63, w = t >> 6;
  const long m0 = (long)by * 64, n0 = (long)bx * 128;
  const int wm = w & 1, wn = w >> 1;
  const int rs = ((((l & 15) ^ ((l >> 4) << 1)) + 16 * (l >> 4))) * 8;
  f32x4 acc[2][4] = {};
  for (int k0 = 0; k0 < K; k0 += 32) {
    {
      int row = t >> 2, kq = t & 3;
      long goff = (m0 + row) * (long)K + k0 + kq * 8;
      int dst = (row >> 4) * 512 + ((((row & 15) ^ (kq << 1)) + 16 * kq)) * 8;
      *(uint4*)&AhS[dst] = *(const uint4*)(Ah + goff);
      *(uint4*)&AlS[dst] = *(const uint4*)(Al + goff);
    }
    #pragma unroll
    for (int p = 0; p < 2; p++) {
      int t2 = t + p * 256;
      int row = t2 >> 2, kq = t2 & 3;
      long gofB = (n0 + row) * (long)K + k0 + kq * 8;
      int dst = (row >> 4) * 512 + ((((row & 15) ^ (kq << 1)) + 16 * kq)) * 8;
      *(uint4*)&BhS[dst] = *(const uint4*)(Bh + gofB);
      *(uint4*)&BlS[dst] = *(const uint4*)(Bl + gofB);
    }
    __syncthreads();
    bf16x8 ah[2], al[2], bh[4], bl[4];
    #pragma unroll
    for (int i = 0; i < 2; i++) {
      ah[i] = *(const bf16x8*)&AhS[(wm * 2 + i) * 512 + rs];
      al[i] = *(const bf16x8*)&AlS[(wm * 2 + i) * 512 + rs];
    }
    #pragma unroll
    for (int j = 0; j < 4; j++) {
      bh[j] = *(const bf16x8*)&BhS[(wn * 4 + j) * 512 + rs];
      bl[j] = *(const bf16x8*)&BlS[(wn * 4 + j) * 512 + rs];
    }
    #pragma unroll
    for (int i = 0; i < 2; i++)
      #pragma unroll
      for (int j = 0; j < 4; j++) {
        acc[i][j] = __builtin_amdgcn_mfma_f32_16x16x32_bf16(ah[i], bh[j], acc[i][j], 0, 0, 0);
        acc[i][j] = __builtin_amdgcn_mfma_f32_16x16x32_bf16(ah[i], bl[j], acc[i][j], 0, 0, 0);
        acc[i][j] = __builtin_amdgcn_mfma_f32_16x16x32_bf16(al[i], bh[j], acc[i][j], 0, 0, 0);
      }
    __syncthreads();
  }
  const long rbase = m0 + wm * 32 + (l >> 4) * 4;
  const int  cbase = (int)n0 + wn * 64 + (l & 15);
  #pragma unroll
  for (int i = 0; i < 2; i++)
    #pragma unroll
    for (int j = 0; j < 4; j++)
      #pragma unroll
      for (int r = 0; r < 4; r++)
        C[(rbase + i * 16 + r) * N + cbase + j * 16] = acc[i][j][r];
}

// ================= valsT: fold split-K pair + transpose + hilo, frag-ordered ========
__global__ __launch_bounds__(256) void cvt_valsT(
    const float* __restrict__ valsP, ushort* __restrict__ vTh, ushort* __restrict__ vTl,
    long slabStride)
{
  const int c = blockIdx.x, h = blockIdx.y, b = blockIdx.z;
  const int t = threadIdx.x;
  __shared__ float tile[32][68];
  const float* s0 = valsP + (long)(2 * b) * slabStride;
  const float* s1 = s0 + slabStride;
  {
    int r = t >> 3, c8 = (t & 7) * 8;
    long g = (long)(c * 32 + r) * EE + h * 64 + c8;
    float4 a0 = *(const float4*)&s0[g];     float4 b0 = *(const float4*)&s1[g];
    float4 a1 = *(const float4*)&s0[g + 4]; float4 b1 = *(const float4*)&s1[g + 4];
    a0.x += b0.x; a0.y += b0.y; a0.z += b0.z; a0.w += b0.w;
    a1.x += b1.x; a1.y += b1.y; a1.z += b1.z; a1.w += b1.w;
    *(float4*)&tile[r][c8] = a0;
    *(float4*)&tile[r][c8 + 4] = a1;
  }
  __syncthreads();
  const int f = t >> 6, l = t & 63;
  const int d = f * 16 + (l & 15), kq = l >> 4;
  float a[8];
  #pragma unroll
  for (int e = 0; e < 8; e++) a[e] = tile[kq * 8 + e][d];
  uint4 ph, pl;
  cvt8_pack(a, ph, pl);
  long obase = (((long)(b * HH + h) * 16 + c) * 2048) + (long)t * 8;
  *(uint4*)&vTh[obase] = ph;
  *(uint4*)&vTl[obase] = pl;
}

// ================= ctx via MFMA: r generated into LDS in A-frag order ================
__global__ __launch_bounds__(256) void nb_ctx_mf(
    const ushort* __restrict__ vTh, const ushort* __restrict__ vTl,
    const float* __restrict__ muq, const float* __restrict__ sg2,
    const float* __restrict__ bmu, const float* __restrict__ bsg,
    ushort* __restrict__ ctxh, ushort* __restrict__ ctxl,
    long sMu, long sC)
{
  int bx, by, bz;
  xcd_remap(bx, by, bz);
  const int h = by, b = bz;
  const long q0 = (long)bx * 128;
  const int t = threadIdx.x;
  const int l = t & 63, w = t >> 6, wm = w & 1, wn = w >> 1;
  __shared__ ushort AhS[4096], AlS[4096];
  __shared__ ushort BhS[2048], BlS[2048];
  __shared__ float mu_s[128], s2_s[128], bm_s[NB], bv_s[NB];
  const float* muqb = muq + (long)b * sMu;
  const float* sg2b = sg2 + (long)b * sMu;
  if (t < 128) {
    mu_s[t] = muqb[(long)h * QQ + q0 + t];
    s2_s[t] = sg2b[(long)h * QQ + q0 + t];
  }
  for (int i = t; i < NB; i += 256) {
    bm_s[i] = bmu[i];
    float x = bsg[i];
    bv_s[i] = x * x;
  }
  __syncthreads();
  const ushort* vThb = vTh + ((long)(b * HH + h) * 16) * 2048;
  const ushort* vTlb = vTl + ((long)(b * HH + h) * 16) * 2048;
  f32x4 acc[4][2] = {};
  for (int c = 0; c < 16; c++) {
    ((uint4*)BhS)[t] = ((const uint4*)(vThb + c * 2048))[t];
    ((uint4*)BlS)[t] = ((const uint4*)(vTlb + c * 2048))[t];
    #pragma unroll
    for (int p = 0; p < 2; p++) {
      int s = t + p * 256;
      int lf = s & 63;
      int q = ((s >> 6) << 4) + (lf & 15);
      int nb = c * 32 + (lf >> 4) * 8;
      float m = mu_s[q], s2 = s2_s[q];
      float a[8];
      #pragma unroll
      for (int e = 0; e < 8; e++) {
        float v = s2 + bv_s[nb + e];
        float d = m - bm_s[nb + e];
        float rv = __builtin_amdgcn_rcpf(v);
        a[e] = __expf(d * d * rv * -0.5f) * __builtin_amdgcn_rsqf(v * 6.2831853071795865f);
      }
      uint4 ph, pl;
      cvt8_pack(a, ph, pl);
      *(uint4*)&AhS[s * 8] = ph;
      *(uint4*)&AlS[s * 8] = pl;
    }
    __syncthreads();
    bf16x8 bhf[2], blf[2];
    #pragma unroll
    for (int j = 0; j < 2; j++) {
      bhf[j] = *(const bf16x8*)&BhS[(wn * 2 + j) * 512 + l * 8];
      blf[j] = *(const bf16x8*)&BlS[(wn * 2 + j) * 512 + l * 8];
    }
    #pragma unroll
    for (int i = 0; i < 4; i++) {
      bf16x8 ah = *(const bf16x8*)&AhS[(wm * 4 + i) * 512 + l * 8];
      bf16x8 al = *(const bf16x8*)&AlS[(wm * 4 + i) * 512 + l * 8];
      #pragma unroll
      for (int j = 0; j < 2; j++) {
        acc[i][j] = __builtin_amdgcn_mfma_f32_16x16x32_bf16(ah, bhf[j], acc[i][j], 0, 0, 0);
        acc[i][j] = __builtin_amdgcn_mfma_f32_16x16x32_bf16(ah, blf[j], acc[i][j], 0, 0, 0);
        acc[i][j] = __builtin_amdgcn_mfma_f32_16x16x32_bf16(al, bhf[j], acc[i][j], 0, 0, 0);
      }
    }
    __syncthreads();
  }
  ushort* ch = ctxh + (long)b * sC;
  ushort* cl = ctxl + (long)b * sC;
  const long rbase = q0 + wm * 64 + (l >> 4) * 4;
  const int  cbase = h * 64 + wn * 32 + (l & 15);
  #pragma unroll
  for (int i = 0; i < 4; i++)
    #pragma unroll
    for (int j = 0; j < 2; j++)
      #pragma unroll
      for (int r = 0; r < 4; r++) {
        long off = (rbase + i * 16 + r) * EE + cbase + j * 16;
        ushort hb, lb;
        hilo(acc[i][j][r], hb, lb);
        ch[off] = hb;
        cl[off] = lb;
      }
}

// ================= collapsed scores path =================
__global__ __launch_bounds__(256) void nb_uvec(
    const float* __restrict__ Bm, const float* __restrict__ wmu, const float* __restrict__ wsg,
    float* __restrict__ ump, float* __restrict__ usp, long sBm, long sU)
{
  Bm += (long)blockIdx.z * sBm; ump += (long)blockIdx.z * sU; usp += (long)blockIdx.z * sU;
  const int e = blockIdx.x * 256 + threadIdx.x;
  const int c = blockIdx.y;
  float am = 0.f, as = 0.f;
  #pragma unroll 8
  for (int n = c * 64; n < c * 64 + 64; n++) {
    float bv = Bm[(long)n * EE + e];
    am += wmu[n] * bv;
    as += wsg[n] * bv;
  }
  ump[(long)c * EE + e] = am;
  usp[(long)c * EE + e] = as;
}

__global__ __launch_bounds__(256) void nb_kw(
    const float* __restrict__ Wk, const float* __restrict__ ump, const float* __restrict__ usp,
    float* __restrict__ kwm, float* __restrict__ kws, long sU, long sK)
{
  ump += (long)blockIdx.z * sU; usp += (long)blockIdx.z * sU;
  kwm += (long)blockIdx.z * sK; kws += (long)blockIdx.z * sK;
  __shared__ float pm[256], ps[256];
  const int e = blockIdx.x, t = threadIdx.x;
  const float* row = Wk + (long)e * EE;
  float am = 0.f, as = 0.f;
  for (int i = t; i < EE; i += 256) {
    float um = 0.f, us = 0.f;
    #pragma unroll
    for (int c = 0; c < 8; c++) { um += ump[(long)c * EE + i]; us += usp[(long)c * EE + i]; }
    float w = row[i];
    am += w * um;
    as += w * us;
  }
  pm[t] = am; ps[t] = as;
  __syncthreads();
  for (int s = 128; s > 0; s >>= 1) {
    if (t < s) { pm[t] += pm[t + s]; ps[t] += ps[t + s]; }
    __syncthreads();
  }
  if (t == 0) { kwm[e] = pm[0]; kws[e] = ps[0]; }
}

__global__ __launch_bounds__(256) void nb_amas(
    const float* __restrict__ Wq, const float* __restrict__ kwm, const float* __restrict__ kws,
    float* __restrict__ AmAs, long sK, long sAm)
{
  kwm += (long)blockIdx.z * sK; kws += (long)blockIdx.z * sK;
  AmAs += (long)blockIdx.z * sAm;
  __shared__ float km[64], ks[64];
  const int t = threadIdx.x;
  const int h = blockIdx.y;
  const int e = blockIdx.x * 256 + t;
  if (t < 64) { km[t] = kwm[h * 64 + t]; ks[t] = kws[h * 64 + t]; }
  __syncthreads();
  float am = 0.f, as = 0.f;
  #pragma unroll 8
  for (int d = 0; d < 64; d++) {
    float w = Wq[(long)(h * 64 + d) * EE + e];
    am += km[d] * w;
    as += ks[d] * w;
  }
  AmAs[(long)e * 32 + h]      = am;
  AmAs[(long)e * 32 + 16 + h] = as;
}

// 8 q-rows per block: AmAs L2 traffic /8 vs the per-row version.
__global__ __launch_bounds__(256) void nb_musig8(
    const float* __restrict__ qb, const float* __restrict__ AmAs,
    float* __restrict__ muq, float* __restrict__ sg2, long sQ, long sAm, long sMu)
{
  qb += (long)blockIdx.z * sQ; AmAs += (long)blockIdx.z * sAm;
  muq += (long)blockIdx.z * sMu; sg2 += (long)blockIdx.z * sMu;
  __shared__ float qs[8 * EE];       // 32 KB
  const int t = threadIdx.x;
  const long q0 = (long)blockIdx.x * 8;
  for (int i = t * 4; i < 8 * EE; i += 1024)
    *(float4*)&qs[i] = *(const float4*)&qb[q0 * EE + i];
  __syncthreads();
  const int o = t & 31, row = t >> 5;
  const float* qr = qs + row * EE;
  float acc = 0.f;
  #pragma unroll 8
  for (int e = 0; e < EE; e++)
    acc += qr[e] * AmAs[(long)e * 32 + o];
  float s = acc * 0.125f;
  if (o < 16) {
    muq[(long)o * QQ + q0 + row] = 1.f / (1.f + expf(-s));
  } else {
    float sp = (s > 20.f) ? s : log1pf(expf(s));
    sg2[(long)(o - 16) * QQ + q0 + row] = fmaxf(sp, 1e-4f);
  }
}

// tier-2 per-row musig (proven)
__global__ __launch_bounds__(256) void nb_musig(
    const float* __restrict__ qb, const float* __restrict__ AmAs,
    float* __restrict__ muq, float* __restrict__ sg2, long sQ, long sAm, long sMu)
{
  qb += (long)blockIdx.z * sQ; AmAs += (long)blockIdx.z * sAm;
  muq += (long)blockIdx.z * sMu; sg2 += (long)blockIdx.z * sMu;
  __shared__ float qs[EE];
  __shared__ float part[8][32];
  const int t = threadIdx.x, qrow = blockIdx.x;
  for (int i = t; i < EE; i += 256) qs[i] = qb[(long)qrow * EE + i];
  __syncthreads();
  const int o = t & 31, ch = t >> 5;
  float acc = 0.f;
  const int e0 = ch * 128;
  #pragma unroll 8
  for (int i = 0; i < 128; i++) {
    int e = e0 + i;
    acc += qs[e] * AmAs[(long)e * 32 + o];
  }
  part[ch][o] = acc;
  __syncthreads();
  if (t < 32) {
    float s = 0.f;
    #pragma unroll
    for (int c = 0; c < 8; c++) s += part[c][o];
    s *= 0.125f;
    if (o < 16) {
      muq[(long)o * QQ + qrow] = 1.f / (1.f + expf(-s));
    } else {
      float sp = (s > 20.f) ? s : log1pf(expf(s));
      sg2[(long)(o - 16) * QQ + qrow] = fmaxf(sp, 1e-4f);
    }
  }
}

// ================= tier-2 ctx (fp32, proven) =================
__global__ __launch_bounds__(128) void nb_ctx128(
    const float* __restrict__ vals, const float* __restrict__ muq, const float* __restrict__ sg2,
    const float* __restrict__ bmu,  const float* __restrict__ bsg, float* __restrict__ ctx,
    long sV, long sMu, long sC)
{
  vals += (long)blockIdx.z * sV; ctx += (long)blockIdx.z * sC;
  muq += (long)blockIdx.z * sMu; sg2 += (long)blockIdx.z * sMu;
  __shared__ float As[32][132], Bs[32][68];
  __shared__ __align__(16) float mu_s[128], s2_s[128];
  const int t = threadIdx.x;
  const int tx = t & 7, ty = t >> 3;
  const long q0 = (long)blockIdx.x * 128;
  const int h = blockIdx.y;
  mu_s[t] = muq[(long)h * QQ + q0 + t];
  s2_s[t] = sg2[(long)h * QQ + q0 + t];
  __syncthreads();
  float acc[8][8] = {};
  for (int n0 = 0; n0 < NB; n0 += 32) {
    #pragma unroll
    for (int i = 0; i < 4; i++) {
      int f = t + i * 128;
      int r = f >> 4, c4 = f & 15;
      *(float4*)&Bs[r][c4 * 4] = *(const float4*)&vals[(long)(n0 + r) * EE + h * 64 + c4 * 4];
    }
    #pragma unroll
    for (int i = 0; i < 8; i++) {
      int idx = t + i * 128;
      int n = idx >> 5, qg = idx & 31;
      float bm = bmu[n0 + n], bs = bsg[n0 + n];
      float bs2 = bs * bs;
      float4 m4 = *(const float4*)&mu_s[qg * 4];
      float4 s4 = *(const float4*)&s2_s[qg * 4];
      float4 rr;
      {
        float v0 = s4.x + bs2, d0 = m4.x - bm;
        float v1 = s4.y + bs2, d1 = m4.y - bm;
        float v2 = s4.z + bs2, d2 = m4.z - bm;
        float v3 = s4.w + bs2, d3 = m4.w - bm;
        float r0 = __builtin_amdgcn_rcpf(v0), r1 = __builtin_amdgcn_rcpf(v1);
        float r2 = __builtin_amdgcn_rcpf(v2), r3 = __builtin_amdgcn_rcpf(v3);
        rr.x = __expf(d0 * d0 * r0 * -0.5f) * __builtin_amdgcn_rsqf(v0 * 6.2831853071795865f);
        rr.y = __expf(d1 * d1 * r1 * -0.5f) * __builtin_amdgcn_rsqf(v1 * 6.2831853071795865f);
        rr.z = __expf(d2 * d2 * r2 * -0.5f) * __builtin_amdgcn_rsqf(v2 * 6.2831853071795865f);
        rr.w = __expf(d3 * d3 * r3 * -0.5f) * __builtin_amdgcn_rsqf(v3 * 6.2831853071795865f);
      }
      *(float4*)&As[n][qg * 4] = rr;
    }
    __syncthreads();
    #pragma unroll
    for (int kk = 0; kk < 32; kk++) {
      float4 a0 = *(const float4*)&As[kk][ty*8];
      float4 a1 = *(const float4*)&As[kk][ty*8+4];
      float4 b0 = *(const float4*)&Bs[kk][tx*8];
      float4 b1 = *(const float4*)&Bs[kk][tx*8+4];
      float ar[8] = {a0.x,a0.y,a0.z,a0.w,a1.x,a1.y,a1.z,a1.w};
      float br[8] = {b0.x,b0.y,b0.z,b0.w,b1.x,b1.y,b1.z,b1.w};
      #pragma unroll
      for (int i = 0; i < 8; i++)
        #pragma unroll
        for (int j = 0; j < 8; j++)
          acc[i][j] += ar[i] * br[j];
    }
    __syncthreads();
  }
  #pragma unroll
  for (int i = 0; i < 8; i++) {
    float4 o0 = make_float4(acc[i][0], acc[i][1], acc[i][2], acc[i][3]);
    float4 o1 = make_float4(acc[i][4], acc[i][5], acc[i][6], acc[i][7]);
    *(float4*)&ctx[(q0 + ty*8 + i) * EE + h * 64 + tx*8    ] = o0;
    *(float4*)&ctx[(q0 + ty*8 + i) * EE + h * 64 + tx*8 + 4] = o1;
  }
}

extern "C" void kernel_launch(void* const* d_in, const int* in_sizes, int n_in,
                              void* d_out, int out_size, void* d_ws, size_t ws_size,
                              hipStream_t stream) {
  const float* k   = (const float*)d_in[0];
  const float* q   = (const float*)d_in[1];
  const float* Wq  = (const float*)d_in[2];
  const float* Wk  = (const float*)d_in[3];
  const float* Wv  = (const float*)d_in[4];
  const float* Wo  = (const float*)d_in[5];
  const float* wmu = (const float*)d_in[6];
  const float* wsg = (const float*)d_in[7];
  const float* Gs  = (const float*)d_in[8];
  const float* bmu = (const float*)d_in[9];
  const float* bsg = (const float*)d_in[10];
  float* out = (float*)d_out;
  char* ws = (char*)d_ws;

  const long sBm = (long)NB * EE;
  const long sU  = 8L * EE;
  const long sK  = EE;
  const long sAm = 32L * EE;
  const long sMu = (long)HH * QQ;
  const long sQ  = (long)QQ * EE;

  if (ws_size >= (50u << 20)) {
    // ---- tier 1 (50 MiB), lifetimes verified disjoint (same as r8/r9) ----
    ushort* kTh  = (ushort*)(ws + 0);
    ushort* kTl  = (ushort*)(ws + (16u << 20));
    ushort* GsTh = (ushort*)(ws + (32u << 20));
    ushort* GsTl = (ushort*)(ws + (34u << 20));
    float*  Bm4  = (float*)(ws + (40u << 20));
    ushort* Bmh  = (ushort*)(ws + 0);
    ushort* Bml  = (ushort*)(ws + (4u << 20));
    ushort* Wvh  = (ushort*)(ws + (8u << 20));
    ushort* Wvl  = (ushort*)(ws + (10u << 20));
    float*  valsP= (float*)(ws + (16u << 20));
    ushort* vTh  = (ushort*)(ws + (32u << 20));
    ushort* vTl  = (ushort*)(ws + (36u << 20));
    ushort* Woh  = (ushort*)(ws + (40u << 20));
    ushort* Wol  = (ushort*)(ws + (42u << 20));
    ushort* ctxh = (ushort*)(ws + 0);
    ushort* ctxl = (ushort*)(ws + (16u << 20));
    char*  sm    = ws + (48u << 20);
    float* ump4  = (float*)(sm);
    float* usp4  = (float*)(sm + (128u << 10));
    float* kwm4  = (float*)(sm + (256u << 10));
    float* kws4  = (float*)(sm + (272u << 10));
    float* AmAs4 = (float*)(sm + (288u << 10));
    float* muq4  = (float*)(sm + (800u << 10));
    float* sg24  = (float*)(sm + (1312u << 10));

    // S1: transposed hilo operands for st2
    cvt_hiloT<<<dim3(NB/32, LL/32, 1),  256, 0, stream>>>(Gs, GsTh, GsTl, LL, NB, 0L, 0L);
    cvt_hiloT<<<dim3(EE/32, LL/32, BB), 256, 0, stream>>>(k, kTh, kTl, LL, EE,
                                                          (long)LL*EE, (long)LL*EE);
    // st2 (MFMA bf16x3, swizzled + XCD remap): Bm4[nb][e] = sum_l GsT[nb][l]*kT[e][l]
    gemm_nt64x128_b3<<<dim3(EE/128, NB/64, BB), 256, 0, stream>>>(
        GsTh, GsTl, kTh, kTl, Bm4, EE, LL, (long)LL*EE, sBm);
    // scores chain
    nb_uvec  <<<dim3(EE/256, 8, BB),  256, 0, stream>>>(Bm4, wmu, wsg, ump4, usp4, sBm, sU);
    nb_kw    <<<dim3(EE, 1, BB),      256, 0, stream>>>(Wk, ump4, usp4, kwm4, kws4, sU, sK);
    nb_amas  <<<dim3(EE/256, HH, BB), 256, 0, stream>>>(Wq, kwm4, kws4, AmAs4, sK, sAm);
    nb_musig8<<<dim3(QQ/8, 1, BB),    256, 0, stream>>>(q, AmAs4, muq4, sg24, sQ, sAm, sMu);
    // Bm -> hilo (kT dead), then Wv+Wo -> hilo fused
    cvt_hilo<<<dim3(256), 256, 0, stream>>>(Bm4, Bmh, Bml, (long)BB * sBm);
    cvt_hilo2<<<dim3(128, 2), 256, 0, stream>>>(Wv, Wvh, Wvl, Wo, Woh, Wol, (long)EE * EE);
    // st3 (MFMA bf16x3): vals slabs = Bm @ Wv^T, split-K=2
    gemm_nt128_b3<<<dim3(EE/128, NB/128, BB*2), 256, 0, stream>>>(
        Bmh, Bml, Wvh, Wvl, valsP, EE, EE, sBm, sBm, 2, EE/2);
    // valsT frag-ordered hilo (GsT dead)
    cvt_valsT<<<dim3(16, HH, BB), 256, 0, stream>>>(valsP, vTh, vTl, sBm);
    // ctx (MFMA bf16x3, XCD remap) -> ctx hilo planes
    nb_ctx_mf<<<dim3(QQ/128, HH, BB), 256, 0, stream>>>(
        vTh, vTl, muq4, sg24, bmu, bsg, ctxh, ctxl, sMu, sQ);
    // st7 (MFMA bf16x3, swizzled + XCD remap): out = ctx @ Wo^T
    gemm_nt128_b3<<<dim3(EE/128, QQ/128, BB), 256, 0, stream>>>(
        ctxh, ctxl, Woh, Wol, out, EE, EE, sQ, sQ, 1, EE);
  } else {
    // ---- tier 2 (ws >= 26 MiB, all-fp32 proven path) ----
    float* BmP   = (float*)(ws + 0);
    float* ctxS  = (float*)(ws + 0);
    float* vals4 = (float*)(ws + (16u << 20));
    char*  sm    = ws + (24u << 20);
    float* ump4  = (float*)(sm);
    float* usp4  = (float*)(sm + (128u << 10));
    float* kwm4  = (float*)(sm + (256u << 10));
    float* kws4  = (float*)(sm + (272u << 10));
    float* AmAs4 = (float*)(sm + (288u << 10));
    float* muq4  = (float*)(sm + (800u << 10));
    float* sg24  = (float*)(sm + (1312u << 10));

    gemm_tn128<<<dim3(EE/128, NB/128, BB*2), 256, 0, stream>>>(
        Gs, k, BmP, NB, EE, 0L, (long)LL*EE, sBm, 2, LL/2);
    add_pairs<<<dim3(256, 1, BB), 256, 0, stream>>>(BmP, 2*sBm, BmP, 2*sBm, sBm);
    gemm_nt128<<<dim3(EE/128, NB/128, BB), 256, 0, stream>>>(
        BmP, Wv, vals4, EE, EE, 2*sBm, 0L, sBm, 1, EE);
    nb_uvec  <<<dim3(EE/256, 8, BB),  256, 0, stream>>>(BmP, wmu, wsg, ump4, usp4, 2*sBm, sU);
    nb_kw    <<<dim3(EE, 1, BB),      256, 0, stream>>>(Wk, ump4, usp4, kwm4, kws4, sU, sK);
    nb_amas  <<<dim3(EE/256, HH, BB), 256, 0, stream>>>(Wq, kwm4, kws4, AmAs4, sK, sAm);
    nb_musig <<<dim3(QQ, 1, BB),      256, 0, stream>>>(q, AmAs4, muq4, sg24, sQ, sAm, sMu);
    for (int b = 0; b < BB; b++) {
      nb_ctx128<<<dim3(QQ/128, HH, 1), 128, 0, stream>>>(
          vals4 + (long)b*sBm, muq4 + (long)b*sMu, sg24 + (long)b*sMu,
          bmu, bsg, ctxS, 0L, 0L, 0L);
      gemm_nt64<<<dim3(EE/64, QQ/64, 1), 256, 0, stream>>>(
          ctxS, Wo, out + (long)b*sQ, QQ, EE, EE, 0L, 0L, 0L);
    }
  }
  (void)in_sizes; (void)n_in; (void)out_size;
}

// Round 11
// 392.199 us; speedup vs baseline: 2.2312x; 1.0347x over previous
//
#include <hip/hip_runtime.h>

#define BB 4
#define LL 2048
#define QQ 2048
#define HH 16
#define DD 64
#define EE 1024
#define NB 512

typedef __attribute__((ext_vector_type(8))) short bf16x8;   // 8 bf16 (4 VGPRs)
typedef __attribute__((ext_vector_type(4))) float f32x4;    // MFMA acc

// hw bf16 convert (RNE on gfx950, lowers to v_cvt_pk_bf16_f32 when paired).
// hilo is self-correcting: lo = x - hi_f captures hi's rounding residual.
__device__ inline ushort bf16_rne(float f) {
  __bf16 b = static_cast<__bf16>(f);
  return __builtin_bit_cast(ushort, b);
}
__device__ inline float bf16_f(ushort h) { return __uint_as_float((uint)h << 16); }
__device__ inline void hilo(float x, ushort& h, ushort& l) {
  h = bf16_rne(x);
  l = bf16_rne(x - bf16_f(h));
}

// pack 8 floats -> hi/lo bf16 uint4s
__device__ inline void cvt8_pack(const float* a, uint4& ph, uint4& pl) {
  ushort h[8], l[8];
  #pragma unroll
  for (int j = 0; j < 8; j++) hilo(a[j], h[j], l[j]);
  ph = make_uint4((uint)h[0] | ((uint)h[1] << 16), (uint)h[2] | ((uint)h[3] << 16),
                  (uint)h[4] | ((uint)h[5] << 16), (uint)h[6] | ((uint)h[7] << 16));
  pl = make_uint4((uint)l[0] | ((uint)l[1] << 16), (uint)l[2] | ((uint)l[3] << 16),
                  (uint)l[4] | ((uint)l[5] << 16), (uint)l[6] | ((uint)l[7] << 16));
}

// XCD-chunked bijective block remap (nwg % 8 == 0 at all call sites).
__device__ inline void xcd_remap(int& bx, int& by, int& bz) {
  int gx = gridDim.x, gy = gridDim.y;
  int nwg = gx * gy * (int)gridDim.z;
  int lin = blockIdx.x + gx * (blockIdx.y + gy * blockIdx.z);
  int swz = (lin & 7) * (nwg >> 3) + (lin >> 3);
  bx = swz % gx; int tmp = swz / gx; by = tmp % gy; bz = tmp / gy;
}

// ---------- x (fp32, n elems) -> hi/lo bf16 planes (same layout) ----------
__global__ __launch_bounds__(256) void cvt_hilo(
    const float* __restrict__ x, ushort* __restrict__ hi, ushort* __restrict__ lo, long n)
{
  long i0 = ((long)blockIdx.x * 256 + threadIdx.x) * 8;
  long stride = (long)gridDim.x * 2048;
  for (long i = i0; i < n; i += stride) {
    float a[8];
    *(float4*)&a[0] = *(const float4*)&x[i];
    *(float4*)&a[4] = *(const float4*)&x[i + 4];
    uint4 ph, pl;
    cvt8_pack(a, ph, pl);
    *(uint4*)&hi[i] = ph;
    *(uint4*)&lo[i] = pl;
  }
}

// ---------- transpose + hilo: x fp32 [R][C] -> hi/lo [C][R] ----------
__global__ __launch_bounds__(256) void cvt_hiloT(
    const float* __restrict__ x, ushort* __restrict__ hiT, ushort* __restrict__ loT,
    int R, int C, long zIn, long zOut)
{
  x += (long)blockIdx.z * zIn; hiT += (long)blockIdx.z * zOut; loT += (long)blockIdx.z * zOut;
  __shared__ float tile[32][33];
  const int t = threadIdx.x;
  const long r0 = (long)blockIdx.y * 32, c0 = (long)blockIdx.x * 32;
  {
    int row = t >> 3, c4 = t & 7;
    float4 v = *(const float4*)&x[(r0 + row) * C + c0 + c4 * 4];
    tile[row][c4*4+0] = v.x; tile[row][c4*4+1] = v.y;
    tile[row][c4*4+2] = v.z; tile[row][c4*4+3] = v.w;
  }
  __syncthreads();
  {
    int col = t >> 3, r4 = t & 7;
    ushort h[4], l[4];
    #pragma unroll
    for (int j = 0; j < 4; j++) hilo(tile[r4 * 4 + j][col], h[j], l[j]);
    uint2 ph = make_uint2((uint)h[0] | ((uint)h[1] << 16), (uint)h[2] | ((uint)h[3] << 16));
    uint2 pl = make_uint2((uint)l[0] | ((uint)l[1] << 16), (uint)l[2] | ((uint)l[3] << 16));
    long o = (c0 + col) * (long)R + r0 + r4 * 4;
    *(uint2*)&hiT[o] = ph;
    *(uint2*)&loT[o] = pl;
  }
}

// ---------- dst[z] = src[2z] + src[2z+1] (tier-2) ----------
__global__ __launch_bounds__(256) void add_pairs(
    float* __restrict__ dst, long dstStride,
    const float* __restrict__ src, long srcPairStride, long n)
{
  float* d = dst + (long)blockIdx.z * dstStride;
  const float* s0 = src + (long)blockIdx.z * srcPairStride;
  const float* s1 = s0 + n;
  long i0 = ((long)blockIdx.x * 256 + threadIdx.x) * 4;
  long stride = (long)gridDim.x * 1024;
  for (long i = i0; i < n; i += stride) {
    float4 a = *(const float4*)&s0[i];
    float4 b = *(const float4*)&s1[i];
    a.x += b.x; a.y += b.y; a.z += b.z; a.w += b.w;
    *(float4*)&d[i] = a;
  }
}

// ================= fp32 GEMMs (tier-2 only) =================

__global__ __launch_bounds__(256) void gemm_nt128(
    const float* __restrict__ A, const float* __restrict__ B, float* __restrict__ C,
    int N, int K, long sA, long sB, long sC, int NS, int Kc)
{
  const int z = blockIdx.z;
  const int b = z / NS, ks = z - b * NS;
  A += (long)b * sA + (long)ks * Kc;
  B += (long)b * sB + (long)ks * Kc;
  C += (long)z * sC;
  __shared__ float As[32][132], Bs[32][132];
  const int t = threadIdx.x;
  const int tx = t & 15, ty = t >> 4;
  const long m0 = (long)blockIdx.y * 128, n0 = (long)blockIdx.x * 128;
  float acc[8][8] = {};
  for (int k0 = 0; k0 < Kc; k0 += 32) {
    #pragma unroll
    for (int i = 0; i < 4; i++) {
      int f = t + i * 256;
      int r = f >> 3, k4 = f & 7;
      float4 va = *(const float4*)&A[(m0 + r) * K + k0 + k4 * 4];
      As[k4*4+0][r] = va.x; As[k4*4+1][r] = va.y; As[k4*4+2][r] = va.z; As[k4*4+3][r] = va.w;
      float4 vb = *(const float4*)&B[(n0 + r) * K + k0 + k4 * 4];
      Bs[k4*4+0][r] = vb.x; Bs[k4*4+1][r] = vb.y; Bs[k4*4+2][r] = vb.z; Bs[k4*4+3][r] = vb.w;
    }
    __syncthreads();
    #pragma unroll
    for (int kk = 0; kk < 32; kk++) {
      float4 a0 = *(const float4*)&As[kk][ty*8];
      float4 a1 = *(const float4*)&As[kk][ty*8+4];
      float4 b0 = *(const float4*)&Bs[kk][tx*8];
      float4 b1 = *(const float4*)&Bs[kk][tx*8+4];
      float ar[8] = {a0.x,a0.y,a0.z,a0.w,a1.x,a1.y,a1.z,a1.w};
      float br[8] = {b0.x,b0.y,b0.z,b0.w,b1.x,b1.y,b1.z,b1.w};
      #pragma unroll
      for (int i = 0; i < 8; i++)
        #pragma unroll
        for (int j = 0; j < 8; j++)
          acc[i][j] += ar[i] * br[j];
    }
    __syncthreads();
  }
  #pragma unroll
  for (int i = 0; i < 8; i++) {
    float4 o0 = make_float4(acc[i][0], acc[i][1], acc[i][2], acc[i][3]);
    float4 o1 = make_float4(acc[i][4], acc[i][5], acc[i][6], acc[i][7]);
    *(float4*)&C[(m0 + ty*8 + i) * N + n0 + tx*8    ] = o0;
    *(float4*)&C[(m0 + ty*8 + i) * N + n0 + tx*8 + 4] = o1;
  }
}

__global__ __launch_bounds__(256) void gemm_tn128(
    const float* __restrict__ A, const float* __restrict__ B, float* __restrict__ C,
    int M, int N, long sA, long sB, long sC, int NS, int Kc)
{
  const int z = blockIdx.z;
  const int b = z / NS, ks = z - b * NS;
  A += (long)b * sA + (long)ks * Kc * M;
  B += (long)b * sB + (long)ks * Kc * N;
  C += (long)z * sC;
  __shared__ float As[32][132], Bs[32][132];
  const int t = threadIdx.x;
  const int tx = t & 15, ty = t >> 4;
  const long m0 = (long)blockIdx.y * 128, n0 = (long)blockIdx.x * 128;
  float acc[8][8] = {};
  for (int k0 = 0; k0 < Kc; k0 += 32) {
    #pragma unroll
    for (int i = 0; i < 4; i++) {
      int f = t + i * 256;
      int r = f >> 5, c4 = f & 31;
      *(float4*)&As[r][c4 * 4] = *(const float4*)&A[(long)(k0 + r) * M + m0 + c4 * 4];
      *(float4*)&Bs[r][c4 * 4] = *(const float4*)&B[(long)(k0 + r) * N + n0 + c4 * 4];
    }
    __syncthreads();
    #pragma unroll
    for (int kk = 0; kk < 32; kk++) {
      float4 a0 = *(const float4*)&As[kk][ty*8];
      float4 a1 = *(const float4*)&As[kk][ty*8+4];
      float4 b0 = *(const float4*)&Bs[kk][tx*8];
      float4 b1 = *(const float4*)&Bs[kk][tx*8+4];
      float ar[8] = {a0.x,a0.y,a0.z,a0.w,a1.x,a1.y,a1.z,a1.w};
      float br[8] = {b0.x,b0.y,b0.z,b0.w,b1.x,b1.y,b1.z,b1.w};
      #pragma unroll
      for (int i = 0; i < 8; i++)
        #pragma unroll
        for (int j = 0; j < 8; j++)
          acc[i][j] += ar[i] * br[j];
    }
    __syncthreads();
  }
  #pragma unroll
  for (int i = 0; i < 8; i++) {
    float4 o0 = make_float4(acc[i][0], acc[i][1], acc[i][2], acc[i][3]);
    float4 o1 = make_float4(acc[i][4], acc[i][5], acc[i][6], acc[i][7]);
    *(float4*)&C[(m0 + ty*8 + i) * N + n0 + tx*8    ] = o0;
    *(float4*)&C[(m0 + ty*8 + i) * N + n0 + tx*8 + 4] = o1;
  }
}

__global__ __launch_bounds__(256) void gemm_nt64(
    const float* __restrict__ A, const float* __restrict__ B, float* __restrict__ C,
    int M, int N, int K, long sA, long sB, long sC)
{
  A += (long)blockIdx.z * sA; B += (long)blockIdx.z * sB; C += (long)blockIdx.z * sC;
  __shared__ float As[32][68], Bs[32][68];
  const int t = threadIdx.x;
  const int tx = t & 15, ty = t >> 4;
  const int m0 = blockIdx.y * 64, n0 = blockIdx.x * 64;
  float acc[4][4] = {};
  for (int k0 = 0; k0 < K; k0 += 32) {
    #pragma unroll
    for (int i = 0; i < 2; i++) {
      int f = t + i * 256;
      int r = f >> 3, k4 = f & 7;
      float4 va = *(const float4*)&A[(long)(m0 + r) * K + k0 + k4 * 4];
      As[k4*4+0][r] = va.x; As[k4*4+1][r] = va.y; As[k4*4+2][r] = va.z; As[k4*4+3][r] = va.w;
      float4 vb = *(const float4*)&B[(long)(n0 + r) * K + k0 + k4 * 4];
      Bs[k4*4+0][r] = vb.x; Bs[k4*4+1][r] = vb.y; Bs[k4*4+2][r] = vb.z; Bs[k4*4+3][r] = vb.w;
    }
    __syncthreads();
    #pragma unroll
    for (int kk = 0; kk < 32; kk++) {
      float4 a4 = *(const float4*)&As[kk][ty * 4];
      float4 b4 = *(const float4*)&Bs[kk][tx * 4];
      float ar[4] = {a4.x, a4.y, a4.z, a4.w};
      float br[4] = {b4.x, b4.y, b4.z, b4.w};
      #pragma unroll
      for (int i = 0; i < 4; i++)
        #pragma unroll
        for (int j = 0; j < 4; j++)
          acc[i][j] += ar[i] * br[j];
    }
    __syncthreads();
  }
  #pragma unroll
  for (int i = 0; i < 4; i++) {
    float4 o = make_float4(acc[i][0], acc[i][1], acc[i][2], acc[i][3]);
    *(float4*)&C[(long)(m0 + ty*4 + i) * N + n0 + tx*4] = o;
  }
}

// ================= bf16x3 MFMA NT GEMMs =================
// Fragment convention (HW-validated r6-r10): A: lane=(row&15)+16*(k>>3), elem=k&7;
// B: lane=(col&15)+16*(k>>3); D: col=lane&15, row=(lane>>4)*4+reg.
// LDS slot swizzle g = ((r15 ^ (kq<<1)) + 16*kq): conflict-free ds_write_b128/read.

// 128x128 tile (st7), fp32 out, XCD remap.
__global__ __launch_bounds__(256) void gemm_nt128_b3(
    const ushort* __restrict__ Ah, const ushort* __restrict__ Al,
    const ushort* __restrict__ Bh, const ushort* __restrict__ Bl,
    float* __restrict__ C, int N, int K, long sA, long sC, int NS, int Kc)
{
  int bx, by, bz;
  xcd_remap(bx, by, bz);
  const int zb = bz / NS, ks = bz - zb * NS;
  Ah += (long)zb * sA + (long)ks * Kc;
  Al += (long)zb * sA + (long)ks * Kc;
  Bh += (long)ks * Kc;
  Bl += (long)ks * Kc;
  C  += (long)bz * sC;
  __shared__ ushort AhS[4096], AlS[4096], BhS[4096], BlS[4096];
  const int t = threadIdx.x;
  const int l = t & 63, w = t >> 6;
  const long m0 = (long)by * 128, n0 = (long)bx * 128;
  const int frA = (w & 1) * 4;
  const int frB = (w >> 1) * 4;
  const int rs = ((((l & 15) ^ ((l >> 4) << 1)) + 16 * (l >> 4))) * 8;
  f32x4 acc[4][4] = {};
  for (int k0 = 0; k0 < Kc; k0 += 32) {
    #pragma unroll
    for (int p = 0; p < 2; p++) {
      int t2 = t + p * 256;
      int row = t2 >> 2, kq = t2 & 3;
      long goff = (m0 + row) * (long)K + k0 + kq * 8;
      long gofB = (n0 + row) * (long)K + k0 + kq * 8;
      int dst = (row >> 4) * 512 + ((((row & 15) ^ (kq << 1)) + 16 * kq)) * 8;
      *(uint4*)&AhS[dst] = *(const uint4*)(Ah + goff);
      *(uint4*)&AlS[dst] = *(const uint4*)(Al + goff);
      *(uint4*)&BhS[dst] = *(const uint4*)(Bh + gofB);
      *(uint4*)&BlS[dst] = *(const uint4*)(Bl + gofB);
    }
    __syncthreads();
    bf16x8 ah[4], al[4], bh[4], bl[4];
    #pragma unroll
    for (int i = 0; i < 4; i++) {
      ah[i] = *(const bf16x8*)&AhS[(frA + i) * 512 + rs];
      al[i] = *(const bf16x8*)&AlS[(frA + i) * 512 + rs];
      bh[i] = *(const bf16x8*)&BhS[(frB + i) * 512 + rs];
      bl[i] = *(const bf16x8*)&BlS[(frB + i) * 512 + rs];
    }
    #pragma unroll
    for (int i = 0; i < 4; i++)
      #pragma unroll
      for (int j = 0; j < 4; j++) {
        acc[i][j] = __builtin_amdgcn_mfma_f32_16x16x32_bf16(ah[i], bh[j], acc[i][j], 0, 0, 0);
        acc[i][j] = __builtin_amdgcn_mfma_f32_16x16x32_bf16(ah[i], bl[j], acc[i][j], 0, 0, 0);
        acc[i][j] = __builtin_amdgcn_mfma_f32_16x16x32_bf16(al[i], bh[j], acc[i][j], 0, 0, 0);
      }
    __syncthreads();
  }
  const long rbase = m0 + (w & 1) * 64 + (l >> 4) * 4;
  const int  cbase = (int)n0 + (w >> 1) * 64 + (l & 15);
  #pragma unroll
  for (int i = 0; i < 4; i++)
    #pragma unroll
    for (int j = 0; j < 4; j++)
      #pragma unroll
      for (int r = 0; r < 4; r++)
        C[(rbase + i * 16 + r) * N + cbase + j * 16] = acc[i][j][r];
}

// 64x128 tile, no split-K, A shared across z, B per-z, OUTPUT = hi/lo ushort planes.
// Used for st2 (GsT x kT -> Bm) and st3T (Wv x Bm -> vals^T). XCD remap.
__global__ __launch_bounds__(256) void gemm_nt64x128_b3_us(
    const ushort* __restrict__ Ah, const ushort* __restrict__ Al,
    const ushort* __restrict__ Bh, const ushort* __restrict__ Bl,
    ushort* __restrict__ Ch, ushort* __restrict__ Cl, int N, int K, long sB, long sC)
{
  int bx, by, bz;
  xcd_remap(bx, by, bz);
  Bh += (long)bz * sB; Bl += (long)bz * sB;
  Ch += (long)bz * sC; Cl += (long)bz * sC;
  __shared__ ushort AhS[2048], AlS[2048], BhS[4096], BlS[4096];   // 24 KB
  const int t = threadIdx.x;
  const int l = t & 63, w = t >> 6;
  const long m0 = (long)by * 64, n0 = (long)bx * 128;
  const int wm = w & 1, wn = w >> 1;
  const int rs = ((((l & 15) ^ ((l >> 4) << 1)) + 16 * (l >> 4))) * 8;
  f32x4 acc[2][4] = {};
  for (int k0 = 0; k0 < K; k0 += 32) {
    {
      int row = t >> 2, kq = t & 3;
      long goff = (m0 + row) * (long)K + k0 + kq * 8;
      int dst = (row >> 4) * 512 + ((((row & 15) ^ (kq << 1)) + 16 * kq)) * 8;
      *(uint4*)&AhS[dst] = *(const uint4*)(Ah + goff);
      *(uint4*)&AlS[dst] = *(const uint4*)(Al + goff);
    }
    #pragma unroll
    for (int p = 0; p < 2; p++) {
      int t2 = t + p * 256;
      int row = t2 >> 2, kq = t2 & 3;
      long gofB = (n0 + row) * (long)K + k0 + kq * 8;
      int dst = (row >> 4) * 512 + ((((row & 15) ^ (kq << 1)) + 16 * kq)) * 8;
      *(uint4*)&BhS[dst] = *(const uint4*)(Bh + gofB);
      *(uint4*)&BlS[dst] = *(const uint4*)(Bl + gofB);
    }
    __syncthreads();
    bf16x8 ah[2], al[2], bh[4], bl[4];
    #pragma unroll
    for (int i = 0; i < 2; i++) {
      ah[i] = *(const bf16x8*)&AhS[(wm * 2 + i) * 512 + rs];
      al[i] = *(const bf16x8*)&AlS[(wm * 2 + i) * 512 + rs];
    }
    #pragma unroll
    for (int j = 0; j < 4; j++) {
      bh[j] = *(const bf16x8*)&BhS[(wn * 4 + j) * 512 + rs];
      bl[j] = *(const bf16x8*)&BlS[(wn * 4 + j) * 512 + rs];
    }
    #pragma unroll
    for (int i = 0; i < 2; i++)
      #pragma unroll
      for (int j = 0; j < 4; j++) {
        acc[i][j] = __builtin_amdgcn_mfma_f32_16x16x32_bf16(ah[i], bh[j], acc[i][j], 0, 0, 0);
        acc[i][j] = __builtin_amdgcn_mfma_f32_16x16x32_bf16(ah[i], bl[j], acc[i][j], 0, 0, 0);
        acc[i][j] = __builtin_amdgcn_mfma_f32_16x16x32_bf16(al[i], bh[j], acc[i][j], 0, 0, 0);
      }
    __syncthreads();
  }
  const long rbase = m0 + wm * 32 + (l >> 4) * 4;
  const int  cbase = (int)n0 + wn * 64 + (l & 15);
  #pragma unroll
  for (int i = 0; i < 2; i++)
    #pragma unroll
    for (int j = 0; j < 4; j++)
      #pragma unroll
      for (int r = 0; r < 4; r++) {
        long off = (rbase + i * 16 + r) * N + cbase + j * 16;
        ushort hb, lb;
        hilo(acc[i][j][r], hb, lb);
        Ch[off] = hb;
        Cl[off] = lb;
      }
}

// ================= ctx via MFMA: r generated into LDS in A-frag order ================
// B staged from row-major vals^T hi/lo planes [b][e=h*64+d][n] with frag swizzle.
__global__ __launch_bounds__(256) void nb_ctx_mf(
    const ushort* __restrict__ vTh, const ushort* __restrict__ vTl,
    const float* __restrict__ muq, const float* __restrict__ sg2,
    const float* __restrict__ bmu, const float* __restrict__ bsg,
    ushort* __restrict__ ctxh, ushort* __restrict__ ctxl,
    long sMu, long sC, long sV)
{
  int bx, by, bz;
  xcd_remap(bx, by, bz);
  const int h = by, b = bz;
  const long q0 = (long)bx * 128;
  const int t = threadIdx.x;
  const int l = t & 63, w = t >> 6, wm = w & 1, wn = w >> 1;
  __shared__ ushort AhS[4096], AlS[4096];
  __shared__ ushort BhS[2048], BlS[2048];
  __shared__ float mu_s[128], s2_s[128], bm_s[NB], bv_s[NB];
  const float* muqb = muq + (long)b * sMu;
  const float* sg2b = sg2 + (long)b * sMu;
  if (t < 128) {
    mu_s[t] = muqb[(long)h * QQ + q0 + t];
    s2_s[t] = sg2b[(long)h * QQ + q0 + t];
  }
  for (int i = t; i < NB; i += 256) {
    bm_s[i] = bmu[i];
    float x = bsg[i];
    bv_s[i] = x * x;
  }
  __syncthreads();
  const ushort* vThb = vTh + (long)b * sV + (long)(h * 64) * NB;
  const ushort* vTlb = vTl + (long)b * sV + (long)(h * 64) * NB;
  const int rs = ((((l & 15) ^ ((l >> 4) << 1)) + 16 * (l >> 4))) * 8;
  const int srow = t >> 2, skq = t & 3;                   // B staging: row=d, kq=n-quad
  const long bsrc = (long)srow * NB + skq * 8;
  const int bdst = (srow >> 4) * 512 + ((((srow & 15) ^ (skq << 1)) + 16 * skq)) * 8;
  f32x4 acc[4][2] = {};
  for (int c = 0; c < 16; c++) {
    *(uint4*)&BhS[bdst] = *(const uint4*)(vThb + bsrc + c * 32);
    *(uint4*)&BlS[bdst] = *(const uint4*)(vTlb + bsrc + c * 32);
    // generate A (r values): 512 slots, 2 per thread. rsq-only transcendental path:
    // exp(-0.5 d^2/v) = exp(-0.5 (d*rsq(v))^2); 1/sqrt(2 pi v) = rsq(v)*0.3989423
    #pragma unroll
    for (int p = 0; p < 2; p++) {
      int s = t + p * 256;
      int lf = s & 63;
      int qq = ((s >> 6) << 4) + (lf & 15);
      int nb0 = c * 32 + (lf >> 4) * 8;
      float m = mu_s[qq], s2 = s2_s[qq];
      float a[8];
      #pragma unroll
      for (int e = 0; e < 8; e++) {
        float v = s2 + bv_s[nb0 + e];
        float d = m - bm_s[nb0 + e];
        float si = __builtin_amdgcn_rsqf(v);
        float tt = d * si;
        a[e] = __expf(tt * tt * -0.5f) * (si * 0.3989422804014327f);
      }
      uint4 ph, pl;
      cvt8_pack(a, ph, pl);
      *(uint4*)&AhS[s * 8] = ph;
      *(uint4*)&AlS[s * 8] = pl;
    }
    __syncthreads();
    bf16x8 bhf[2], blf[2];
    #pragma unroll
    for (int j = 0; j < 2; j++) {
      bhf[j] = *(const bf16x8*)&BhS[(wn * 2 + j) * 512 + rs];
      blf[j] = *(const bf16x8*)&BlS[(wn * 2 + j) * 512 + rs];
    }
    #pragma unroll
    for (int i = 0; i < 4; i++) {
      bf16x8 ah = *(const bf16x8*)&AhS[(wm * 4 + i) * 512 + l * 8];
      bf16x8 al = *(const bf16x8*)&AlS[(wm * 4 + i) * 512 + l * 8];
      #pragma unroll
      for (int j = 0; j < 2; j++) {
        acc[i][j] = __builtin_amdgcn_mfma_f32_16x16x32_bf16(ah, bhf[j], acc[i][j], 0, 0, 0);
        acc[i][j] = __builtin_amdgcn_mfma_f32_16x16x32_bf16(ah, blf[j], acc[i][j], 0, 0, 0);
        acc[i][j] = __builtin_amdgcn_mfma_f32_16x16x32_bf16(al, bhf[j], acc[i][j], 0, 0, 0);
      }
    }
    __syncthreads();
  }
  ushort* ch = ctxh + (long)b * sC;
  ushort* cl = ctxl + (long)b * sC;
  const long rbase = q0 + wm * 64 + (l >> 4) * 4;
  const int  cbase = h * 64 + wn * 32 + (l & 15);
  #pragma unroll
  for (int i = 0; i < 4; i++)
    #pragma unroll
    for (int j = 0; j < 2; j++)
      #pragma unroll
      for (int r = 0; r < 4; r++) {
        long off = (rbase + i * 16 + r) * EE + cbase + j * 16;
        ushort hb, lb;
        hilo(acc[i][j][r], hb, lb);
        ch[off] = hb;
        cl[off] = lb;
      }
}

// ================= collapsed scores path =================
// tier-1: read Bm hi/lo planes (hi+lo reconstructs fp32 to ~2^-17 rel)
__global__ __launch_bounds__(256) void nb_uvec_us(
    const ushort* __restrict__ Bmh, const ushort* __restrict__ Bml,
    const float* __restrict__ wmu, const float* __restrict__ wsg,
    float* __restrict__ ump, float* __restrict__ usp, long sBm, long sU)
{
  Bmh += (long)blockIdx.z * sBm; Bml += (long)blockIdx.z * sBm;
  ump += (long)blockIdx.z * sU; usp += (long)blockIdx.z * sU;
  const int e = blockIdx.x * 256 + threadIdx.x;
  const int c = blockIdx.y;
  float am = 0.f, as = 0.f;
  #pragma unroll 8
  for (int n = c * 64; n < c * 64 + 64; n++) {
    float bv = bf16_f(Bmh[(long)n * EE + e]) + bf16_f(Bml[(long)n * EE + e]);
    am += wmu[n] * bv;
    as += wsg[n] * bv;
  }
  ump[(long)c * EE + e] = am;
  usp[(long)c * EE + e] = as;
}

// tier-2 fp32 version
__global__ __launch_bounds__(256) void nb_uvec(
    const float* __restrict__ Bm, const float* __restrict__ wmu, const float* __restrict__ wsg,
    float* __restrict__ ump, float* __restrict__ usp, long sBm, long sU)
{
  Bm += (long)blockIdx.z * sBm; ump += (long)blockIdx.z * sU; usp += (long)blockIdx.z * sU;
  const int e = blockIdx.x * 256 + threadIdx.x;
  const int c = blockIdx.y;
  float am = 0.f, as = 0.f;
  #pragma unroll 8
  for (int n = c * 64; n < c * 64 + 64; n++) {
    float bv = Bm[(long)n * EE + e];
    am += wmu[n] * bv;
    as += wsg[n] * bv;
  }
  ump[(long)c * EE + e] = am;
  usp[(long)c * EE + e] = as;
}

__global__ __launch_bounds__(256) void nb_kw(
    const float* __restrict__ Wk, const float* __restrict__ ump, const float* __restrict__ usp,
    float* __restrict__ kwm, float* __restrict__ kws, long sU, long sK)
{
  ump += (long)blockIdx.z * sU; usp += (long)blockIdx.z * sU;
  kwm += (long)blockIdx.z * sK; kws += (long)blockIdx.z * sK;
  __shared__ float pm[256], ps[256];
  const int e = blockIdx.x, t = threadIdx.x;
  const float* row = Wk + (long)e * EE;
  float am = 0.f, as = 0.f;
  for (int i = t; i < EE; i += 256) {
    float um = 0.f, us = 0.f;
    #pragma unroll
    for (int c = 0; c < 8; c++) { um += ump[(long)c * EE + i]; us += usp[(long)c * EE + i]; }
    float w = row[i];
    am += w * um;
    as += w * us;
  }
  pm[t] = am; ps[t] = as;
  __syncthreads();
  for (int s = 128; s > 0; s >>= 1) {
    if (t < s) { pm[t] += pm[t + s]; ps[t] += ps[t + s]; }
    __syncthreads();
  }
  if (t == 0) { kwm[e] = pm[0]; kws[e] = ps[0]; }
}

__global__ __launch_bounds__(256) void nb_amas(
    const float* __restrict__ Wq, const float* __restrict__ kwm, const float* __restrict__ kws,
    float* __restrict__ AmAs, long sK, long sAm)
{
  kwm += (long)blockIdx.z * sK; kws += (long)blockIdx.z * sK;
  AmAs += (long)blockIdx.z * sAm;
  __shared__ float km[64], ks[64];
  const int t = threadIdx.x;
  const int h = blockIdx.y;
  const int e = blockIdx.x * 256 + t;
  if (t < 64) { km[t] = kwm[h * 64 + t]; ks[t] = kws[h * 64 + t]; }
  __syncthreads();
  float am = 0.f, as = 0.f;
  #pragma unroll 8
  for (int d = 0; d < 64; d++) {
    float w = Wq[(long)(h * 64 + d) * EE + e];
    am += km[d] * w;
    as += ks[d] * w;
  }
  AmAs[(long)e * 32 + h]      = am;
  AmAs[(long)e * 32 + 16 + h] = as;
}

__global__ __launch_bounds__(256) void nb_musig8(
    const float* __restrict__ qb, const float* __restrict__ AmAs,
    float* __restrict__ muq, float* __restrict__ sg2, long sQ, long sAm, long sMu)
{
  qb += (long)blockIdx.z * sQ; AmAs += (long)blockIdx.z * sAm;
  muq += (long)blockIdx.z * sMu; sg2 += (long)blockIdx.z * sMu;
  __shared__ float qs[8 * EE];
  const int t = threadIdx.x;
  const long q0 = (long)blockIdx.x * 8;
  for (int i = t * 4; i < 8 * EE; i += 1024)
    *(float4*)&qs[i] = *(const float4*)&qb[q0 * EE + i];
  __syncthreads();
  const int o = t & 31, row = t >> 5;
  const float* qr = qs + row * EE;
  float acc = 0.f;
  #pragma unroll 8
  for (int e = 0; e < EE; e++)
    acc += qr[e] * AmAs[(long)e * 32 + o];
  float s = acc * 0.125f;
  if (o < 16) {
    muq[(long)o * QQ + q0 + row] = 1.f / (1.f + expf(-s));
  } else {
    float sp = (s > 20.f) ? s : log1pf(expf(s));
    sg2[(long)(o - 16) * QQ + q0 + row] = fmaxf(sp, 1e-4f);
  }
}

__global__ __launch_bounds__(256) void nb_musig(
    const float* __restrict__ qb, const float* __restrict__ AmAs,
    float* __restrict__ muq, float* __restrict__ sg2, long sQ, long sAm, long sMu)
{
  qb += (long)blockIdx.z * sQ; AmAs += (long)blockIdx.z * sAm;
  muq += (long)blockIdx.z * sMu; sg2 += (long)blockIdx.z * sMu;
  __shared__ float qs[EE];
  __shared__ float part[8][32];
  const int t = threadIdx.x, qrow = blockIdx.x;
  for (int i = t; i < EE; i += 256) qs[i] = qb[(long)qrow * EE + i];
  __syncthreads();
  const int o = t & 31, ch = t >> 5;
  float acc = 0.f;
  const int e0 = ch * 128;
  #pragma unroll 8
  for (int i = 0; i < 128; i++) {
    int e = e0 + i;
    acc += qs[e] * AmAs[(long)e * 32 + o];
  }
  part[ch][o] = acc;
  __syncthreads();
  if (t < 32) {
    float s = 0.f;
    #pragma unroll
    for (int c = 0; c < 8; c++) s += part[c][o];
    s *= 0.125f;
    if (o < 16) {
      muq[(long)o * QQ + qrow] = 1.f / (1.f + expf(-s));
    } else {
      float sp = (s > 20.f) ? s : log1pf(expf(s));
      sg2[(long)(o - 16) * QQ + qrow] = fmaxf(sp, 1e-4f);
    }
  }
}

// ================= tier-2 ctx (fp32, proven) =================
__global__ __launch_bounds__(128) void nb_ctx128(
    const float* __restrict__ vals, const float* __restrict__ muq, const float* __restrict__ sg2,
    const float* __restrict__ bmu,  const float* __restrict__ bsg, float* __restrict__ ctx,
    long sV, long sMu, long sC)
{
  vals += (long)blockIdx.z * sV; ctx += (long)blockIdx.z * sC;
  muq += (long)blockIdx.z * sMu; sg2 += (long)blockIdx.z * sMu;
  __shared__ float As[32][132], Bs[32][68];
  __shared__ __align__(16) float mu_s[128], s2_s[128];
  const int t = threadIdx.x;
  const int tx = t & 7, ty = t >> 3;
  const long q0 = (long)blockIdx.x * 128;
  const int h = blockIdx.y;
  mu_s[t] = muq[(long)h * QQ + q0 + t];
  s2_s[t] = sg2[(long)h * QQ + q0 + t];
  __syncthreads();
  float acc[8][8] = {};
  for (int n0 = 0; n0 < NB; n0 += 32) {
    #pragma unroll
    for (int i = 0; i < 4; i++) {
      int f = t + i * 128;
      int r = f >> 4, c4 = f & 15;
      *(float4*)&Bs[r][c4 * 4] = *(const float4*)&vals[(long)(n0 + r) * EE + h * 64 + c4 * 4];
    }
    #pragma unroll
    for (int i = 0; i < 8; i++) {
      int idx = t + i * 128;
      int n = idx >> 5, qg = idx & 31;
      float bm = bmu[n0 + n], bs = bsg[n0 + n];
      float bs2 = bs * bs;
      float4 m4 = *(const float4*)&mu_s[qg * 4];
      float4 s4 = *(const float4*)&s2_s[qg * 4];
      float4 rr;
      {
        float v0 = s4.x + bs2, d0 = m4.x - bm;
        float v1 = s4.y + bs2, d1 = m4.y - bm;
        float v2 = s4.z + bs2, d2 = m4.z - bm;
        float v3 = s4.w + bs2, d3 = m4.w - bm;
        float r0 = __builtin_amdgcn_rcpf(v0), r1 = __builtin_amdgcn_rcpf(v1);
        float r2 = __builtin_amdgcn_rcpf(v2), r3 = __builtin_amdgcn_rcpf(v3);
        rr.x = __expf(d0 * d0 * r0 * -0.5f) * __builtin_amdgcn_rsqf(v0 * 6.2831853071795865f);
        rr.y = __expf(d1 * d1 * r1 * -0.5f) * __builtin_amdgcn_rsqf(v1 * 6.2831853071795865f);
        rr.z = __expf(d2 * d2 * r2 * -0.5f) * __builtin_amdgcn_rsqf(v2 * 6.2831853071795865f);
        rr.w = __expf(d3 * d3 * r3 * -0.5f) * __builtin_amdgcn_rsqf(v3 * 6.2831853071795865f);
      }
      *(float4*)&As[n][qg * 4] = rr;
    }
    __syncthreads();
    #pragma unroll
    for (int kk = 0; kk < 32; kk++) {
      float4 a0 = *(const float4*)&As[kk][ty*8];
      float4 a1 = *(const float4*)&As[kk][ty*8+4];
      float4 b0 = *(const float4*)&Bs[kk][tx*8];
      float4 b1 = *(const float4*)&Bs[kk][tx*8+4];
      float ar[8] = {a0.x,a0.y,a0.z,a0.w,a1.x,a1.y,a1.z,a1.w};
      float br[8] = {b0.x,b0.y,b0.z,b0.w,b1.x,b1.y,b1.z,b1.w};
      #pragma unroll
      for (int i = 0; i < 8; i++)
        #pragma unroll
        for (int j = 0; j < 8; j++)
          acc[i][j] += ar[i] * br[j];
    }
    __syncthreads();
  }
  #pragma unroll
  for (int i = 0; i < 8; i++) {
    float4 o0 = make_float4(acc[i][0], acc[i][1], acc[i][2], acc[i][3]);
    float4 o1 = make_float4(acc[i][4], acc[i][5], acc[i][6], acc[i][7]);
    *(float4*)&ctx[(q0 + ty*8 + i) * EE + h * 64 + tx*8    ] = o0;
    *(float4*)&ctx[(q0 + ty*8 + i) * EE + h * 64 + tx*8 + 4] = o1;
  }
}

extern "C" void kernel_launch(void* const* d_in, const int* in_sizes, int n_in,
                              void* d_out, int out_size, void* d_ws, size_t ws_size,
                              hipStream_t stream) {
  const float* k   = (const float*)d_in[0];
  const float* q   = (const float*)d_in[1];
  const float* Wq  = (const float*)d_in[2];
  const float* Wk  = (const float*)d_in[3];
  const float* Wv  = (const float*)d_in[4];
  const float* Wo  = (const float*)d_in[5];
  const float* wmu = (const float*)d_in[6];
  const float* wsg = (const float*)d_in[7];
  const float* Gs  = (const float*)d_in[8];
  const float* bmu = (const float*)d_in[9];
  const float* bsg = (const float*)d_in[10];
  float* out = (float*)d_out;
  char* ws = (char*)d_ws;

  const long sBm = (long)NB * EE;   // 512K elems (Bm / vT per batch)
  const long sU  = 8L * EE;
  const long sK  = EE;
  const long sAm = 32L * EE;
  const long sMu = (long)HH * QQ;
  const long sQ  = (long)QQ * EE;

  if (ws_size >= (50u << 20)) {
    // ---- tier 1 (48 MiB + smalls), lifetimes stream-ordered disjoint ----
    // [0,16):  kTh {S1..st2} -> Wvh[0,2) Wvl[2,4) {cvt..st3T} -> ctxh {ctx..st7}
    // [16,32): kTl {S1..st2} -> ctxl {ctx..st7}
    // [32,36): GsTh/GsTl {S1..st2} -> vTh [32,36) {st3T..ctx} -> Woh[32,34) Wol[34,36) {..st7}
    // [36,40): vTl {st3T..ctx}
    // [40,44): Bmh {st2..st3T} | [44,48): Bml
    // [48,50): smalls
    ushort* kTh  = (ushort*)(ws + 0);
    ushort* kTl  = (ushort*)(ws + (16u << 20));
    ushort* GsTh = (ushort*)(ws + (32u << 20));
    ushort* GsTl = (ushort*)(ws + (34u << 20));
    ushort* Bmh  = (ushort*)(ws + (40u << 20));
    ushort* Bml  = (ushort*)(ws + (44u << 20));
    ushort* Wvh  = (ushort*)(ws + 0);
    ushort* Wvl  = (ushort*)(ws + (2u << 20));
    ushort* vTh  = (ushort*)(ws + (32u << 20));
    ushort* vTl  = (ushort*)(ws + (36u << 20));
    ushort* Woh  = (ushort*)(ws + (32u << 20));
    ushort* Wol  = (ushort*)(ws + (34u << 20));
    ushort* ctxh = (ushort*)(ws + 0);
    ushort* ctxl = (ushort*)(ws + (16u << 20));
    char*  sm    = ws + (48u << 20);
    float* ump4  = (float*)(sm);
    float* usp4  = (float*)(sm + (128u << 10));
    float* kwm4  = (float*)(sm + (256u << 10));
    float* kws4  = (float*)(sm + (272u << 10));
    float* AmAs4 = (float*)(sm + (288u << 10));
    float* muq4  = (float*)(sm + (800u << 10));
    float* sg24  = (float*)(sm + (1312u << 10));

    // S1: transposed hilo operands for st2
    cvt_hiloT<<<dim3(NB/32, LL/32, 1),  256, 0, stream>>>(Gs, GsTh, GsTl, LL, NB, 0L, 0L);
    cvt_hiloT<<<dim3(EE/32, LL/32, BB), 256, 0, stream>>>(k, kTh, kTl, LL, EE,
                                                          (long)LL*EE, (long)LL*EE);
    // st2 (MFMA bf16x3): Bm[nb][e] = sum_l GsT[nb][l]*kT[e][l] -> hi/lo planes directly
    gemm_nt64x128_b3_us<<<dim3(EE/128, NB/64, BB), 256, 0, stream>>>(
        GsTh, GsTl, kTh, kTl, Bmh, Bml, EE, LL, (long)LL*EE, sBm);
    // scores chain (uvec reads Bm hi/lo)
    nb_uvec_us<<<dim3(EE/256, 8, BB),  256, 0, stream>>>(Bmh, Bml, wmu, wsg, ump4, usp4, sBm, sU);
    nb_kw     <<<dim3(EE, 1, BB),      256, 0, stream>>>(Wk, ump4, usp4, kwm4, kws4, sU, sK);
    nb_amas   <<<dim3(EE/256, HH, BB), 256, 0, stream>>>(Wq, kwm4, kws4, AmAs4, sK, sAm);
    nb_musig8 <<<dim3(QQ/8, 1, BB),    256, 0, stream>>>(q, AmAs4, muq4, sg24, sQ, sAm, sMu);
    // Wv -> hilo (kT dead)
    cvt_hilo<<<dim3(256), 256, 0, stream>>>(Wv, Wvh, Wvl, (long)EE * EE);
    // st3T (MFMA bf16x3): vals^T[e][nb] = sum_k Wv[e][k]*Bm[nb][k] -> hi/lo planes
    // (GsT dead -> vT home)
    gemm_nt64x128_b3_us<<<dim3(NB/128, EE/64, BB), 256, 0, stream>>>(
        Wvh, Wvl, Bmh, Bml, vTh, vTl, NB, EE, sBm, sBm);
    // ctx (MFMA bf16x3, r on the fly) -> ctx hilo planes (Wv/kTl dead)
    nb_ctx_mf<<<dim3(QQ/128, HH, BB), 256, 0, stream>>>(
        vTh, vTl, muq4, sg24, bmu, bsg, ctxh, ctxl, sMu, sQ, sBm);
    // Wo -> hilo (vT dead)
    cvt_hilo<<<dim3(256), 256, 0, stream>>>(Wo, Woh, Wol, (long)EE * EE);
    // st7 (MFMA bf16x3): out = ctx @ Wo^T
    gemm_nt128_b3<<<dim3(EE/128, QQ/128, BB), 256, 0, stream>>>(
        ctxh, ctxl, Woh, Wol, out, EE, EE, sQ, sQ, 1, EE);
  } else {
    // ---- tier 2 (ws >= 26 MiB, all-fp32 proven path) ----
    float* BmP   = (float*)(ws + 0);
    float* ctxS  = (float*)(ws + 0);
    float* vals4 = (float*)(ws + (16u << 20));
    char*  sm    = ws + (24u << 20);
    float* ump4  = (float*)(sm);
    float* usp4  = (float*)(sm + (128u << 10));
    float* kwm4  = (float*)(sm + (256u << 10));
    float* kws4  = (float*)(sm + (272u << 10));
    float* AmAs4 = (float*)(sm + (288u << 10));
    float* muq4  = (float*)(sm + (800u << 10));
    float* sg24  = (float*)(sm + (1312u << 10));

    gemm_tn128<<<dim3(EE/128, NB/128, BB*2), 256, 0, stream>>>(
        Gs, k, BmP, NB, EE, 0L, (long)LL*EE, sBm, 2, LL/2);
    add_pairs<<<dim3(256, 1, BB), 256, 0, stream>>>(BmP, 2*sBm, BmP, 2*sBm, sBm);
    gemm_nt128<<<dim3(EE/128, NB/128, BB), 256, 0, stream>>>(
        BmP, Wv, vals4, EE, EE, 2*sBm, 0L, sBm, 1, EE);
    nb_uvec  <<<dim3(EE/256, 8, BB),  256, 0, stream>>>(BmP, wmu, wsg, ump4, usp4, 2*sBm, sU);
    nb_kw    <<<dim3(EE, 1, BB),      256, 0, stream>>>(Wk, ump4, usp4, kwm4, kws4, sU, sK);
    nb_amas  <<<dim3(EE/256, HH, BB), 256, 0, stream>>>(Wq, kwm4, kws4, AmAs4, sK, sAm);
    nb_musig <<<dim3(QQ, 1, BB),      256, 0, stream>>>(q, AmAs4, muq4, sg24, sQ, sAm, sMu);
    for (int b = 0; b < BB; b++) {
      nb_ctx128<<<dim3(QQ/128, HH, 1), 128, 0, stream>>>(
          vals4 + (long)b*sBm, muq4 + (long)b*sMu, sg24 + (long)b*sMu,
          bmu, bsg, ctxS, 0L, 0L, 0L);
      gemm_nt64<<<dim3(EE/64, QQ/64, 1), 256, 0, stream>>>(
          ctxS, Wo, out + (long)b*sQ, QQ, EE, EE, 0L, 0L, 0L);
    }
  }
  (void)in_sizes; (void)n_in; (void)out_size;
}